// Round 5
// baseline (418.413 us; speedup 1.0000x reference)
//
#include <hip/hip_runtime.h>
#include <math.h>

#define N_ENT 200000
#define N_USERS 100000
#define NKEY 300000            // N_ENT + N_USERS unified key space
#define N_FACTORS 4
#define NREL1 25               // N_REL - 1
#define CH 64
#define N_EDGES 1000000
#define NNZ 1000000
#define NREC 2000000           // N_EDGES + NNZ unified records
#define BSHIFT 11
#define NBUCKET 147            // ceil(NKEY / 2048)
#define TILE 2048

// 1 / (2*sqrt(32))
#define SCORE_SCALE 0.08838834764831845f
#define INV_Q14 6.103888176768602e-05f   // 1/16383

__device__ __forceinline__ float red16(float d) {
    d += __shfl_xor(d, 1);
    d += __shfl_xor(d, 2);
    d += __shfl_xor(d, 4);
    d += __shfl_xor(d, 8);
    return d;
}
__device__ __forceinline__ float dot4(float4 a, float4 b) {
    return a.x * b.x + a.y * b.y + a.z * b.z + a.w * b.w;
}
__device__ __forceinline__ unsigned short f2bf(float f) {   // RNE
    unsigned u = __float_as_uint(f);
    u += 0x7FFFu + ((u >> 16) & 1u);
    return (unsigned short)(u >> 16);
}
__device__ __forceinline__ float4 unpack_bf4(uint2 t) {
    return make_float4(__uint_as_float(t.x << 16), __uint_as_float(t.x & 0xFFFF0000u),
                       __uint_as_float(t.y << 16), __uint_as_float(t.y & 0xFFFF0000u));
}

// ---- tiny precompute: Mvec[r] = (W W^T) weight[r]; wnorm[r]; disen[f][c] ----
__global__ void precompute_k(const float* __restrict__ W,
                             const float* __restrict__ weight,
                             const float* __restrict__ datt,
                             float* __restrict__ Mvec,
                             float* __restrict__ wnorm,
                             float* __restrict__ disen) {
    __shared__ float sW[64 * 64];
    __shared__ float sw[NREL1 * 64];
    __shared__ float sWWt[64 * 64];
    int tid = threadIdx.x;
    for (int i = tid; i < 64 * 64; i += 256) sW[i] = W[i];
    for (int i = tid; i < NREL1 * 64; i += 256) sw[i] = weight[i];
    __syncthreads();
    for (int e = tid; e < 64 * 64; e += 256) {
        int i = e >> 6, j = e & 63;
        float s = 0.f;
        for (int k = 0; k < 64; ++k) s += sW[i * 64 + k] * sW[j * 64 + k];
        sWWt[e] = s;
    }
    __syncthreads();
    for (int e = tid; e < NREL1 * 64; e += 256) {
        int r = e >> 6, i = e & 63;
        float s = 0.f;
        for (int j = 0; j < 64; ++j) s += sWWt[i * 64 + j] * sw[r * 64 + j];
        Mvec[e] = s;
    }
    for (int r = tid; r < NREL1; r += 256) {
        float s = 0.f;
        for (int j = 0; j < 64; ++j) { float v = sw[r * 64 + j]; s += v * v; }
        wnorm[r] = s;
    }
    for (int e = tid; e < N_FACTORS * 64; e += 256) {
        int f = e >> 6, c = e & 63;
        float m = -1e30f;
        for (int r = 0; r < NREL1; ++r) m = fmaxf(m, datt[f * NREL1 + r]);
        float ssum = 0.f, acc = 0.f;
        for (int r = 0; r < NREL1; ++r) {
            float p = expf(datt[f * NREL1 + r] - m);
            ssum += p;
            acc += p * sw[r * 64 + c];
        }
        disen[e] = acc / ssum;
    }
}

// ---- convert entity table to bf16 shadow (halves gather bytes) ----
__global__ void conv_k(const float* __restrict__ ent, unsigned* __restrict__ entb) {
    int i = blockIdx.x * 256 + threadIdx.x;       // one thread per 8 floats
    if (i >= N_ENT * 8) return;
    const float4* e4 = (const float4*)ent;
    float4 a = e4[i * 2], b = e4[i * 2 + 1];
    uint4 o;
    o.x = (unsigned)f2bf(a.x) | ((unsigned)f2bf(a.y) << 16);
    o.y = (unsigned)f2bf(a.z) | ((unsigned)f2bf(a.w) << 16);
    o.z = (unsigned)f2bf(b.x) | ((unsigned)f2bf(b.y) << 16);
    o.w = (unsigned)f2bf(b.z) | ((unsigned)f2bf(b.w) << 16);
    ((uint4*)entb)[i] = o;
}

// ---- unified count over 300k keys ----
__global__ void count2_k(const int* __restrict__ head,
                         const int* __restrict__ rows,
                         unsigned* __restrict__ cnt) {
    int i = blockIdx.x * 256 + threadIdx.x;
    if (i < N_EDGES) atomicAdd(&cnt[head[i]], 1u);
    else if (i < NREC) atomicAdd(&cnt[N_ENT + rows[i - N_EDGES]], 1u);
}

// ---- scan: per-512-block sums ----
__global__ void block_sums512_k(const unsigned* __restrict__ cnt,
                                unsigned* __restrict__ part) {
    int i = blockIdx.x * 512 + threadIdx.x;
    unsigned v = (i < NKEY) ? cnt[i] : 0u;
    for (int o = 32; o; o >>= 1) v += __shfl_down(v, o);
    __shared__ unsigned ws[8];
    if ((threadIdx.x & 63) == 0) ws[threadIdx.x >> 6] = v;
    __syncthreads();
    if (threadIdx.x == 0) {
        unsigned s = 0;
        for (int w = 0; w < 8; ++w) s += ws[w];
        part[blockIdx.x] = s;
    }
}

// ---- scan: single-block exclusive scan of n<=1024 partials ----
__global__ void scan1024_k(unsigned* __restrict__ p, int n) {
    __shared__ unsigned s[1024];
    int tid = threadIdx.x;
    unsigned v = (tid < n) ? p[tid] : 0u;
    s[tid] = v; __syncthreads();
    for (int o = 1; o < 1024; o <<= 1) {
        unsigned t = (tid >= o) ? s[tid - o] : 0u;
        __syncthreads();
        s[tid] += t;
        __syncthreads();
    }
    if (tid < n) p[tid] = s[tid] - v;
}

// ---- scan: emit offsets + cursor init (cnt becomes kcur) ----
__global__ void scan_emit512_k(unsigned* cnt,
                               const unsigned* __restrict__ part,
                               unsigned* __restrict__ offs) {
    __shared__ unsigned s[512];
    int tid = threadIdx.x;
    int i = blockIdx.x * 512 + tid;
    unsigned v = (i < NKEY) ? cnt[i] : 0u;
    s[tid] = v; __syncthreads();
    for (int o = 1; o < 512; o <<= 1) {
        unsigned t = (tid >= o) ? s[tid - o] : 0u;
        __syncthreads();
        s[tid] += t;
        __syncthreads();
    }
    unsigned base = part[blockIdx.x];
    if (i < NKEY) {
        unsigned excl = base + s[tid] - v;
        offs[i] = excl;
        cnt[i] = excl;                    // per-key cursor init
        if (i == NKEY - 1) offs[NKEY] = base + s[tid];
    }
}

// ---- bucket cursor init: gcur[b] = offs[b<<11] ----
__global__ void gcur_init_k(const unsigned* __restrict__ offs,
                            unsigned* __restrict__ gcur) {
    int b = threadIdx.x;
    if (b < NBUCKET) gcur[b] = offs[b << BSHIFT];
}

// ---- stage 1: LDS-binned scatter into bucket-staged arrays ----
__global__ void binfill_k(const int* __restrict__ head, const int* __restrict__ tail,
                          const int* __restrict__ etype,
                          const int* __restrict__ rows, const int* __restrict__ cols,
                          const float* __restrict__ vals,
                          unsigned* __restrict__ gcur,
                          unsigned* __restrict__ skey, unsigned* __restrict__ spay) {
    __shared__ unsigned hist[NBUCKET], base[NBUCKET], gbase[NBUCKET];
    __shared__ unsigned sh[256];
    __shared__ unsigned lkey[TILE], lpay[TILE];
    int tid = threadIdx.x;
    int tile0 = blockIdx.x * TILE;
    int tile_n = min(TILE, NREC - tile0);
    for (int b = tid; b < NBUCKET; b += 256) hist[b] = 0u;
    __syncthreads();
    unsigned key[8], pay[8], rank[8];
    for (int r = 0; r < 8; ++r) {
        int li = r * 256 + tid;
        key[r] = 0xFFFFFFFFu;
        if (li < tile_n) {
            int idx = tile0 + li;
            unsigned k, p;
            if (idx < N_EDGES) {
                k = (unsigned)head[idx];
                p = (unsigned)tail[idx] | ((unsigned)(etype[idx] - 1) << 18);
            } else {
                int j = idx - N_EDGES;
                k = (unsigned)(N_ENT + rows[j]);
                unsigned q = (unsigned)(vals[j] * 16383.f + 0.5f);
                p = (unsigned)cols[j] | (q << 18);
            }
            key[r] = k; pay[r] = p;
            rank[r] = atomicAdd(&hist[k >> BSHIFT], 1u);
        }
    }
    __syncthreads();
    unsigned v = (tid < NBUCKET) ? hist[tid] : 0u;
    sh[tid] = v; __syncthreads();
    for (int o = 1; o < 256; o <<= 1) {
        unsigned t = (tid >= o) ? sh[tid - o] : 0u;
        __syncthreads();
        sh[tid] += t;
        __syncthreads();
    }
    if (tid < NBUCKET) {
        base[tid] = sh[tid] - v;
        gbase[tid] = v ? atomicAdd(&gcur[tid], v) : 0u;
    }
    __syncthreads();
    for (int r = 0; r < 8; ++r) {
        if (key[r] != 0xFFFFFFFFu) {
            unsigned b = key[r] >> BSHIFT;
            unsigned pos = base[b] + rank[r];
            lkey[pos] = key[r]; lpay[pos] = pay[r];
        }
    }
    __syncthreads();
    for (int i = tid; i < tile_n; i += 256) {
        unsigned k = lkey[i];
        unsigned b = k >> BSHIFT;
        unsigned dst = gbase[b] + ((unsigned)i - base[b]);
        skey[dst] = k; spay[dst] = lpay[i];
    }
}

// ---- stage 2: one block per bucket; scatter within L2-resident window ----
__global__ void binplace_k(const unsigned* __restrict__ offs,
                           unsigned* __restrict__ kcur,
                           const unsigned* __restrict__ skey,
                           const unsigned* __restrict__ spay,
                           unsigned* __restrict__ csr) {
    int b = blockIdx.x;
    unsigned start = offs[b << BSHIFT];
    int endk = (b + 1) << BSHIFT;
    if (endk > NKEY) endk = NKEY;
    unsigned end = offs[endk];
    for (unsigned i = start + threadIdx.x; i < end; i += 256) {
        unsigned k = skey[i];
        unsigned pos = atomicAdd(&kcur[k], 1u);
        csr[pos] = spay[i];
    }
}

// ---- fallback direct fill ----
__global__ void fill_direct_k(const int* __restrict__ head, const int* __restrict__ tail,
                              const int* __restrict__ etype,
                              const int* __restrict__ rows, const int* __restrict__ cols,
                              const float* __restrict__ vals,
                              unsigned* __restrict__ kcur, unsigned* __restrict__ csr) {
    int i = blockIdx.x * 256 + threadIdx.x;
    if (i < N_EDGES) {
        unsigned p = (unsigned)tail[i] | ((unsigned)(etype[i] - 1) << 18);
        unsigned pos = atomicAdd(&kcur[head[i]], 1u);
        csr[pos] = p;
    } else if (i < NREC) {
        int j = i - N_EDGES;
        unsigned q = (unsigned)(vals[j] * 16383.f + 0.5f);
        unsigned p = (unsigned)cols[j] | (q << 18);
        unsigned pos = atomicAdd(&kcur[N_ENT + rows[j]], 1u);
        csr[pos] = p;
    }
}

// ---- entity gather: per head, two passes over its CSR segment ----
template<bool BF>
__global__ void ent_gather_k(const float* __restrict__ ent,
                             const unsigned* __restrict__ entb,
                             const float* __restrict__ weight,
                             const float* __restrict__ Mvec,
                             const float* __restrict__ wnorm,
                             const unsigned* __restrict__ offs,
                             const unsigned* __restrict__ csr,
                             float* __restrict__ out) {
    int gid = blockIdx.x * 256 + threadIdx.x;
    int h = gid >> 4;
    int sub = threadIdx.x & 15;
    if (h >= N_ENT) return;
    int beg = offs[h], end = offs[h + 1];
    const float4* e4 = (const float4*)ent;
    float4* o4 = (float4*)out;
    if (beg == end) {
        o4[h * 16 + sub] = make_float4(0.f, 0.f, 0.f, 0.f);
        return;
    }
    float4 hv = e4[h * 16 + sub];
    float dr = 0.f;
    for (int i = beg; i < end; ++i) {
        unsigned p = csr[i];
        int r = p >> 18;
        float d = red16(dot4(hv, ((const float4*)Mvec)[r * 16 + sub]));
        dr += __expf(d * SCORE_SCALE);
    }
    float inv_dr = 1.0f / dr;
    float4 acc = make_float4(0.f, 0.f, 0.f, 0.f);
    float dt = 0.f;
    for (int i = beg; i < end; ++i) {
        unsigned p = csr[i];
        int t = p & 0x3FFFF;
        int r = p >> 18;
        float d1 = red16(dot4(hv, ((const float4*)Mvec)[r * 16 + sub]));
        float er = __expf(d1 * SCORE_SCALE);
        float ra = er * inv_dr;
        float4 tv;
        if (BF) tv = unpack_bf4(((const uint2*)entb)[t * 16 + sub]);
        else    tv = e4[t * 16 + sub];
        float d2 = red16(dot4(hv, tv));
        float et = __expf(d2 + ra * ra * wnorm[r]);
        dt += et;
        float4 wv = ((const float4*)weight)[r * 16 + sub];
        acc.x += et * tv.x * wv.x;
        acc.y += et * tv.y * wv.y;
        acc.z += et * tv.z * wv.z;
        acc.w += et * tv.w * wv.w;
    }
    float inv = 1.0f / (dt * (float)(end - beg));
    acc.x *= inv; acc.y *= inv; acc.z *= inv; acc.w *= inv;
    o4[h * 16 + sub] = acc;
}

// ---- user gather + fused softmax scaling epilogue ----
template<bool BF>
__global__ void user_gather_k(const float* __restrict__ ent,
                              const unsigned* __restrict__ entb,
                              const float* __restrict__ uemb,
                              const float* __restrict__ lat,
                              const float* __restrict__ disen,
                              const unsigned* __restrict__ offs,
                              const unsigned* __restrict__ csr,
                              float* __restrict__ out_user) {
    int gid = blockIdx.x * 256 + threadIdx.x;
    int u = gid >> 4;
    int sub = threadIdx.x & 15;
    if (u >= N_USERS) return;
    int beg = offs[N_ENT + u], end = offs[N_ENT + u + 1];
    const float4* e4 = (const float4*)ent;
    float4 acc = make_float4(0.f, 0.f, 0.f, 0.f);
    for (int i = beg; i < end; ++i) {
        unsigned p = csr[i];
        int c = p & 0x3FFFF;
        float v = (float)(p >> 18) * INV_Q14;
        float4 cv;
        if (BF) cv = unpack_bf4(((const uint2*)entb)[c * 16 + sub]);
        else    cv = e4[c * 16 + sub];
        acc.x += v * cv.x; acc.y += v * cv.y; acc.z += v * cv.z; acc.w += v * cv.w;
    }
    float4 uv = ((const float4*)uemb)[u * 16 + sub];
    float d[N_FACTORS];
    for (int f = 0; f < N_FACTORS; ++f)
        d[f] = red16(dot4(uv, ((const float4*)lat)[f * 16 + sub]));
    float m = fmaxf(fmaxf(d[0], d[1]), fmaxf(d[2], d[3]));
    float s = 0.f, p_[N_FACTORS];
    for (int f = 0; f < N_FACTORS; ++f) { p_[f] = __expf(d[f] - m); s += p_[f]; }
    float invs = 1.0f / s;
    float4 g = make_float4(0.f, 0.f, 0.f, 0.f);
    for (int f = 0; f < N_FACTORS; ++f) {
        float w = p_[f] * invs;
        float4 dv = ((const float4*)disen)[f * 16 + sub];
        g.x += w * dv.x; g.y += w * dv.y; g.z += w * dv.z; g.w += w * dv.w;
    }
    acc.x *= (1.0f + g.x); acc.y *= (1.0f + g.y);
    acc.z *= (1.0f + g.z); acc.w *= (1.0f + g.w);
    ((float4*)out_user)[u * 16 + sub] = acc;
}

extern "C" void kernel_launch(void* const* d_in, const int* in_sizes, int n_in,
                              void* d_out, int out_size, void* d_ws, size_t ws_size,
                              hipStream_t stream) {
    (void)in_sizes; (void)n_in; (void)out_size;
    const float* ent    = (const float*)d_in[0];
    const float* uemb   = (const float*)d_in[1];
    const float* lat    = (const float*)d_in[2];
    const int*   eidx   = (const int*)d_in[3];
    const int*   etype  = (const int*)d_in[4];
    const int*   urows  = (const int*)d_in[5];
    const int*   ucols  = (const int*)d_in[6];
    const float* uvals  = (const float*)d_in[7];
    const float* weight = (const float*)d_in[8];
    const float* datt   = (const float*)d_in[9];
    const float* W      = (const float*)d_in[10];

    const int* head = eidx;
    const int* tail = eidx + N_EDGES;
    float* out = (float*)d_out;
    float* out_user = out + (size_t)N_ENT * 64;

    // ws layout (4B words)
    unsigned* cnt   = (unsigned*)d_ws;            // 300000 (becomes kcur)
    unsigned* offs  = cnt + NKEY;                 // 300001
    unsigned* part  = offs + (NKEY + 1);          // 1024 (586 used)
    unsigned* gcur  = part + 1024;                // 160 (147 used)
    float*    Mvec  = (float*)(gcur + 160);       // 1600
    float*    wnorm = Mvec + NREL1 * 64;          // 32
    float*    disen = wnorm + 32;                 // 256
    unsigned* csr   = (unsigned*)(disen + N_FACTORS * 64);  // 2M
    unsigned* skey  = csr + NREC;                 // 2M (binned only)
    unsigned* spay  = skey + NREC;                // 2M (binned only)
    unsigned* entb  = spay + NREC;                // 3.2M words (bf16 table)

    size_t base_words   = (size_t)(skey - cnt);
    size_t need_binned  = (base_words + 2 * (size_t)NREC) * 4;
    size_t need_bf      = (base_words + 2 * (size_t)NREC + (size_t)N_ENT * 32) * 4;
    bool binned = ws_size >= need_binned;
    bool bf     = ws_size >= need_bf;

    const int BLK = 256;
    const int NBLK512 = (NKEY + 511) / 512;       // 586

    hipMemsetAsync(d_ws, 0, (size_t)NKEY * 4, stream);

    precompute_k<<<1, 256, 0, stream>>>(W, weight, datt, Mvec, wnorm, disen);
    if (bf) conv_k<<<(N_ENT * 8 + BLK - 1) / BLK, BLK, 0, stream>>>(ent, entb);
    count2_k<<<(NREC + BLK - 1) / BLK, BLK, 0, stream>>>(head, urows, cnt);
    block_sums512_k<<<NBLK512, 512, 0, stream>>>(cnt, part);
    scan1024_k<<<1, 1024, 0, stream>>>(part, NBLK512);
    scan_emit512_k<<<NBLK512, 512, 0, stream>>>(cnt, part, offs);

    if (binned) {
        gcur_init_k<<<1, 256, 0, stream>>>(offs, gcur);
        binfill_k<<<(NREC + TILE - 1) / TILE, BLK, 0, stream>>>(
            head, tail, etype, urows, ucols, uvals, gcur, skey, spay);
        binplace_k<<<NBUCKET, BLK, 0, stream>>>(offs, cnt, skey, spay, csr);
    } else {
        fill_direct_k<<<(NREC + BLK - 1) / BLK, BLK, 0, stream>>>(
            head, tail, etype, urows, ucols, uvals, cnt, csr);
    }

    int gridEnt  = (N_ENT * 16 + BLK - 1) / BLK;
    int gridUser = (N_USERS * 16 + BLK - 1) / BLK;
    if (bf) {
        ent_gather_k<true><<<gridEnt, BLK, 0, stream>>>(
            ent, entb, weight, Mvec, wnorm, offs, csr, out);
        user_gather_k<true><<<gridUser, BLK, 0, stream>>>(
            ent, entb, uemb, lat, disen, offs, csr, out_user);
    } else {
        ent_gather_k<false><<<gridEnt, BLK, 0, stream>>>(
            ent, entb, weight, Mvec, wnorm, offs, csr, out);
        user_gather_k<false><<<gridUser, BLK, 0, stream>>>(
            ent, entb, uemb, lat, disen, offs, csr, out_user);
    }
}

// Round 6
// 391.608 us; speedup vs baseline: 1.0684x; 1.0684x over previous
//
#include <hip/hip_runtime.h>
#include <math.h>

#define N_ENT 200000
#define N_USERS 100000
#define NKEY 300000            // N_ENT + N_USERS unified key space
#define N_FACTORS 4
#define NREL1 25               // N_REL - 1
#define CH 64
#define N_EDGES 1000000
#define NNZ 1000000
#define NREC 2000000           // N_EDGES + NNZ unified records
#define BSHIFT 11
#define NBUCKET 147            // ceil(NKEY / 2048)
#define TILE 2048

// 1 / (2*sqrt(32))
#define SCORE_SCALE 0.08838834764831845f
#define INV_Q14 6.103888176768602e-05f   // 1/16383

__device__ __forceinline__ float red8(float d) {
    d += __shfl_xor(d, 1);
    d += __shfl_xor(d, 2);
    d += __shfl_xor(d, 4);
    return d;
}
__device__ __forceinline__ float dot4(float4 a, float4 b) {
    return a.x * b.x + a.y * b.y + a.z * b.z + a.w * b.w;
}
__device__ __forceinline__ unsigned short f2bf(float f) {   // RNE
    unsigned u = __float_as_uint(f);
    u += 0x7FFFu + ((u >> 16) & 1u);
    return (unsigned short)(u >> 16);
}
__device__ __forceinline__ float bf2f(unsigned short u) {
    return __uint_as_float(((unsigned)u) << 16);
}
__device__ __forceinline__ float4 bf4lo(uint4 t) {
    return make_float4(__uint_as_float(t.x << 16), __uint_as_float(t.x & 0xFFFF0000u),
                       __uint_as_float(t.y << 16), __uint_as_float(t.y & 0xFFFF0000u));
}
__device__ __forceinline__ float4 bf4hi(uint4 t) {
    return make_float4(__uint_as_float(t.z << 16), __uint_as_float(t.z & 0xFFFF0000u),
                       __uint_as_float(t.w << 16), __uint_as_float(t.w & 0xFFFF0000u));
}

// ---- tiny precompute: Mvec[r] = (W W^T) weight[r]; wnorm[r]; disen[f][c] ----
__global__ void precompute_k(const float* __restrict__ W,
                             const float* __restrict__ weight,
                             const float* __restrict__ datt,
                             float* __restrict__ Mvec,
                             float* __restrict__ wnorm,
                             float* __restrict__ disen) {
    __shared__ float sW[64 * 64];
    __shared__ float sw[NREL1 * 64];
    __shared__ float sWWt[64 * 64];
    int tid = threadIdx.x;
    for (int i = tid; i < 64 * 64; i += 256) sW[i] = W[i];
    for (int i = tid; i < NREL1 * 64; i += 256) sw[i] = weight[i];
    __syncthreads();
    for (int e = tid; e < 64 * 64; e += 256) {
        int i = e >> 6, j = e & 63;
        float s = 0.f;
        for (int k = 0; k < 64; ++k) s += sW[i * 64 + k] * sW[j * 64 + k];
        sWWt[e] = s;
    }
    __syncthreads();
    for (int e = tid; e < NREL1 * 64; e += 256) {
        int r = e >> 6, i = e & 63;
        float s = 0.f;
        for (int j = 0; j < 64; ++j) s += sWWt[i * 64 + j] * sw[r * 64 + j];
        Mvec[e] = s;
    }
    for (int r = tid; r < NREL1; r += 256) {
        float s = 0.f;
        for (int j = 0; j < 64; ++j) { float v = sw[r * 64 + j]; s += v * v; }
        wnorm[r] = s;
    }
    for (int e = tid; e < N_FACTORS * 64; e += 256) {
        int f = e >> 6, c = e & 63;
        float m = -1e30f;
        for (int r = 0; r < NREL1; ++r) m = fmaxf(m, datt[f * NREL1 + r]);
        float ssum = 0.f, acc = 0.f;
        for (int r = 0; r < NREL1; ++r) {
            float p = expf(datt[f * NREL1 + r] - m);
            ssum += p;
            acc += p * sw[r * 64 + c];
        }
        disen[e] = acc / ssum;
    }
}

// ---- convert entity table to bf16 shadow (halves gather bytes) ----
__global__ void conv_k(const float* __restrict__ ent, unsigned* __restrict__ entb) {
    int i = blockIdx.x * 256 + threadIdx.x;       // one thread per 8 floats
    if (i >= N_ENT * 8) return;
    const float4* e4 = (const float4*)ent;
    float4 a = e4[i * 2], b = e4[i * 2 + 1];
    uint4 o;
    o.x = (unsigned)f2bf(a.x) | ((unsigned)f2bf(a.y) << 16);
    o.y = (unsigned)f2bf(a.z) | ((unsigned)f2bf(a.w) << 16);
    o.z = (unsigned)f2bf(b.x) | ((unsigned)f2bf(b.y) << 16);
    o.w = (unsigned)f2bf(b.z) | ((unsigned)f2bf(b.w) << 16);
    ((uint4*)entb)[i] = o;
}

// ---- E-table: E16[h][r] = bf16(exp(scale * dot(ent[h], Mvec[r]))) ----
__global__ void e_table_k(const float* __restrict__ ent,
                          const float* __restrict__ Mvec,
                          unsigned short* __restrict__ E16) {
    __shared__ float4 sM[NREL1 * 16];
    int tid = threadIdx.x;
    for (int i = tid; i < NREL1 * 16; i += 256) sM[i] = ((const float4*)Mvec)[i];
    __syncthreads();
    int gid = blockIdx.x * 256 + tid;
    int h = gid >> 3;
    int sub = tid & 7;
    if (h >= N_ENT) return;
    const float4* e4 = (const float4*)ent;
    float4 hv0 = e4[h * 16 + sub * 2], hv1 = e4[h * 16 + sub * 2 + 1];
    for (int r = 0; r < NREL1; ++r) {
        float d = dot4(hv0, sM[r * 16 + sub * 2]) + dot4(hv1, sM[r * 16 + sub * 2 + 1]);
        d = red8(d);
        if (sub == (r & 7)) E16[h * NREL1 + r] = f2bf(__expf(d * SCORE_SCALE));
    }
}

// ---- unified count over 300k keys ----
__global__ void count2_k(const int* __restrict__ head,
                         const int* __restrict__ rows,
                         unsigned* __restrict__ cnt) {
    int i = blockIdx.x * 256 + threadIdx.x;
    if (i < N_EDGES) atomicAdd(&cnt[head[i]], 1u);
    else if (i < NREC) atomicAdd(&cnt[N_ENT + rows[i - N_EDGES]], 1u);
}

// ---- scan: per-512-block sums ----
__global__ void block_sums512_k(const unsigned* __restrict__ cnt,
                                unsigned* __restrict__ part) {
    int i = blockIdx.x * 512 + threadIdx.x;
    unsigned v = (i < NKEY) ? cnt[i] : 0u;
    for (int o = 32; o; o >>= 1) v += __shfl_down(v, o);
    __shared__ unsigned ws[8];
    if ((threadIdx.x & 63) == 0) ws[threadIdx.x >> 6] = v;
    __syncthreads();
    if (threadIdx.x == 0) {
        unsigned s = 0;
        for (int w = 0; w < 8; ++w) s += ws[w];
        part[blockIdx.x] = s;
    }
}

// ---- scan: single-block exclusive scan of n<=1024 partials ----
__global__ void scan1024_k(unsigned* __restrict__ p, int n) {
    __shared__ unsigned s[1024];
    int tid = threadIdx.x;
    unsigned v = (tid < n) ? p[tid] : 0u;
    s[tid] = v; __syncthreads();
    for (int o = 1; o < 1024; o <<= 1) {
        unsigned t = (tid >= o) ? s[tid - o] : 0u;
        __syncthreads();
        s[tid] += t;
        __syncthreads();
    }
    if (tid < n) p[tid] = s[tid] - v;
}

// ---- scan: emit offsets + cursor init (cnt becomes kcur) ----
__global__ void scan_emit512_k(unsigned* cnt,
                               const unsigned* __restrict__ part,
                               unsigned* __restrict__ offs) {
    __shared__ unsigned s[512];
    int tid = threadIdx.x;
    int i = blockIdx.x * 512 + tid;
    unsigned v = (i < NKEY) ? cnt[i] : 0u;
    s[tid] = v; __syncthreads();
    for (int o = 1; o < 512; o <<= 1) {
        unsigned t = (tid >= o) ? s[tid - o] : 0u;
        __syncthreads();
        s[tid] += t;
        __syncthreads();
    }
    unsigned base = part[blockIdx.x];
    if (i < NKEY) {
        unsigned excl = base + s[tid] - v;
        offs[i] = excl;
        cnt[i] = excl;                    // per-key cursor init
        if (i == NKEY - 1) offs[NKEY] = base + s[tid];
    }
}

// ---- bucket cursor init: gcur[b] = offs[b<<11] ----
__global__ void gcur_init_k(const unsigned* __restrict__ offs,
                            unsigned* __restrict__ gcur) {
    int b = threadIdx.x;
    if (b < NBUCKET) gcur[b] = offs[b << BSHIFT];
}

// ---- stage 1: LDS-binned scatter into bucket-staged arrays ----
__global__ void binfill_k(const int* __restrict__ head, const int* __restrict__ tail,
                          const int* __restrict__ etype,
                          const int* __restrict__ rows, const int* __restrict__ cols,
                          const float* __restrict__ vals,
                          unsigned* __restrict__ gcur,
                          unsigned* __restrict__ skey, unsigned* __restrict__ spay) {
    __shared__ unsigned hist[NBUCKET], base[NBUCKET], gbase[NBUCKET];
    __shared__ unsigned sh[256];
    __shared__ unsigned lkey[TILE], lpay[TILE];
    int tid = threadIdx.x;
    int tile0 = blockIdx.x * TILE;
    int tile_n = min(TILE, NREC - tile0);
    for (int b = tid; b < NBUCKET; b += 256) hist[b] = 0u;
    __syncthreads();
    unsigned key[8], pay[8], rank[8];
    for (int r = 0; r < 8; ++r) {
        int li = r * 256 + tid;
        key[r] = 0xFFFFFFFFu;
        if (li < tile_n) {
            int idx = tile0 + li;
            unsigned k, p;
            if (idx < N_EDGES) {
                k = (unsigned)head[idx];
                p = (unsigned)tail[idx] | ((unsigned)(etype[idx] - 1) << 18);
            } else {
                int j = idx - N_EDGES;
                k = (unsigned)(N_ENT + rows[j]);
                unsigned q = (unsigned)(vals[j] * 16383.f + 0.5f);
                p = (unsigned)cols[j] | (q << 18);
            }
            key[r] = k; pay[r] = p;
            rank[r] = atomicAdd(&hist[k >> BSHIFT], 1u);
        }
    }
    __syncthreads();
    unsigned v = (tid < NBUCKET) ? hist[tid] : 0u;
    sh[tid] = v; __syncthreads();
    for (int o = 1; o < 256; o <<= 1) {
        unsigned t = (tid >= o) ? sh[tid - o] : 0u;
        __syncthreads();
        sh[tid] += t;
        __syncthreads();
    }
    if (tid < NBUCKET) {
        base[tid] = sh[tid] - v;
        gbase[tid] = v ? atomicAdd(&gcur[tid], v) : 0u;
    }
    __syncthreads();
    for (int r = 0; r < 8; ++r) {
        if (key[r] != 0xFFFFFFFFu) {
            unsigned b = key[r] >> BSHIFT;
            unsigned pos = base[b] + rank[r];
            lkey[pos] = key[r]; lpay[pos] = pay[r];
        }
    }
    __syncthreads();
    for (int i = tid; i < tile_n; i += 256) {
        unsigned k = lkey[i];
        unsigned b = k >> BSHIFT;
        unsigned dst = gbase[b] + ((unsigned)i - base[b]);
        skey[dst] = k; spay[dst] = lpay[i];
    }
}

// ---- stage 2: one block per bucket; scatter within L2-resident window ----
__global__ void binplace_k(const unsigned* __restrict__ offs,
                           unsigned* __restrict__ kcur,
                           const unsigned* __restrict__ skey,
                           const unsigned* __restrict__ spay,
                           unsigned* __restrict__ csr) {
    int b = blockIdx.x;
    unsigned start = offs[b << BSHIFT];
    int endk = (b + 1) << BSHIFT;
    if (endk > NKEY) endk = NKEY;
    unsigned end = offs[endk];
    for (unsigned i = start + threadIdx.x; i < end; i += 256) {
        unsigned k = skey[i];
        unsigned pos = atomicAdd(&kcur[k], 1u);
        csr[pos] = spay[i];
    }
}

// ---- fallback direct fill ----
__global__ void fill_direct_k(const int* __restrict__ head, const int* __restrict__ tail,
                              const int* __restrict__ etype,
                              const int* __restrict__ rows, const int* __restrict__ cols,
                              const float* __restrict__ vals,
                              unsigned* __restrict__ kcur, unsigned* __restrict__ csr) {
    int i = blockIdx.x * 256 + threadIdx.x;
    if (i < N_EDGES) {
        unsigned p = (unsigned)tail[i] | ((unsigned)(etype[i] - 1) << 18);
        unsigned pos = atomicAdd(&kcur[head[i]], 1u);
        csr[pos] = p;
    } else if (i < NREC) {
        int j = i - N_EDGES;
        unsigned q = (unsigned)(vals[j] * 16383.f + 0.5f);
        unsigned p = (unsigned)cols[j] | (q << 18);
        unsigned pos = atomicAdd(&kcur[N_ENT + rows[j]], 1u);
        csr[pos] = p;
    }
}

// ---- fused gather: 8 lanes per key; entities then users (unified key space) ----
template<bool FAST>   // FAST: bf16 entb gathers + E-table; else fp32 + on-the-fly Mvec
__global__ void gather8_k(const float* __restrict__ ent,
                          const uint4* __restrict__ entb,
                          const unsigned short* __restrict__ E16,
                          const float* __restrict__ weight,
                          const float* __restrict__ Mvec,
                          const float* __restrict__ wnorm,
                          const float* __restrict__ uemb,
                          const float* __restrict__ lat,
                          const float* __restrict__ disen,
                          const unsigned* __restrict__ offs,
                          const unsigned* __restrict__ csr,
                          float* __restrict__ out) {
    int gid = blockIdx.x * 256 + threadIdx.x;
    int key = gid >> 3;
    int sub = threadIdx.x & 7;
    if (key >= NKEY) return;
    unsigned beg = offs[key], end = offs[key + 1];
    const float4* e4 = (const float4*)ent;
    const float4* w4 = (const float4*)weight;
    float4* o4 = (float4*)out;
    const float4 z = make_float4(0.f, 0.f, 0.f, 0.f);

    if (key < N_ENT) {
        int h = key;
        if (beg == end) {
            o4[h * 16 + sub * 2] = z;
            o4[h * 16 + sub * 2 + 1] = z;
            return;
        }
        float4 hv0 = e4[h * 16 + sub * 2], hv1 = e4[h * 16 + sub * 2 + 1];
        // pass 1: denom_r (lane-parallel over edges in FAST mode)
        float dr = 0.f;
        if (FAST) {
            for (unsigned i = beg + sub; i < end; i += 8)
                dr += bf2f(E16[h * NREL1 + (csr[i] >> 18)]);
            dr = red8(dr);
        } else {
            for (unsigned i = beg; i < end; ++i) {
                int r = csr[i] >> 18;
                float d = dot4(hv0, ((const float4*)Mvec)[r * 16 + sub * 2]) +
                          dot4(hv1, ((const float4*)Mvec)[r * 16 + sub * 2 + 1]);
                dr += __expf(red8(d) * SCORE_SCALE);
            }
        }
        float inv_dr = 1.0f / dr;
        // pass 2: numerator + denom_t, 2-way unrolled for MLP
        float4 a0 = z, a1 = z;
        float dt = 0.f;
        unsigned i = beg;
        for (; i + 2 <= end; i += 2) {
            unsigned p0 = csr[i], p1 = csr[i + 1];
            int t0 = p0 & 0x3FFFF, r0 = p0 >> 18;
            int t1 = p1 & 0x3FFFF, r1 = p1 >> 18;
            float4 tv00, tv01, tv10, tv11;
            if (FAST) {
                uint4 tb0 = entb[t0 * 8 + sub];
                uint4 tb1 = entb[t1 * 8 + sub];
                tv00 = bf4lo(tb0); tv01 = bf4hi(tb0);
                tv10 = bf4lo(tb1); tv11 = bf4hi(tb1);
            } else {
                tv00 = e4[t0 * 16 + sub * 2]; tv01 = e4[t0 * 16 + sub * 2 + 1];
                tv10 = e4[t1 * 16 + sub * 2]; tv11 = e4[t1 * 16 + sub * 2 + 1];
            }
            float d0 = red8(dot4(hv0, tv00) + dot4(hv1, tv01));
            float d1 = red8(dot4(hv0, tv10) + dot4(hv1, tv11));
            float er0, er1;
            if (FAST) {
                er0 = bf2f(E16[h * NREL1 + r0]);
                er1 = bf2f(E16[h * NREL1 + r1]);
            } else {
                float q0 = dot4(hv0, ((const float4*)Mvec)[r0 * 16 + sub * 2]) +
                           dot4(hv1, ((const float4*)Mvec)[r0 * 16 + sub * 2 + 1]);
                float q1 = dot4(hv0, ((const float4*)Mvec)[r1 * 16 + sub * 2]) +
                           dot4(hv1, ((const float4*)Mvec)[r1 * 16 + sub * 2 + 1]);
                er0 = __expf(red8(q0) * SCORE_SCALE);
                er1 = __expf(red8(q1) * SCORE_SCALE);
            }
            float ra0 = er0 * inv_dr, ra1 = er1 * inv_dr;
            float et0 = __expf(d0 + ra0 * ra0 * wnorm[r0]);
            float et1 = __expf(d1 + ra1 * ra1 * wnorm[r1]);
            dt += et0 + et1;
            float4 wv;
            wv = w4[r0 * 16 + sub * 2];
            a0.x += et0 * tv00.x * wv.x; a0.y += et0 * tv00.y * wv.y;
            a0.z += et0 * tv00.z * wv.z; a0.w += et0 * tv00.w * wv.w;
            wv = w4[r0 * 16 + sub * 2 + 1];
            a1.x += et0 * tv01.x * wv.x; a1.y += et0 * tv01.y * wv.y;
            a1.z += et0 * tv01.z * wv.z; a1.w += et0 * tv01.w * wv.w;
            wv = w4[r1 * 16 + sub * 2];
            a0.x += et1 * tv10.x * wv.x; a0.y += et1 * tv10.y * wv.y;
            a0.z += et1 * tv10.z * wv.z; a0.w += et1 * tv10.w * wv.w;
            wv = w4[r1 * 16 + sub * 2 + 1];
            a1.x += et1 * tv11.x * wv.x; a1.y += et1 * tv11.y * wv.y;
            a1.z += et1 * tv11.z * wv.z; a1.w += et1 * tv11.w * wv.w;
        }
        if (i < end) {
            unsigned p = csr[i];
            int t = p & 0x3FFFF, r = p >> 18;
            float4 tv0, tv1;
            if (FAST) {
                uint4 tb = entb[t * 8 + sub];
                tv0 = bf4lo(tb); tv1 = bf4hi(tb);
            } else {
                tv0 = e4[t * 16 + sub * 2]; tv1 = e4[t * 16 + sub * 2 + 1];
            }
            float d = red8(dot4(hv0, tv0) + dot4(hv1, tv1));
            float er;
            if (FAST) {
                er = bf2f(E16[h * NREL1 + r]);
            } else {
                float q = dot4(hv0, ((const float4*)Mvec)[r * 16 + sub * 2]) +
                          dot4(hv1, ((const float4*)Mvec)[r * 16 + sub * 2 + 1]);
                er = __expf(red8(q) * SCORE_SCALE);
            }
            float ra = er * inv_dr;
            float et = __expf(d + ra * ra * wnorm[r]);
            dt += et;
            float4 wv;
            wv = w4[r * 16 + sub * 2];
            a0.x += et * tv0.x * wv.x; a0.y += et * tv0.y * wv.y;
            a0.z += et * tv0.z * wv.z; a0.w += et * tv0.w * wv.w;
            wv = w4[r * 16 + sub * 2 + 1];
            a1.x += et * tv1.x * wv.x; a1.y += et * tv1.y * wv.y;
            a1.z += et * tv1.z * wv.z; a1.w += et * tv1.w * wv.w;
        }
        float inv = 1.0f / (dt * (float)(end - beg));
        a0.x *= inv; a0.y *= inv; a0.z *= inv; a0.w *= inv;
        a1.x *= inv; a1.y *= inv; a1.z *= inv; a1.w *= inv;
        o4[h * 16 + sub * 2] = a0;
        o4[h * 16 + sub * 2 + 1] = a1;
    } else {
        int u = key - N_ENT;
        float4 a0 = z, a1 = z;
        unsigned i = beg;
        for (; i + 2 <= end; i += 2) {
            unsigned p0 = csr[i], p1 = csr[i + 1];
            int c0 = p0 & 0x3FFFF, c1 = p1 & 0x3FFFF;
            float v0 = (float)(p0 >> 18) * INV_Q14;
            float v1 = (float)(p1 >> 18) * INV_Q14;
            float4 tv00, tv01, tv10, tv11;
            if (FAST) {
                uint4 tb0 = entb[c0 * 8 + sub];
                uint4 tb1 = entb[c1 * 8 + sub];
                tv00 = bf4lo(tb0); tv01 = bf4hi(tb0);
                tv10 = bf4lo(tb1); tv11 = bf4hi(tb1);
            } else {
                tv00 = e4[c0 * 16 + sub * 2]; tv01 = e4[c0 * 16 + sub * 2 + 1];
                tv10 = e4[c1 * 16 + sub * 2]; tv11 = e4[c1 * 16 + sub * 2 + 1];
            }
            a0.x += v0 * tv00.x + v1 * tv10.x; a0.y += v0 * tv00.y + v1 * tv10.y;
            a0.z += v0 * tv00.z + v1 * tv10.z; a0.w += v0 * tv00.w + v1 * tv10.w;
            a1.x += v0 * tv01.x + v1 * tv11.x; a1.y += v0 * tv01.y + v1 * tv11.y;
            a1.z += v0 * tv01.z + v1 * tv11.z; a1.w += v0 * tv01.w + v1 * tv11.w;
        }
        if (i < end) {
            unsigned p = csr[i];
            int c = p & 0x3FFFF;
            float v = (float)(p >> 18) * INV_Q14;
            float4 tv0, tv1;
            if (FAST) {
                uint4 tb = entb[c * 8 + sub];
                tv0 = bf4lo(tb); tv1 = bf4hi(tb);
            } else {
                tv0 = e4[c * 16 + sub * 2]; tv1 = e4[c * 16 + sub * 2 + 1];
            }
            a0.x += v * tv0.x; a0.y += v * tv0.y; a0.z += v * tv0.z; a0.w += v * tv0.w;
            a1.x += v * tv1.x; a1.y += v * tv1.y; a1.z += v * tv1.z; a1.w += v * tv1.w;
        }
        // epilogue: *(1 + softmax(uemb@lat^T) @ disen)
        float4 uv0 = ((const float4*)uemb)[u * 16 + sub * 2];
        float4 uv1 = ((const float4*)uemb)[u * 16 + sub * 2 + 1];
        float d[N_FACTORS];
        for (int f = 0; f < N_FACTORS; ++f) {
            float t = dot4(uv0, ((const float4*)lat)[f * 16 + sub * 2]) +
                      dot4(uv1, ((const float4*)lat)[f * 16 + sub * 2 + 1]);
            d[f] = red8(t);
        }
        float m = fmaxf(fmaxf(d[0], d[1]), fmaxf(d[2], d[3]));
        float s = 0.f, p_[N_FACTORS];
        for (int f = 0; f < N_FACTORS; ++f) { p_[f] = __expf(d[f] - m); s += p_[f]; }
        float invs = 1.0f / s;
        float4 g0 = z, g1 = z;
        for (int f = 0; f < N_FACTORS; ++f) {
            float w = p_[f] * invs;
            float4 dv = ((const float4*)disen)[f * 16 + sub * 2];
            g0.x += w * dv.x; g0.y += w * dv.y; g0.z += w * dv.z; g0.w += w * dv.w;
            dv = ((const float4*)disen)[f * 16 + sub * 2 + 1];
            g1.x += w * dv.x; g1.y += w * dv.y; g1.z += w * dv.z; g1.w += w * dv.w;
        }
        a0.x *= (1.0f + g0.x); a0.y *= (1.0f + g0.y);
        a0.z *= (1.0f + g0.z); a0.w *= (1.0f + g0.w);
        a1.x *= (1.0f + g1.x); a1.y *= (1.0f + g1.y);
        a1.z *= (1.0f + g1.z); a1.w *= (1.0f + g1.w);
        o4[key * 16 + sub * 2] = a0;
        o4[key * 16 + sub * 2 + 1] = a1;
    }
}

extern "C" void kernel_launch(void* const* d_in, const int* in_sizes, int n_in,
                              void* d_out, int out_size, void* d_ws, size_t ws_size,
                              hipStream_t stream) {
    (void)in_sizes; (void)n_in; (void)out_size;
    const float* ent    = (const float*)d_in[0];
    const float* uemb   = (const float*)d_in[1];
    const float* lat    = (const float*)d_in[2];
    const int*   eidx   = (const int*)d_in[3];
    const int*   etype  = (const int*)d_in[4];
    const int*   urows  = (const int*)d_in[5];
    const int*   ucols  = (const int*)d_in[6];
    const float* uvals  = (const float*)d_in[7];
    const float* weight = (const float*)d_in[8];
    const float* datt   = (const float*)d_in[9];
    const float* W      = (const float*)d_in[10];

    const int* head = eidx;
    const int* tail = eidx + N_EDGES;
    float* out = (float*)d_out;

    // ws layout (4B words)
    unsigned* cnt   = (unsigned*)d_ws;            // 300000 (becomes kcur)
    unsigned* offs  = cnt + NKEY;                 // 300001
    unsigned* part  = offs + (NKEY + 1);          // 1024 (586 used)
    unsigned* gcur  = part + 1024;                // 160 (147 used)
    float*    Mvec  = (float*)(gcur + 160);       // 1600
    float*    wnorm = Mvec + NREL1 * 64;          // 32
    float*    disen = wnorm + 32;                 // 256
    unsigned* csr   = (unsigned*)(disen + N_FACTORS * 64);  // 2M
    unsigned* skey  = csr + NREC;                 // 2M (fast only)
    unsigned* spay  = skey + NREC;                // 2M (fast only)
    unsigned* entb  = spay + NREC;                // 6.4M words bf16 table (fast only)
    // E-table aliases skey/spay (used only after binplace_k is done)
    unsigned short* E16 = (unsigned short*)skey;  // 5M shorts = 10MB <= 16MB

    size_t base_words = (size_t)(skey - cnt);
    size_t need_fast  = (base_words + 2 * (size_t)NREC + (size_t)N_ENT * 32) * 4;
    bool fast = ws_size >= need_fast;

    const int BLK = 256;
    const int NBLK512 = (NKEY + 511) / 512;       // 586

    hipMemsetAsync(d_ws, 0, (size_t)NKEY * 4, stream);

    precompute_k<<<1, 256, 0, stream>>>(W, weight, datt, Mvec, wnorm, disen);
    if (fast) conv_k<<<(N_ENT * 8 + BLK - 1) / BLK, BLK, 0, stream>>>(ent, entb);
    count2_k<<<(NREC + BLK - 1) / BLK, BLK, 0, stream>>>(head, urows, cnt);
    block_sums512_k<<<NBLK512, 512, 0, stream>>>(cnt, part);
    scan1024_k<<<1, 1024, 0, stream>>>(part, NBLK512);
    scan_emit512_k<<<NBLK512, 512, 0, stream>>>(cnt, part, offs);

    if (fast) {
        gcur_init_k<<<1, 256, 0, stream>>>(offs, gcur);
        binfill_k<<<(NREC + TILE - 1) / TILE, BLK, 0, stream>>>(
            head, tail, etype, urows, ucols, uvals, gcur, skey, spay);
        binplace_k<<<NBUCKET, BLK, 0, stream>>>(offs, cnt, skey, spay, csr);
        e_table_k<<<(N_ENT * 8 + BLK - 1) / BLK, BLK, 0, stream>>>(ent, Mvec, E16);
        gather8_k<true><<<(NKEY * 8 + BLK - 1) / BLK, BLK, 0, stream>>>(
            ent, (const uint4*)entb, E16, weight, Mvec, wnorm,
            uemb, lat, disen, offs, csr, out);
    } else {
        fill_direct_k<<<(NREC + BLK - 1) / BLK, BLK, 0, stream>>>(
            head, tail, etype, urows, ucols, uvals, cnt, csr);
        gather8_k<false><<<(NKEY * 8 + BLK - 1) / BLK, BLK, 0, stream>>>(
            ent, (const uint4*)entb, E16, weight, Mvec, wnorm,
            uemb, lat, disen, offs, csr, out);
    }
}

// Round 9
// 224.502 us; speedup vs baseline: 1.8637x; 1.7443x over previous
//
#include <hip/hip_runtime.h>
#include <math.h>

#define N_ENT 200000
#define N_USERS 100000
#define NKEY 300000            // N_ENT + N_USERS unified key space
#define N_FACTORS 4
#define NREL1 25               // N_REL - 1
#define CH 64
#define N_EDGES 1000000
#define NNZ 1000000
#define NREC 2000000           // N_EDGES + NNZ unified records
#define BSHIFT 11
#define BKEYS 2048
#define NBUCKET 147            // ceil(NKEY / 2048)
#define TILE 2048
// Per-bucket staging capacity. Entity buckets: mean 2048*5=10240 (sigma~100).
// User buckets: mean 2048*10=20480 (sigma~142). 24576 = user mean + ~29 sigma.
#define CAP 24576

// 1 / (2*sqrt(32))
#define SCORE_SCALE 0.08838834764831845f
#define INV_Q14 6.103888176768602e-05f   // 1/16383

__device__ __forceinline__ float red8(float d) {
    d += __shfl_xor(d, 1);
    d += __shfl_xor(d, 2);
    d += __shfl_xor(d, 4);
    return d;
}
__device__ __forceinline__ float dot4(float4 a, float4 b) {
    return a.x * b.x + a.y * b.y + a.z * b.z + a.w * b.w;
}
__device__ __forceinline__ unsigned short f2bf(float f) {   // RNE
    unsigned u = __float_as_uint(f);
    u += 0x7FFFu + ((u >> 16) & 1u);
    return (unsigned short)(u >> 16);
}
__device__ __forceinline__ float bf2f(unsigned short u) {
    return __uint_as_float(((unsigned)u) << 16);
}
__device__ __forceinline__ float4 bf4lo(uint4 t) {
    return make_float4(__uint_as_float(t.x << 16), __uint_as_float(t.x & 0xFFFF0000u),
                       __uint_as_float(t.y << 16), __uint_as_float(t.y & 0xFFFF0000u));
}
__device__ __forceinline__ float4 bf4hi(uint4 t) {
    return make_float4(__uint_as_float(t.z << 16), __uint_as_float(t.z & 0xFFFF0000u),
                       __uint_as_float(t.w << 16), __uint_as_float(t.w & 0xFFFF0000u));
}

// ---- tiny precompute: Mvec[r] = (W W^T) weight[r]; wnorm[r]; disen[f][c] ----
__global__ void precompute_k(const float* __restrict__ W,
                             const float* __restrict__ weight,
                             const float* __restrict__ datt,
                             float* __restrict__ Mvec,
                             float* __restrict__ wnorm,
                             float* __restrict__ disen) {
    __shared__ float sW[64 * 64];
    __shared__ float sw[NREL1 * 64];
    __shared__ float sWWt[64 * 64];
    int tid = threadIdx.x;
    for (int i = tid; i < 64 * 64; i += 256) sW[i] = W[i];
    for (int i = tid; i < NREL1 * 64; i += 256) sw[i] = weight[i];
    __syncthreads();
    for (int e = tid; e < 64 * 64; e += 256) {
        int i = e >> 6, j = e & 63;
        float s = 0.f;
        for (int k = 0; k < 64; ++k) s += sW[i * 64 + k] * sW[j * 64 + k];
        sWWt[e] = s;
    }
    __syncthreads();
    for (int e = tid; e < NREL1 * 64; e += 256) {
        int r = e >> 6, i = e & 63;
        float s = 0.f;
        for (int j = 0; j < 64; ++j) s += sWWt[i * 64 + j] * sw[r * 64 + j];
        Mvec[e] = s;
    }
    for (int r = tid; r < NREL1; r += 256) {
        float s = 0.f;
        for (int j = 0; j < 64; ++j) { float v = sw[r * 64 + j]; s += v * v; }
        wnorm[r] = s;
    }
    for (int e = tid; e < N_FACTORS * 64; e += 256) {
        int f = e >> 6, c = e & 63;
        float m = -1e30f;
        for (int r = 0; r < NREL1; ++r) m = fmaxf(m, datt[f * NREL1 + r]);
        float ssum = 0.f, acc = 0.f;
        for (int r = 0; r < NREL1; ++r) {
            float p = expf(datt[f * NREL1 + r] - m);
            ssum += p;
            acc += p * sw[r * 64 + c];
        }
        disen[e] = acc / ssum;
    }
}

// ---- gcur init: staging cursor starts at b*CAP ----
__global__ void gcur_init2_k(unsigned* __restrict__ gcur) {
    int b = threadIdx.x;
    if (b < NBUCKET) gcur[b] = (unsigned)b * CAP;
}

// ---- stage 1: LDS-binned scatter into fixed-capacity staging buckets ----
__global__ void binfill_k(const int* __restrict__ head, const int* __restrict__ tail,
                          const int* __restrict__ etype,
                          const int* __restrict__ rows, const int* __restrict__ cols,
                          const float* __restrict__ vals,
                          unsigned* __restrict__ gcur,
                          uint2* __restrict__ stg) {
    __shared__ unsigned hist[NBUCKET], base[NBUCKET], gbase[NBUCKET];
    __shared__ unsigned sh[256];
    __shared__ uint2 lrec[TILE];
    int tid = threadIdx.x;
    int tile0 = blockIdx.x * TILE;
    int tile_n = min(TILE, NREC - tile0);
    for (int b = tid; b < NBUCKET; b += 256) hist[b] = 0u;
    __syncthreads();
    unsigned key[8], pay[8], rank[8];
    for (int r = 0; r < 8; ++r) {
        int li = r * 256 + tid;
        key[r] = 0xFFFFFFFFu;
        if (li < tile_n) {
            int idx = tile0 + li;
            unsigned k, p;
            if (idx < N_EDGES) {
                k = (unsigned)head[idx];
                p = (unsigned)tail[idx] | ((unsigned)(etype[idx] - 1) << 18);
            } else {
                int j = idx - N_EDGES;
                k = (unsigned)(N_ENT + rows[j]);
                unsigned q = (unsigned)(vals[j] * 16383.f + 0.5f);
                p = (unsigned)cols[j] | (q << 18);
            }
            key[r] = k; pay[r] = p;
            rank[r] = atomicAdd(&hist[k >> BSHIFT], 1u);
        }
    }
    __syncthreads();
    unsigned v = (tid < NBUCKET) ? hist[tid] : 0u;
    sh[tid] = v; __syncthreads();
    for (int o = 1; o < 256; o <<= 1) {
        unsigned t = (tid >= o) ? sh[tid - o] : 0u;
        __syncthreads();
        sh[tid] += t;
        __syncthreads();
    }
    if (tid < NBUCKET) {
        base[tid] = sh[tid] - v;
        gbase[tid] = v ? atomicAdd(&gcur[tid], v) : 0u;
    }
    __syncthreads();
    for (int r = 0; r < 8; ++r) {
        if (key[r] != 0xFFFFFFFFu) {
            unsigned b = key[r] >> BSHIFT;
            unsigned pos = base[b] + rank[r];
            lrec[pos] = make_uint2(key[r], pay[r]);
        }
    }
    __syncthreads();
    // burst copy: consecutive LDS indices -> consecutive staging addresses per run
    for (int i = tid; i < tile_n; i += 256) {
        uint2 rec = lrec[i];
        unsigned b = rec.x >> BSHIFT;
        unsigned dst = gbase[b] + ((unsigned)i - base[b]);
        if (dst < (b + 1u) * CAP) stg[dst] = rec;   // overflow guard (never fires)
    }
}

// ---- bucket totals -> exclusive scan -> bucket bases ----
__global__ void bucket_scan_k(const unsigned* __restrict__ gcur,
                              unsigned* __restrict__ bbase,
                              unsigned* __restrict__ offs) {
    __shared__ unsigned s[256];
    int tid = threadIdx.x;
    unsigned c = (tid < NBUCKET) ? (gcur[tid] - (unsigned)tid * CAP) : 0u;
    if (c > CAP) c = CAP;                 // paranoia: overflow clamp
    unsigned v = c;
    s[tid] = v; __syncthreads();
    for (int o = 1; o < 256; o <<= 1) {
        unsigned t = (tid >= o) ? s[tid - o] : 0u;
        __syncthreads();
        s[tid] += t;
        __syncthreads();
    }
    if (tid < NBUCKET) bbase[tid] = s[tid] - v;
    if (tid == 0) offs[NKEY] = NREC;
}

// ---- stage 2: per-bucket LDS count+scan -> offs[] + place records ----
__global__ void binplace2_k(const uint2* __restrict__ stg,
                            const unsigned* __restrict__ gcur,
                            const unsigned* __restrict__ bbase,
                            unsigned* __restrict__ offs,
                            unsigned* __restrict__ csr) {
    __shared__ unsigned cnt[BKEYS];     // 8 KB
    __shared__ unsigned sc[1024];
    int b = blockIdx.x;
    int tid = threadIdx.x;
    unsigned n = gcur[b] - (unsigned)b * CAP;
    if (n > CAP) n = CAP;               // paranoia: overflow clamp
    unsigned gb = bbase[b];
    const uint2* seg = stg + (size_t)b * CAP;
    cnt[tid * 2] = 0u; cnt[tid * 2 + 1] = 0u;
    __syncthreads();
    for (unsigned i = tid; i < n; i += 1024) {
        unsigned kk = seg[i].x - ((unsigned)b << BSHIFT);
        atomicAdd(&cnt[kk], 1u);
    }
    __syncthreads();
    unsigned c0 = cnt[tid * 2], c1 = cnt[tid * 2 + 1];
    unsigned tsum = c0 + c1;
    sc[tid] = tsum; __syncthreads();
    for (int o = 1; o < 1024; o <<= 1) {
        unsigned t = (tid >= o) ? sc[tid - o] : 0u;
        __syncthreads();
        sc[tid] += t;
        __syncthreads();
    }
    unsigned e0 = sc[tid] - tsum;
    unsigned e1 = e0 + c0;
    int k0 = (b << BSHIFT) + tid * 2;
    if (k0 < NKEY)     offs[k0]     = gb + e0;
    if (k0 + 1 < NKEY) offs[k0 + 1] = gb + e1;
    cnt[tid * 2] = e0; cnt[tid * 2 + 1] = e1;
    __syncthreads();
    for (unsigned i = tid; i < n; i += 1024) {
        uint2 rec = seg[i];
        unsigned kk = rec.x - ((unsigned)b << BSHIFT);
        unsigned pos = atomicAdd(&cnt[kk], 1u);
        csr[gb + pos] = rec.y;
    }
}

// ---- fused: bf16 entity shadow + E-table (one streaming pass over ent) ----
__global__ void convE_k(const float* __restrict__ ent,
                        const float* __restrict__ Mvec,
                        uint4* __restrict__ entb,
                        unsigned short* __restrict__ E16) {
    __shared__ float4 sM[NREL1 * 16];
    int tid = threadIdx.x;
    for (int i = tid; i < NREL1 * 16; i += 256) sM[i] = ((const float4*)Mvec)[i];
    __syncthreads();
    int gid = blockIdx.x * 256 + tid;
    int h = gid >> 3;
    int sub = tid & 7;
    if (h >= N_ENT) return;
    const float4* e4 = (const float4*)ent;
    float4 a = e4[h * 16 + sub * 2], b4 = e4[h * 16 + sub * 2 + 1];
    uint4 o;
    o.x = (unsigned)f2bf(a.x)  | ((unsigned)f2bf(a.y)  << 16);
    o.y = (unsigned)f2bf(a.z)  | ((unsigned)f2bf(a.w)  << 16);
    o.z = (unsigned)f2bf(b4.x) | ((unsigned)f2bf(b4.y) << 16);
    o.w = (unsigned)f2bf(b4.z) | ((unsigned)f2bf(b4.w) << 16);
    entb[h * 8 + sub] = o;
    for (int r = 0; r < NREL1; ++r) {
        float d = dot4(a, sM[r * 16 + sub * 2]) + dot4(b4, sM[r * 16 + sub * 2 + 1]);
        d = red8(d);
        if (sub == (r & 7)) E16[h * NREL1 + r] = f2bf(__expf(d * SCORE_SCALE));
    }
}

// ---- fused gather: 8 lanes per key; entities then users (unified key space) ----
template<bool FAST>   // FAST: bf16 entb gathers + E-table; else fp32 + on-the-fly Mvec
__global__ void gather8_k(const float* __restrict__ ent,
                          const uint4* __restrict__ entb,
                          const unsigned short* __restrict__ E16,
                          const float* __restrict__ weight,
                          const float* __restrict__ Mvec,
                          const float* __restrict__ wnorm,
                          const float* __restrict__ uemb,
                          const float* __restrict__ lat,
                          const float* __restrict__ disen,
                          const unsigned* __restrict__ offs,
                          const unsigned* __restrict__ csr,
                          float* __restrict__ out) {
    int gid = blockIdx.x * 256 + threadIdx.x;
    int key = gid >> 3;
    int sub = threadIdx.x & 7;
    if (key >= NKEY) return;
    unsigned beg = offs[key], end = offs[key + 1];
    const float4* e4 = (const float4*)ent;
    const float4* w4 = (const float4*)weight;
    float4* o4 = (float4*)out;
    const float4 z = make_float4(0.f, 0.f, 0.f, 0.f);

    if (key < N_ENT) {
        int h = key;
        if (beg == end) {
            o4[h * 16 + sub * 2] = z;
            o4[h * 16 + sub * 2 + 1] = z;
            return;
        }
        float4 hv0 = e4[h * 16 + sub * 2], hv1 = e4[h * 16 + sub * 2 + 1];
        float dr = 0.f;
        if (FAST) {
            for (unsigned i = beg + sub; i < end; i += 8)
                dr += bf2f(E16[h * NREL1 + (csr[i] >> 18)]);
            dr = red8(dr);
        } else {
            for (unsigned i = beg; i < end; ++i) {
                int r = csr[i] >> 18;
                float d = dot4(hv0, ((const float4*)Mvec)[r * 16 + sub * 2]) +
                          dot4(hv1, ((const float4*)Mvec)[r * 16 + sub * 2 + 1]);
                dr += __expf(red8(d) * SCORE_SCALE);
            }
        }
        float inv_dr = 1.0f / dr;
        float4 a0 = z, a1 = z;
        float dt = 0.f;
        unsigned i = beg;
        for (; i + 2 <= end; i += 2) {
            unsigned p0 = csr[i], p1 = csr[i + 1];
            int t0 = p0 & 0x3FFFF, r0 = p0 >> 18;
            int t1 = p1 & 0x3FFFF, r1 = p1 >> 18;
            float4 tv00, tv01, tv10, tv11;
            if (FAST) {
                uint4 tb0 = entb[t0 * 8 + sub];
                uint4 tb1 = entb[t1 * 8 + sub];
                tv00 = bf4lo(tb0); tv01 = bf4hi(tb0);
                tv10 = bf4lo(tb1); tv11 = bf4hi(tb1);
            } else {
                tv00 = e4[t0 * 16 + sub * 2]; tv01 = e4[t0 * 16 + sub * 2 + 1];
                tv10 = e4[t1 * 16 + sub * 2]; tv11 = e4[t1 * 16 + sub * 2 + 1];
            }
            float d0 = red8(dot4(hv0, tv00) + dot4(hv1, tv01));
            float d1 = red8(dot4(hv0, tv10) + dot4(hv1, tv11));
            float er0, er1;
            if (FAST) {
                er0 = bf2f(E16[h * NREL1 + r0]);
                er1 = bf2f(E16[h * NREL1 + r1]);
            } else {
                float q0 = dot4(hv0, ((const float4*)Mvec)[r0 * 16 + sub * 2]) +
                           dot4(hv1, ((const float4*)Mvec)[r0 * 16 + sub * 2 + 1]);
                float q1 = dot4(hv0, ((const float4*)Mvec)[r1 * 16 + sub * 2]) +
                           dot4(hv1, ((const float4*)Mvec)[r1 * 16 + sub * 2 + 1]);
                er0 = __expf(red8(q0) * SCORE_SCALE);
                er1 = __expf(red8(q1) * SCORE_SCALE);
            }
            float ra0 = er0 * inv_dr, ra1 = er1 * inv_dr;
            float et0 = __expf(d0 + ra0 * ra0 * wnorm[r0]);
            float et1 = __expf(d1 + ra1 * ra1 * wnorm[r1]);
            dt += et0 + et1;
            float4 wv;
            wv = w4[r0 * 16 + sub * 2];
            a0.x += et0 * tv00.x * wv.x; a0.y += et0 * tv00.y * wv.y;
            a0.z += et0 * tv00.z * wv.z; a0.w += et0 * tv00.w * wv.w;
            wv = w4[r0 * 16 + sub * 2 + 1];
            a1.x += et0 * tv01.x * wv.x; a1.y += et0 * tv01.y * wv.y;
            a1.z += et0 * tv01.z * wv.z; a1.w += et0 * tv01.w * wv.w;
            wv = w4[r1 * 16 + sub * 2];
            a0.x += et1 * tv10.x * wv.x; a0.y += et1 * tv10.y * wv.y;
            a0.z += et1 * tv10.z * wv.z; a0.w += et1 * tv10.w * wv.w;
            wv = w4[r1 * 16 + sub * 2 + 1];
            a1.x += et1 * tv11.x * wv.x; a1.y += et1 * tv11.y * wv.y;
            a1.z += et1 * tv11.z * wv.z; a1.w += et1 * tv11.w * wv.w;
        }
        if (i < end) {
            unsigned p = csr[i];
            int t = p & 0x3FFFF, r = p >> 18;
            float4 tv0, tv1;
            if (FAST) {
                uint4 tb = entb[t * 8 + sub];
                tv0 = bf4lo(tb); tv1 = bf4hi(tb);
            } else {
                tv0 = e4[t * 16 + sub * 2]; tv1 = e4[t * 16 + sub * 2 + 1];
            }
            float d = red8(dot4(hv0, tv0) + dot4(hv1, tv1));
            float er;
            if (FAST) {
                er = bf2f(E16[h * NREL1 + r]);
            } else {
                float q = dot4(hv0, ((const float4*)Mvec)[r * 16 + sub * 2]) +
                          dot4(hv1, ((const float4*)Mvec)[r * 16 + sub * 2 + 1]);
                er = __expf(red8(q) * SCORE_SCALE);
            }
            float ra = er * inv_dr;
            float et = __expf(d + ra * ra * wnorm[r]);
            dt += et;
            float4 wv;
            wv = w4[r * 16 + sub * 2];
            a0.x += et * tv0.x * wv.x; a0.y += et * tv0.y * wv.y;
            a0.z += et * tv0.z * wv.z; a0.w += et * tv0.w * wv.w;
            wv = w4[r * 16 + sub * 2 + 1];
            a1.x += et * tv1.x * wv.x; a1.y += et * tv1.y * wv.y;
            a1.z += et * tv1.z * wv.z; a1.w += et * tv1.w * wv.w;
        }
        float inv = 1.0f / (dt * (float)(end - beg));
        a0.x *= inv; a0.y *= inv; a0.z *= inv; a0.w *= inv;
        a1.x *= inv; a1.y *= inv; a1.z *= inv; a1.w *= inv;
        o4[h * 16 + sub * 2] = a0;
        o4[h * 16 + sub * 2 + 1] = a1;
    } else {
        int u = key - N_ENT;
        float4 a0 = z, a1 = z;
        unsigned i = beg;
        for (; i + 2 <= end; i += 2) {
            unsigned p0 = csr[i], p1 = csr[i + 1];
            int c0 = p0 & 0x3FFFF, c1 = p1 & 0x3FFFF;
            float v0 = (float)(p0 >> 18) * INV_Q14;
            float v1 = (float)(p1 >> 18) * INV_Q14;
            float4 tv00, tv01, tv10, tv11;
            if (FAST) {
                uint4 tb0 = entb[c0 * 8 + sub];
                uint4 tb1 = entb[c1 * 8 + sub];
                tv00 = bf4lo(tb0); tv01 = bf4hi(tb0);
                tv10 = bf4lo(tb1); tv11 = bf4hi(tb1);
            } else {
                tv00 = e4[c0 * 16 + sub * 2]; tv01 = e4[c0 * 16 + sub * 2 + 1];
                tv10 = e4[c1 * 16 + sub * 2]; tv11 = e4[c1 * 16 + sub * 2 + 1];
            }
            a0.x += v0 * tv00.x + v1 * tv10.x; a0.y += v0 * tv00.y + v1 * tv10.y;
            a0.z += v0 * tv00.z + v1 * tv10.z; a0.w += v0 * tv00.w + v1 * tv10.w;
            a1.x += v0 * tv01.x + v1 * tv11.x; a1.y += v0 * tv01.y + v1 * tv11.y;
            a1.z += v0 * tv01.z + v1 * tv11.z; a1.w += v0 * tv01.w + v1 * tv11.w;
        }
        if (i < end) {
            unsigned p = csr[i];
            int c = p & 0x3FFFF;
            float v = (float)(p >> 18) * INV_Q14;
            float4 tv0, tv1;
            if (FAST) {
                uint4 tb = entb[c * 8 + sub];
                tv0 = bf4lo(tb); tv1 = bf4hi(tb);
            } else {
                tv0 = e4[c * 16 + sub * 2]; tv1 = e4[c * 16 + sub * 2 + 1];
            }
            a0.x += v * tv0.x; a0.y += v * tv0.y; a0.z += v * tv0.z; a0.w += v * tv0.w;
            a1.x += v * tv1.x; a1.y += v * tv1.y; a1.z += v * tv1.z; a1.w += v * tv1.w;
        }
        float4 uv0 = ((const float4*)uemb)[u * 16 + sub * 2];
        float4 uv1 = ((const float4*)uemb)[u * 16 + sub * 2 + 1];
        float d[N_FACTORS];
        for (int f = 0; f < N_FACTORS; ++f) {
            float t = dot4(uv0, ((const float4*)lat)[f * 16 + sub * 2]) +
                      dot4(uv1, ((const float4*)lat)[f * 16 + sub * 2 + 1]);
            d[f] = red8(t);
        }
        float m = fmaxf(fmaxf(d[0], d[1]), fmaxf(d[2], d[3]));
        float s = 0.f, p_[N_FACTORS];
        for (int f = 0; f < N_FACTORS; ++f) { p_[f] = __expf(d[f] - m); s += p_[f]; }
        float invs = 1.0f / s;
        float4 g0 = z, g1 = z;
        for (int f = 0; f < N_FACTORS; ++f) {
            float w = p_[f] * invs;
            float4 dv = ((const float4*)disen)[f * 16 + sub * 2];
            g0.x += w * dv.x; g0.y += w * dv.y; g0.z += w * dv.z; g0.w += w * dv.w;
            dv = ((const float4*)disen)[f * 16 + sub * 2 + 1];
            g1.x += w * dv.x; g1.y += w * dv.y; g1.z += w * dv.z; g1.w += w * dv.w;
        }
        a0.x *= (1.0f + g0.x); a0.y *= (1.0f + g0.y);
        a0.z *= (1.0f + g0.z); a0.w *= (1.0f + g0.w);
        a1.x *= (1.0f + g1.x); a1.y *= (1.0f + g1.y);
        a1.z *= (1.0f + g1.z); a1.w *= (1.0f + g1.w);
        o4[key * 16 + sub * 2] = a0;
        o4[key * 16 + sub * 2 + 1] = a1;
    }
}

extern "C" void kernel_launch(void* const* d_in, const int* in_sizes, int n_in,
                              void* d_out, int out_size, void* d_ws, size_t ws_size,
                              hipStream_t stream) {
    (void)in_sizes; (void)n_in; (void)out_size;
    const float* ent    = (const float*)d_in[0];
    const float* uemb   = (const float*)d_in[1];
    const float* lat    = (const float*)d_in[2];
    const int*   eidx   = (const int*)d_in[3];
    const int*   etype  = (const int*)d_in[4];
    const int*   urows  = (const int*)d_in[5];
    const int*   ucols  = (const int*)d_in[6];
    const float* uvals  = (const float*)d_in[7];
    const float* weight = (const float*)d_in[8];
    const float* datt   = (const float*)d_in[9];
    const float* W      = (const float*)d_in[10];

    const int* head = eidx;
    const int* tail = eidx + N_EDGES;
    float* out = (float*)d_out;

    // ws layout (4B words). offs padded to NKEY+2 so 'big' starts 8B-aligned.
    unsigned* gcur  = (unsigned*)d_ws;            // 256 (147 used)
    unsigned* bbase = gcur + 256;                 // 256
    unsigned* offs  = bbase + 256;                // NKEY+2 (offs[NKEY] used, +1 pad)
    float*    Mvec  = (float*)(offs + NKEY + 2);  // 1600
    float*    wnorm = Mvec + NREL1 * 64;          // 32
    float*    disen = wnorm + 32;                 // 256
    unsigned* csr   = (unsigned*)(disen + N_FACTORS * 64);   // 2M
    unsigned* big   = csr + NREC;                 // union region (8B aligned)
    uint2*    stg   = (uint2*)big;                // 147*CAP uint2 = 7.23M words
    unsigned* entb  = big;                        // N_ENT*32 = 6.4M words bf16 rows
    // E16 AFTER the full entb: entb rows are 64 bf16 = 32 words each (R7/R8 bug:
    // used N_ENT*16 -> E16 overlapped entb's upper half -> corrupted -> NaN)
    unsigned short* E16 = (unsigned short*)(entb + (size_t)N_ENT * 32);  // 2.5M words

    size_t base_words = 256 + 256 + (NKEY + 2) + 1888 + (size_t)NREC;
    size_t stg_words  = (size_t)NBUCKET * CAP * 2;                        // 7.23M
    size_t tbl_words  = (size_t)N_ENT * 32 + ((size_t)N_ENT * NREL1 + 1) / 2;  // 8.9M
    size_t big_words  = stg_words > tbl_words ? stg_words : tbl_words;
    size_t need_fast  = (base_words + big_words) * 4;   // ~44.8 MB
    size_t need_min   = (base_words + stg_words) * 4;   // ~38.1 MB
    bool fast = ws_size >= need_fast;
    if (ws_size < need_min) return;   // cannot run (never in practice)

    const int BLK = 256;

    gcur_init2_k<<<1, 256, 0, stream>>>(gcur);
    precompute_k<<<1, 256, 0, stream>>>(W, weight, datt, Mvec, wnorm, disen);
    binfill_k<<<(NREC + TILE - 1) / TILE, BLK, 0, stream>>>(
        head, tail, etype, urows, ucols, uvals, gcur, stg);
    bucket_scan_k<<<1, 256, 0, stream>>>(gcur, bbase, offs);
    binplace2_k<<<NBUCKET, 1024, 0, stream>>>(stg, gcur, bbase, offs, csr);

    int gridG = (NKEY * 8 + BLK - 1) / BLK;
    if (fast) {
        convE_k<<<(N_ENT * 8 + BLK - 1) / BLK, BLK, 0, stream>>>(
            ent, Mvec, (uint4*)entb, E16);
        gather8_k<true><<<gridG, BLK, 0, stream>>>(
            ent, (const uint4*)entb, E16, weight, Mvec, wnorm,
            uemb, lat, disen, offs, csr, out);
    } else {
        gather8_k<false><<<gridG, BLK, 0, stream>>>(
            ent, (const uint4*)entb, E16, weight, Mvec, wnorm,
            uemb, lat, disen, offs, csr, out);
    }
}

// Round 11
// 203.677 us; speedup vs baseline: 2.0543x; 1.1022x over previous
//
#include <hip/hip_runtime.h>
#include <math.h>

#define N_ENT 200000
#define N_USERS 100000
#define NKEY 300000            // N_ENT + N_USERS unified key space
#define N_FACTORS 4
#define NREL1 25               // N_REL - 1
#define CH 64
#define N_EDGES 1000000
#define NNZ 1000000
#define NREC 2000000           // N_EDGES + NNZ unified records
#define BSHIFT 11
#define BKEYS 2048
#define NBUCKET 147            // ceil(NKEY / 2048)
#define TILE 2048
// Per-bucket staging capacity. Entity buckets: mean 2048*5=10240 (sigma~100).
// User buckets: mean 2048*10=20480 (sigma~142). 24576 = user mean + ~29 sigma.
#define CAP 24576
#define NCONVB ((N_ENT * 8 + 1023) / 1024)   // 1563 conv-role blocks

// 1 / (2*sqrt(32))
#define SCORE_SCALE 0.08838834764831845f
#define INV_Q14 6.103888176768602e-05f   // 1/16383

__device__ __forceinline__ float red8(float d) {
    d += __shfl_xor(d, 1);
    d += __shfl_xor(d, 2);
    d += __shfl_xor(d, 4);
    return d;
}
__device__ __forceinline__ float dot4(float4 a, float4 b) {
    return a.x * b.x + a.y * b.y + a.z * b.z + a.w * b.w;
}
__device__ __forceinline__ unsigned short f2bf(float f) {   // RNE
    unsigned u = __float_as_uint(f);
    u += 0x7FFFu + ((u >> 16) & 1u);
    return (unsigned short)(u >> 16);
}
__device__ __forceinline__ float bf2f(unsigned short u) {
    return __uint_as_float(((unsigned)u) << 16);
}
__device__ __forceinline__ float4 bf4lo(uint4 t) {
    return make_float4(__uint_as_float(t.x << 16), __uint_as_float(t.x & 0xFFFF0000u),
                       __uint_as_float(t.y << 16), __uint_as_float(t.y & 0xFFFF0000u));
}
__device__ __forceinline__ float4 bf4hi(uint4 t) {
    return make_float4(__uint_as_float(t.z << 16), __uint_as_float(t.z & 0xFFFF0000u),
                       __uint_as_float(t.w << 16), __uint_as_float(t.w & 0xFFFF0000u));
}

// ---- tiny precompute: Mvec[r] = (W W^T) weight[r]; wnorm[r]; disen[f][c] ----
__global__ void precompute_k(const float* __restrict__ W,
                             const float* __restrict__ weight,
                             const float* __restrict__ datt,
                             float* __restrict__ Mvec,
                             float* __restrict__ wnorm,
                             float* __restrict__ disen) {
    __shared__ float sW[64 * 64];
    __shared__ float sw[NREL1 * 64];
    __shared__ float sWWt[64 * 64];
    int tid = threadIdx.x;
    for (int i = tid; i < 64 * 64; i += 256) sW[i] = W[i];
    for (int i = tid; i < NREL1 * 64; i += 256) sw[i] = weight[i];
    __syncthreads();
    for (int e = tid; e < 64 * 64; e += 256) {
        int i = e >> 6, j = e & 63;
        float s = 0.f;
        for (int k = 0; k < 64; ++k) s += sW[i * 64 + k] * sW[j * 64 + k];
        sWWt[e] = s;
    }
    __syncthreads();
    for (int e = tid; e < NREL1 * 64; e += 256) {
        int r = e >> 6, i = e & 63;
        float s = 0.f;
        for (int j = 0; j < 64; ++j) s += sWWt[i * 64 + j] * sw[r * 64 + j];
        Mvec[e] = s;
    }
    for (int r = tid; r < NREL1; r += 256) {
        float s = 0.f;
        for (int j = 0; j < 64; ++j) { float v = sw[r * 64 + j]; s += v * v; }
        wnorm[r] = s;
    }
    for (int e = tid; e < N_FACTORS * 64; e += 256) {
        int f = e >> 6, c = e & 63;
        float m = -1e30f;
        for (int r = 0; r < NREL1; ++r) m = fmaxf(m, datt[f * NREL1 + r]);
        float ssum = 0.f, acc = 0.f;
        for (int r = 0; r < NREL1; ++r) {
            float p = expf(datt[f * NREL1 + r] - m);
            ssum += p;
            acc += p * sw[r * 64 + c];
        }
        disen[e] = acc / ssum;
    }
}

// ---- stage 1: LDS-binned scatter into fixed-capacity staging buckets ----
// gcur[b] is a pure COUNT (zeroed by memset); staging base = b*CAP + old count.
__global__ void binfill_k(const int* __restrict__ head, const int* __restrict__ tail,
                          const int* __restrict__ etype,
                          const int* __restrict__ rows, const int* __restrict__ cols,
                          const float* __restrict__ vals,
                          unsigned* __restrict__ gcur,
                          uint2* __restrict__ stg) {
    __shared__ unsigned hist[NBUCKET], base[NBUCKET], gbase[NBUCKET];
    __shared__ unsigned sh[256];
    __shared__ uint2 lrec[TILE];
    int tid = threadIdx.x;
    int tile0 = blockIdx.x * TILE;
    int tile_n = min(TILE, NREC - tile0);
    for (int b = tid; b < NBUCKET; b += 256) hist[b] = 0u;
    __syncthreads();
    unsigned key[8], pay[8], rank[8];
    for (int r = 0; r < 8; ++r) {
        int li = r * 256 + tid;
        key[r] = 0xFFFFFFFFu;
        if (li < tile_n) {
            int idx = tile0 + li;
            unsigned k, p;
            if (idx < N_EDGES) {
                k = (unsigned)head[idx];
                p = (unsigned)tail[idx] | ((unsigned)(etype[idx] - 1) << 18);
            } else {
                int j = idx - N_EDGES;
                k = (unsigned)(N_ENT + rows[j]);
                unsigned q = (unsigned)(vals[j] * 16383.f + 0.5f);
                p = (unsigned)cols[j] | (q << 18);
            }
            key[r] = k; pay[r] = p;
            rank[r] = atomicAdd(&hist[k >> BSHIFT], 1u);
        }
    }
    __syncthreads();
    unsigned v = (tid < NBUCKET) ? hist[tid] : 0u;
    sh[tid] = v; __syncthreads();
    for (int o = 1; o < 256; o <<= 1) {
        unsigned t = (tid >= o) ? sh[tid - o] : 0u;
        __syncthreads();
        sh[tid] += t;
        __syncthreads();
    }
    if (tid < NBUCKET) {
        base[tid] = sh[tid] - v;
        gbase[tid] = (unsigned)tid * CAP + (v ? atomicAdd(&gcur[tid], v) : 0u);
    }
    __syncthreads();
    for (int r = 0; r < 8; ++r) {
        if (key[r] != 0xFFFFFFFFu) {
            unsigned b = key[r] >> BSHIFT;
            unsigned pos = base[b] + rank[r];
            lrec[pos] = make_uint2(key[r], pay[r]);
        }
    }
    __syncthreads();
    // burst copy: consecutive LDS indices -> consecutive staging addresses per run
    for (int i = tid; i < tile_n; i += 256) {
        uint2 rec = lrec[i];
        unsigned b = rec.x >> BSHIFT;
        unsigned dst = gbase[b] + ((unsigned)i - base[b]);
        if (dst < (b + 1u) * CAP) stg[dst] = rec;   // overflow guard (never fires)
    }
}

// ---- device body: place one bucket (1024 threads); shm needs 3074 words ----
__device__ __forceinline__
void place_bucket_dev(int b, int tid, const uint2* __restrict__ stg,
                      const unsigned* __restrict__ gcur,
                      unsigned* __restrict__ offs, unsigned* __restrict__ csr,
                      unsigned* shm) {
    // inline bucket-base: prefix over clamped counts (147 elems in 256-scan)
    unsigned c = (tid < NBUCKET) ? gcur[tid] : 0u;
    if (c > CAP) c = CAP;
    if (tid < 256) shm[tid] = c;
    __syncthreads();
    for (int o = 1; o < 256; o <<= 1) {
        unsigned t = (tid >= o && tid < 256) ? shm[tid - o] : 0u;
        __syncthreads();
        if (tid < 256) shm[tid] += t;
        __syncthreads();
    }
    if (tid == 0) {
        unsigned cb = gcur[b]; if (cb > CAP) cb = CAP;
        shm[3073] = cb;
        shm[3072] = shm[b] - cb;                      // exclusive base
        if (b == NBUCKET - 1) offs[NKEY] = shm[NBUCKET - 1];  // grand total
    }
    __syncthreads();
    unsigned n = shm[3073], gb = shm[3072];
    const uint2* seg = stg + (size_t)b * CAP;
    // per-key count (cnt = shm[0..2047], distinct from shm[3072..3073])
    unsigned* cnt = shm;
    unsigned* sc  = shm + 2048;
    cnt[tid * 2] = 0u; cnt[tid * 2 + 1] = 0u;
    __syncthreads();
    for (unsigned i = tid; i < n; i += 1024) {
        unsigned kk = seg[i].x - ((unsigned)b << BSHIFT);
        atomicAdd(&cnt[kk], 1u);
    }
    __syncthreads();
    unsigned c0 = cnt[tid * 2], c1 = cnt[tid * 2 + 1];
    unsigned tsum = c0 + c1;
    sc[tid] = tsum; __syncthreads();
    for (int o = 1; o < 1024; o <<= 1) {
        unsigned t = (tid >= o) ? sc[tid - o] : 0u;
        __syncthreads();
        sc[tid] += t;
        __syncthreads();
    }
    unsigned e0 = sc[tid] - tsum;
    unsigned e1 = e0 + c0;
    int k0 = (b << BSHIFT) + tid * 2;
    if (k0 < NKEY)     offs[k0]     = gb + e0;
    if (k0 + 1 < NKEY) offs[k0 + 1] = gb + e1;
    cnt[tid * 2] = e0; cnt[tid * 2 + 1] = e1;
    __syncthreads();
    for (unsigned i = tid; i < n; i += 1024) {
        uint2 rec = seg[i];
        unsigned kk = rec.x - ((unsigned)b << BSHIFT);
        unsigned pos = atomicAdd(&cnt[kk], 1u);
        csr[gb + pos] = rec.y;
    }
}

// ---- device body: convE for conv-block cb (1024 threads); shm >= 1600 words ----
__device__ __forceinline__
void convE_dev(int cb, int tid, const float* __restrict__ ent,
               const float* __restrict__ Mvec,
               uint4* __restrict__ entb, unsigned short* __restrict__ E16,
               unsigned* shm) {
    float4* sM = (float4*)shm;          // NREL1*16 = 400 float4 = 1600 words
    for (int i = tid; i < NREL1 * 16; i += 1024) sM[i] = ((const float4*)Mvec)[i];
    __syncthreads();
    int idx = cb * 1024 + tid;
    int h = idx >> 3;
    int sub = tid & 7;
    if (h >= N_ENT) return;
    const float4* e4 = (const float4*)ent;
    float4 a = e4[h * 16 + sub * 2], b4 = e4[h * 16 + sub * 2 + 1];
    uint4 o;
    o.x = (unsigned)f2bf(a.x)  | ((unsigned)f2bf(a.y)  << 16);
    o.y = (unsigned)f2bf(a.z)  | ((unsigned)f2bf(a.w)  << 16);
    o.z = (unsigned)f2bf(b4.x) | ((unsigned)f2bf(b4.y) << 16);
    o.w = (unsigned)f2bf(b4.z) | ((unsigned)f2bf(b4.w) << 16);
    entb[h * 8 + sub] = o;
    for (int r = 0; r < NREL1; ++r) {
        float d = dot4(a, sM[r * 16 + sub * 2]) + dot4(b4, sM[r * 16 + sub * 2 + 1]);
        d = red8(d);
        if (sub == (r & 7)) E16[h * NREL1 + r] = f2bf(__expf(d * SCORE_SCALE));
    }
}

// ---- serial path: place only (convE follows as its own launch; stg aliasing OK) ----
__global__ void binplace3_k(const uint2* __restrict__ stg,
                            const unsigned* __restrict__ gcur,
                            unsigned* __restrict__ offs,
                            unsigned* __restrict__ csr) {
    __shared__ __align__(16) unsigned shm[3074];
    place_bucket_dev(blockIdx.x, threadIdx.x, stg, gcur, offs, csr, shm);
}

__global__ void convE2_k(const float* __restrict__ ent,
                         const float* __restrict__ Mvec,
                         uint4* __restrict__ entb,
                         unsigned short* __restrict__ E16) {
    __shared__ __align__(16) unsigned shm[3074];
    convE_dev(blockIdx.x, threadIdx.x, ent, Mvec, entb, E16, shm);
}

// ---- fused path: ONLY legal when entb/E16 do NOT alias stg (disjoint layout).
// R10 crashed here: with aliased layout, conv blocks overwrite staging records
// while bucket blocks still read them -> corrupted keys -> OOB writes.
__global__ void placeconv_k(const uint2* __restrict__ stg,
                            const unsigned* __restrict__ gcur,
                            unsigned* __restrict__ offs,
                            unsigned* __restrict__ csr,
                            const float* __restrict__ ent,
                            const float* __restrict__ Mvec,
                            uint4* __restrict__ entb,
                            unsigned short* __restrict__ E16) {
    __shared__ __align__(16) unsigned shm[3074];
    int b = blockIdx.x;
    if (b < NBUCKET)
        place_bucket_dev(b, threadIdx.x, stg, gcur, offs, csr, shm);
    else
        convE_dev(b - NBUCKET, threadIdx.x, ent, Mvec, entb, E16, shm);
}

// ---- fused gather: 8 lanes per key; entities then users (unified key space) ----
template<bool FAST>   // FAST: bf16 entb gathers + E-table; else fp32 + on-the-fly Mvec
__global__ void gather8_k(const float* __restrict__ ent,
                          const uint4* __restrict__ entb,
                          const unsigned short* __restrict__ E16,
                          const float* __restrict__ weight,
                          const float* __restrict__ Mvec,
                          const float* __restrict__ wnorm,
                          const float* __restrict__ uemb,
                          const float* __restrict__ lat,
                          const float* __restrict__ disen,
                          const unsigned* __restrict__ offs,
                          const unsigned* __restrict__ csr,
                          float* __restrict__ out) {
    int gid = blockIdx.x * 256 + threadIdx.x;
    int key = gid >> 3;
    int sub = threadIdx.x & 7;
    if (key >= NKEY) return;
    unsigned beg = offs[key], end = offs[key + 1];
    const float4* e4 = (const float4*)ent;
    const float4* w4 = (const float4*)weight;
    float4* o4 = (float4*)out;
    const float4 z = make_float4(0.f, 0.f, 0.f, 0.f);

    if (key < N_ENT) {
        int h = key;
        if (beg == end) {
            o4[h * 16 + sub * 2] = z;
            o4[h * 16 + sub * 2 + 1] = z;
            return;
        }
        float4 hv0 = e4[h * 16 + sub * 2], hv1 = e4[h * 16 + sub * 2 + 1];
        float dr = 0.f;
        if (FAST) {
            for (unsigned i = beg + sub; i < end; i += 8)
                dr += bf2f(E16[h * NREL1 + (csr[i] >> 18)]);
            dr = red8(dr);
        } else {
            for (unsigned i = beg; i < end; ++i) {
                int r = csr[i] >> 18;
                float d = dot4(hv0, ((const float4*)Mvec)[r * 16 + sub * 2]) +
                          dot4(hv1, ((const float4*)Mvec)[r * 16 + sub * 2 + 1]);
                dr += __expf(red8(d) * SCORE_SCALE);
            }
        }
        float inv_dr = 1.0f / dr;
        float4 a0 = z, a1 = z;
        float dt = 0.f;
        unsigned i = beg;
        for (; i + 2 <= end; i += 2) {
            unsigned p0 = csr[i], p1 = csr[i + 1];
            int t0 = p0 & 0x3FFFF, r0 = p0 >> 18;
            int t1 = p1 & 0x3FFFF, r1 = p1 >> 18;
            float4 tv00, tv01, tv10, tv11;
            if (FAST) {
                uint4 tb0 = entb[t0 * 8 + sub];
                uint4 tb1 = entb[t1 * 8 + sub];
                tv00 = bf4lo(tb0); tv01 = bf4hi(tb0);
                tv10 = bf4lo(tb1); tv11 = bf4hi(tb1);
            } else {
                tv00 = e4[t0 * 16 + sub * 2]; tv01 = e4[t0 * 16 + sub * 2 + 1];
                tv10 = e4[t1 * 16 + sub * 2]; tv11 = e4[t1 * 16 + sub * 2 + 1];
            }
            float d0 = red8(dot4(hv0, tv00) + dot4(hv1, tv01));
            float d1 = red8(dot4(hv0, tv10) + dot4(hv1, tv11));
            float er0, er1;
            if (FAST) {
                er0 = bf2f(E16[h * NREL1 + r0]);
                er1 = bf2f(E16[h * NREL1 + r1]);
            } else {
                float q0 = dot4(hv0, ((const float4*)Mvec)[r0 * 16 + sub * 2]) +
                           dot4(hv1, ((const float4*)Mvec)[r0 * 16 + sub * 2 + 1]);
                float q1 = dot4(hv0, ((const float4*)Mvec)[r1 * 16 + sub * 2]) +
                           dot4(hv1, ((const float4*)Mvec)[r1 * 16 + sub * 2 + 1]);
                er0 = __expf(red8(q0) * SCORE_SCALE);
                er1 = __expf(red8(q1) * SCORE_SCALE);
            }
            float ra0 = er0 * inv_dr, ra1 = er1 * inv_dr;
            float et0 = __expf(d0 + ra0 * ra0 * wnorm[r0]);
            float et1 = __expf(d1 + ra1 * ra1 * wnorm[r1]);
            dt += et0 + et1;
            float4 wv;
            wv = w4[r0 * 16 + sub * 2];
            a0.x += et0 * tv00.x * wv.x; a0.y += et0 * tv00.y * wv.y;
            a0.z += et0 * tv00.z * wv.z; a0.w += et0 * tv00.w * wv.w;
            wv = w4[r0 * 16 + sub * 2 + 1];
            a1.x += et0 * tv01.x * wv.x; a1.y += et0 * tv01.y * wv.y;
            a1.z += et0 * tv01.z * wv.z; a1.w += et0 * tv01.w * wv.w;
            wv = w4[r1 * 16 + sub * 2];
            a0.x += et1 * tv10.x * wv.x; a0.y += et1 * tv10.y * wv.y;
            a0.z += et1 * tv10.z * wv.z; a0.w += et1 * tv10.w * wv.w;
            wv = w4[r1 * 16 + sub * 2 + 1];
            a1.x += et1 * tv11.x * wv.x; a1.y += et1 * tv11.y * wv.y;
            a1.z += et1 * tv11.z * wv.z; a1.w += et1 * tv11.w * wv.w;
        }
        if (i < end) {
            unsigned p = csr[i];
            int t = p & 0x3FFFF, r = p >> 18;
            float4 tv0, tv1;
            if (FAST) {
                uint4 tb = entb[t * 8 + sub];
                tv0 = bf4lo(tb); tv1 = bf4hi(tb);
            } else {
                tv0 = e4[t * 16 + sub * 2]; tv1 = e4[t * 16 + sub * 2 + 1];
            }
            float d = red8(dot4(hv0, tv0) + dot4(hv1, tv1));
            float er;
            if (FAST) {
                er = bf2f(E16[h * NREL1 + r]);
            } else {
                float q = dot4(hv0, ((const float4*)Mvec)[r * 16 + sub * 2]) +
                          dot4(hv1, ((const float4*)Mvec)[r * 16 + sub * 2 + 1]);
                er = __expf(red8(q) * SCORE_SCALE);
            }
            float ra = er * inv_dr;
            float et = __expf(d + ra * ra * wnorm[r]);
            dt += et;
            float4 wv;
            wv = w4[r * 16 + sub * 2];
            a0.x += et * tv0.x * wv.x; a0.y += et * tv0.y * wv.y;
            a0.z += et * tv0.z * wv.z; a0.w += et * tv0.w * wv.w;
            wv = w4[r * 16 + sub * 2 + 1];
            a1.x += et * tv1.x * wv.x; a1.y += et * tv1.y * wv.y;
            a1.z += et * tv1.z * wv.z; a1.w += et * tv1.w * wv.w;
        }
        float inv = 1.0f / (dt * (float)(end - beg));
        a0.x *= inv; a0.y *= inv; a0.z *= inv; a0.w *= inv;
        a1.x *= inv; a1.y *= inv; a1.z *= inv; a1.w *= inv;
        o4[h * 16 + sub * 2] = a0;
        o4[h * 16 + sub * 2 + 1] = a1;
    } else {
        int u = key - N_ENT;
        float4 a0 = z, a1 = z;
        unsigned i = beg;
        for (; i + 2 <= end; i += 2) {
            unsigned p0 = csr[i], p1 = csr[i + 1];
            int c0 = p0 & 0x3FFFF, c1 = p1 & 0x3FFFF;
            float v0 = (float)(p0 >> 18) * INV_Q14;
            float v1 = (float)(p1 >> 18) * INV_Q14;
            float4 tv00, tv01, tv10, tv11;
            if (FAST) {
                uint4 tb0 = entb[c0 * 8 + sub];
                uint4 tb1 = entb[c1 * 8 + sub];
                tv00 = bf4lo(tb0); tv01 = bf4hi(tb0);
                tv10 = bf4lo(tb1); tv11 = bf4hi(tb1);
            } else {
                tv00 = e4[c0 * 16 + sub * 2]; tv01 = e4[c0 * 16 + sub * 2 + 1];
                tv10 = e4[c1 * 16 + sub * 2]; tv11 = e4[c1 * 16 + sub * 2 + 1];
            }
            a0.x += v0 * tv00.x + v1 * tv10.x; a0.y += v0 * tv00.y + v1 * tv10.y;
            a0.z += v0 * tv00.z + v1 * tv10.z; a0.w += v0 * tv00.w + v1 * tv10.w;
            a1.x += v0 * tv01.x + v1 * tv11.x; a1.y += v0 * tv01.y + v1 * tv11.y;
            a1.z += v0 * tv01.z + v1 * tv11.z; a1.w += v0 * tv01.w + v1 * tv11.w;
        }
        if (i < end) {
            unsigned p = csr[i];
            int c = p & 0x3FFFF;
            float v = (float)(p >> 18) * INV_Q14;
            float4 tv0, tv1;
            if (FAST) {
                uint4 tb = entb[c * 8 + sub];
                tv0 = bf4lo(tb); tv1 = bf4hi(tb);
            } else {
                tv0 = e4[c * 16 + sub * 2]; tv1 = e4[c * 16 + sub * 2 + 1];
            }
            a0.x += v * tv0.x; a0.y += v * tv0.y; a0.z += v * tv0.z; a0.w += v * tv0.w;
            a1.x += v * tv1.x; a1.y += v * tv1.y; a1.z += v * tv1.z; a1.w += v * tv1.w;
        }
        float4 uv0 = ((const float4*)uemb)[u * 16 + sub * 2];
        float4 uv1 = ((const float4*)uemb)[u * 16 + sub * 2 + 1];
        float d[N_FACTORS];
        for (int f = 0; f < N_FACTORS; ++f) {
            float t = dot4(uv0, ((const float4*)lat)[f * 16 + sub * 2]) +
                      dot4(uv1, ((const float4*)lat)[f * 16 + sub * 2 + 1]);
            d[f] = red8(t);
        }
        float m = fmaxf(fmaxf(d[0], d[1]), fmaxf(d[2], d[3]));
        float s = 0.f, p_[N_FACTORS];
        for (int f = 0; f < N_FACTORS; ++f) { p_[f] = __expf(d[f] - m); s += p_[f]; }
        float invs = 1.0f / s;
        float4 g0 = z, g1 = z;
        for (int f = 0; f < N_FACTORS; ++f) {
            float w = p_[f] * invs;
            float4 dv = ((const float4*)disen)[f * 16 + sub * 2];
            g0.x += w * dv.x; g0.y += w * dv.y; g0.z += w * dv.z; g0.w += w * dv.w;
            dv = ((const float4*)disen)[f * 16 + sub * 2 + 1];
            g1.x += w * dv.x; g1.y += w * dv.y; g1.z += w * dv.z; g1.w += w * dv.w;
        }
        a0.x *= (1.0f + g0.x); a0.y *= (1.0f + g0.y);
        a0.z *= (1.0f + g0.z); a0.w *= (1.0f + g0.w);
        a1.x *= (1.0f + g1.x); a1.y *= (1.0f + g1.y);
        a1.z *= (1.0f + g1.z); a1.w *= (1.0f + g1.w);
        o4[key * 16 + sub * 2] = a0;
        o4[key * 16 + sub * 2 + 1] = a1;
    }
}

extern "C" void kernel_launch(void* const* d_in, const int* in_sizes, int n_in,
                              void* d_out, int out_size, void* d_ws, size_t ws_size,
                              hipStream_t stream) {
    (void)in_sizes; (void)n_in; (void)out_size;
    const float* ent    = (const float*)d_in[0];
    const float* uemb   = (const float*)d_in[1];
    const float* lat    = (const float*)d_in[2];
    const int*   eidx   = (const int*)d_in[3];
    const int*   etype  = (const int*)d_in[4];
    const int*   urows  = (const int*)d_in[5];
    const int*   ucols  = (const int*)d_in[6];
    const float* uvals  = (const float*)d_in[7];
    const float* weight = (const float*)d_in[8];
    const float* datt   = (const float*)d_in[9];
    const float* W      = (const float*)d_in[10];

    const int* head = eidx;
    const int* tail = eidx + N_EDGES;
    float* out = (float*)d_out;

    // ws layout (4B words). offs padded to NKEY+2 so 'big' starts 8B-aligned.
    unsigned* gcur  = (unsigned*)d_ws;            // 256 (147 used; pure counts)
    unsigned* offs  = gcur + 256;                 // NKEY+2 (offs[NKEY] used, +1 pad)
    float*    Mvec  = (float*)(offs + NKEY + 2);  // 1600
    float*    wnorm = Mvec + NREL1 * 64;          // 32
    float*    disen = wnorm + 32;                 // 256
    unsigned* csr   = (unsigned*)(disen + N_FACTORS * 64);   // 2M
    unsigned* big   = csr + NREC;                 // union / sequential region

    size_t base_words = 256 + (NKEY + 2) + 1888 + (size_t)NREC;           // 2.30M
    size_t stg_words  = (size_t)NBUCKET * CAP * 2;                        // 7.23M
    size_t tbl_words  = (size_t)N_ENT * 32 + ((size_t)N_ENT * NREL1 + 1) / 2;  // 8.9M
    size_t big_alias  = stg_words > tbl_words ? stg_words : tbl_words;
    size_t need_fast     = (base_words + big_alias) * 4;              // ~44.8 MB
    size_t need_min      = (base_words + stg_words) * 4;              // ~38.1 MB
    size_t need_disjoint = (base_words + stg_words + tbl_words) * 4;  // ~73.7 MB
    bool fast     = ws_size >= need_fast;
    bool disjoint = ws_size >= need_disjoint;   // disjoint implies fast
    if (ws_size < need_min) return;             // cannot run (never in practice)

    uint2*    stg  = (uint2*)big;
    // serial path: entb/E16 ALIAS stg (legal: convE launches after binplace3).
    // disjoint path: entb/E16 AFTER stg (legal to run concurrently).
    unsigned* entw = disjoint ? (big + stg_words) : big;
    uint4*    entb = (uint4*)entw;
    unsigned short* E16 = (unsigned short*)(entw + (size_t)N_ENT * 32);

    const int BLK = 256;

    hipMemsetAsync(gcur, 0, 256 * sizeof(unsigned), stream);
    precompute_k<<<1, 256, 0, stream>>>(W, weight, datt, Mvec, wnorm, disen);
    binfill_k<<<(NREC + TILE - 1) / TILE, BLK, 0, stream>>>(
        head, tail, etype, urows, ucols, uvals, gcur, stg);

    if (disjoint) {
        placeconv_k<<<NBUCKET + NCONVB, 1024, 0, stream>>>(
            stg, gcur, offs, csr, ent, Mvec, entb, E16);
    } else {
        binplace3_k<<<NBUCKET, 1024, 0, stream>>>(stg, gcur, offs, csr);
        if (fast)
            convE2_k<<<NCONVB, 1024, 0, stream>>>(ent, Mvec, entb, E16);
    }

    int gridG = (NKEY * 8 + BLK - 1) / BLK;
    if (fast) {
        gather8_k<true><<<gridG, BLK, 0, stream>>>(
            ent, entb, E16, weight, Mvec, wnorm,
            uemb, lat, disen, offs, csr, out);
    } else {
        gather8_k<false><<<gridG, BLK, 0, stream>>>(
            ent, entb, E16, weight, Mvec, wnorm,
            uemb, lat, disen, offs, csr, out);
    }
}

// Round 12
// 201.983 us; speedup vs baseline: 2.0715x; 1.0084x over previous
//
#include <hip/hip_runtime.h>
#include <math.h>

#define N_ENT 200000
#define N_USERS 100000
#define NKEY 300000            // N_ENT + N_USERS unified key space
#define N_FACTORS 4
#define NREL1 25               // N_REL - 1
#define CH 64
#define N_EDGES 1000000
#define NNZ 1000000
#define NREC 2000000           // N_EDGES + NNZ unified records
#define BSHIFT 11
#define BKEYS 2048
#define NBUCKET 147            // ceil(NKEY / 2048)
#define TILE 2048
// Per-bucket staging capacity. Entity buckets: mean 2048*5=10240 (sigma~100).
// User buckets: mean 2048*10=20480 (sigma~142). 24576 = user mean + ~29 sigma.
#define CAP 24576
#define NCONVB ((N_ENT * 8 + 1023) / 1024)   // 1563 conv-role blocks

// 1 / (2*sqrt(32))
#define SCORE_SCALE 0.08838834764831845f
#define INV_Q14 6.103888176768602e-05f   // 1/16383

__device__ __forceinline__ float red8(float d) {
    d += __shfl_xor(d, 1);
    d += __shfl_xor(d, 2);
    d += __shfl_xor(d, 4);
    return d;
}
__device__ __forceinline__ float dot4(float4 a, float4 b) {
    return a.x * b.x + a.y * b.y + a.z * b.z + a.w * b.w;
}
__device__ __forceinline__ unsigned short f2bf(float f) {   // RNE
    unsigned u = __float_as_uint(f);
    u += 0x7FFFu + ((u >> 16) & 1u);
    return (unsigned short)(u >> 16);
}
__device__ __forceinline__ float bf2f(unsigned short u) {
    return __uint_as_float(((unsigned)u) << 16);
}
__device__ __forceinline__ float4 bf4lo(uint4 t) {
    return make_float4(__uint_as_float(t.x << 16), __uint_as_float(t.x & 0xFFFF0000u),
                       __uint_as_float(t.y << 16), __uint_as_float(t.y & 0xFFFF0000u));
}
__device__ __forceinline__ float4 bf4hi(uint4 t) {
    return make_float4(__uint_as_float(t.z << 16), __uint_as_float(t.z & 0xFFFF0000u),
                       __uint_as_float(t.w << 16), __uint_as_float(t.w & 0xFFFF0000u));
}

// ---- tiny precompute: Mvec[r] = (W W^T) weight[r]; wnorm[r]; disen[f][c] ----
__global__ void precompute_k(const float* __restrict__ W,
                             const float* __restrict__ weight,
                             const float* __restrict__ datt,
                             float* __restrict__ Mvec,
                             float* __restrict__ wnorm,
                             float* __restrict__ disen) {
    __shared__ float sW[64 * 64];
    __shared__ float sw[NREL1 * 64];
    __shared__ float sWWt[64 * 64];
    int tid = threadIdx.x;
    for (int i = tid; i < 64 * 64; i += 256) sW[i] = W[i];
    for (int i = tid; i < NREL1 * 64; i += 256) sw[i] = weight[i];
    __syncthreads();
    for (int e = tid; e < 64 * 64; e += 256) {
        int i = e >> 6, j = e & 63;
        float s = 0.f;
        for (int k = 0; k < 64; ++k) s += sW[i * 64 + k] * sW[j * 64 + k];
        sWWt[e] = s;
    }
    __syncthreads();
    for (int e = tid; e < NREL1 * 64; e += 256) {
        int r = e >> 6, i = e & 63;
        float s = 0.f;
        for (int j = 0; j < 64; ++j) s += sWWt[i * 64 + j] * sw[r * 64 + j];
        Mvec[e] = s;
    }
    for (int r = tid; r < NREL1; r += 256) {
        float s = 0.f;
        for (int j = 0; j < 64; ++j) { float v = sw[r * 64 + j]; s += v * v; }
        wnorm[r] = s;
    }
    for (int e = tid; e < N_FACTORS * 64; e += 256) {
        int f = e >> 6, c = e & 63;
        float m = -1e30f;
        for (int r = 0; r < NREL1; ++r) m = fmaxf(m, datt[f * NREL1 + r]);
        float ssum = 0.f, acc = 0.f;
        for (int r = 0; r < NREL1; ++r) {
            float p = expf(datt[f * NREL1 + r] - m);
            ssum += p;
            acc += p * sw[r * 64 + c];
        }
        disen[e] = acc / ssum;
    }
}

// ---- stage 1 (direct): rank-atomics + per-bucket window reserve + register
// writes. No LDS scan, no lrec round-trip (binplace re-sorts the bucket anyway,
// so LDS compaction was only a write-coalescing nicety: 22 barriers -> 4).
__global__ void binfill_k(const int* __restrict__ head, const int* __restrict__ tail,
                          const int* __restrict__ etype,
                          const int* __restrict__ rows, const int* __restrict__ cols,
                          const float* __restrict__ vals,
                          unsigned* __restrict__ gcur,
                          uint2* __restrict__ stg) {
    __shared__ unsigned hist[NBUCKET], gbase[NBUCKET];
    int tid = threadIdx.x;
    int tile0 = blockIdx.x * TILE;
    int tile_n = min(TILE, NREC - tile0);
    for (int b = tid; b < NBUCKET; b += 256) hist[b] = 0u;
    __syncthreads();
    unsigned key[8], pay[8], rank[8];
    for (int r = 0; r < 8; ++r) {
        int li = r * 256 + tid;
        key[r] = 0xFFFFFFFFu;
        if (li < tile_n) {
            int idx = tile0 + li;
            unsigned k, p;
            if (idx < N_EDGES) {
                k = (unsigned)head[idx];
                p = (unsigned)tail[idx] | ((unsigned)(etype[idx] - 1) << 18);
            } else {
                int j = idx - N_EDGES;
                k = (unsigned)(N_ENT + rows[j]);
                unsigned q = (unsigned)(vals[j] * 16383.f + 0.5f);
                p = (unsigned)cols[j] | (q << 18);
            }
            key[r] = k; pay[r] = p;
            rank[r] = atomicAdd(&hist[k >> BSHIFT], 1u);
        }
    }
    __syncthreads();
    if (tid < NBUCKET) {
        unsigned v = hist[tid];
        gbase[tid] = (unsigned)tid * CAP + (v ? atomicAdd(&gcur[tid], v) : 0u);
    }
    __syncthreads();
    for (int r = 0; r < 8; ++r) {
        if (key[r] != 0xFFFFFFFFu) {
            unsigned b = key[r] >> BSHIFT;
            unsigned dst = gbase[b] + rank[r];
            if (dst < (b + 1u) * CAP)               // overflow guard (never fires)
                stg[dst] = make_uint2(key[r], pay[r]);
        }
    }
}

// ---- device body: place one bucket (1024 threads); shm needs 3074 words ----
__device__ __forceinline__
void place_bucket_dev(int b, int tid, const uint2* __restrict__ stg,
                      const unsigned* __restrict__ gcur,
                      unsigned* __restrict__ offs, unsigned* __restrict__ csr,
                      unsigned* shm) {
    // inline bucket-base: prefix over clamped counts (147 elems in 256-scan)
    unsigned c = (tid < NBUCKET) ? gcur[tid] : 0u;
    if (c > CAP) c = CAP;
    if (tid < 256) shm[tid] = c;
    __syncthreads();
    for (int o = 1; o < 256; o <<= 1) {
        unsigned t = (tid >= o && tid < 256) ? shm[tid - o] : 0u;
        __syncthreads();
        if (tid < 256) shm[tid] += t;
        __syncthreads();
    }
    if (tid == 0) {
        unsigned cb = gcur[b]; if (cb > CAP) cb = CAP;
        shm[3073] = cb;
        shm[3072] = shm[b] - cb;                      // exclusive base
        if (b == NBUCKET - 1) offs[NKEY] = shm[NBUCKET - 1];  // grand total
    }
    __syncthreads();
    unsigned n = shm[3073], gb = shm[3072];
    const uint2* seg = stg + (size_t)b * CAP;
    // per-key count (cnt = shm[0..2047], distinct from shm[3072..3073])
    unsigned* cnt = shm;
    unsigned* sc  = shm + 2048;
    cnt[tid * 2] = 0u; cnt[tid * 2 + 1] = 0u;
    __syncthreads();
    for (unsigned i = tid; i < n; i += 1024) {
        unsigned kk = seg[i].x - ((unsigned)b << BSHIFT);
        atomicAdd(&cnt[kk], 1u);
    }
    __syncthreads();
    unsigned c0 = cnt[tid * 2], c1 = cnt[tid * 2 + 1];
    unsigned tsum = c0 + c1;
    sc[tid] = tsum; __syncthreads();
    for (int o = 1; o < 1024; o <<= 1) {
        unsigned t = (tid >= o) ? sc[tid - o] : 0u;
        __syncthreads();
        sc[tid] += t;
        __syncthreads();
    }
    unsigned e0 = sc[tid] - tsum;
    unsigned e1 = e0 + c0;
    int k0 = (b << BSHIFT) + tid * 2;
    if (k0 < NKEY)     offs[k0]     = gb + e0;
    if (k0 + 1 < NKEY) offs[k0 + 1] = gb + e1;
    cnt[tid * 2] = e0; cnt[tid * 2 + 1] = e1;
    __syncthreads();
    for (unsigned i = tid; i < n; i += 1024) {
        uint2 rec = seg[i];
        unsigned kk = rec.x - ((unsigned)b << BSHIFT);
        unsigned pos = atomicAdd(&cnt[kk], 1u);
        csr[gb + pos] = rec.y;
    }
}

// ---- device body: convE for conv-block cb (1024 threads); shm >= 1600 words ----
__device__ __forceinline__
void convE_dev(int cb, int tid, const float* __restrict__ ent,
               const float* __restrict__ Mvec,
               uint4* __restrict__ entb, unsigned short* __restrict__ E16,
               unsigned* shm) {
    float4* sM = (float4*)shm;          // NREL1*16 = 400 float4 = 1600 words
    for (int i = tid; i < NREL1 * 16; i += 1024) sM[i] = ((const float4*)Mvec)[i];
    __syncthreads();
    int idx = cb * 1024 + tid;
    int h = idx >> 3;
    int sub = tid & 7;
    if (h >= N_ENT) return;
    const float4* e4 = (const float4*)ent;
    float4 a = e4[h * 16 + sub * 2], b4 = e4[h * 16 + sub * 2 + 1];
    uint4 o;
    o.x = (unsigned)f2bf(a.x)  | ((unsigned)f2bf(a.y)  << 16);
    o.y = (unsigned)f2bf(a.z)  | ((unsigned)f2bf(a.w)  << 16);
    o.z = (unsigned)f2bf(b4.x) | ((unsigned)f2bf(b4.y) << 16);
    o.w = (unsigned)f2bf(b4.z) | ((unsigned)f2bf(b4.w) << 16);
    entb[h * 8 + sub] = o;
    for (int r = 0; r < NREL1; ++r) {
        float d = dot4(a, sM[r * 16 + sub * 2]) + dot4(b4, sM[r * 16 + sub * 2 + 1]);
        d = red8(d);
        if (sub == (r & 7)) E16[h * NREL1 + r] = f2bf(__expf(d * SCORE_SCALE));
    }
}

// ---- serial path: place only (convE follows as its own launch; stg aliasing OK) ----
__global__ void binplace3_k(const uint2* __restrict__ stg,
                            const unsigned* __restrict__ gcur,
                            unsigned* __restrict__ offs,
                            unsigned* __restrict__ csr) {
    __shared__ __align__(16) unsigned shm[3074];
    place_bucket_dev(blockIdx.x, threadIdx.x, stg, gcur, offs, csr, shm);
}

__global__ void convE2_k(const float* __restrict__ ent,
                         const float* __restrict__ Mvec,
                         uint4* __restrict__ entb,
                         unsigned short* __restrict__ E16) {
    __shared__ __align__(16) unsigned shm[3074];
    convE_dev(blockIdx.x, threadIdx.x, ent, Mvec, entb, E16, shm);
}

// ---- fused path: ONLY legal when entb/E16 do NOT alias stg (disjoint layout).
__global__ void placeconv_k(const uint2* __restrict__ stg,
                            const unsigned* __restrict__ gcur,
                            unsigned* __restrict__ offs,
                            unsigned* __restrict__ csr,
                            const float* __restrict__ ent,
                            const float* __restrict__ Mvec,
                            uint4* __restrict__ entb,
                            unsigned short* __restrict__ E16) {
    __shared__ __align__(16) unsigned shm[3074];
    int b = blockIdx.x;
    if (b < NBUCKET)
        place_bucket_dev(b, threadIdx.x, stg, gcur, offs, csr, shm);
    else
        convE_dev(b - NBUCKET, threadIdx.x, ent, Mvec, entb, E16, shm);
}

// ---- fused gather: 8 lanes per key; entities then users (unified key space) ----
template<bool FAST>   // FAST: bf16 entb gathers + E-table; else fp32 + on-the-fly Mvec
__global__ void gather8_k(const float* __restrict__ ent,
                          const uint4* __restrict__ entb,
                          const unsigned short* __restrict__ E16,
                          const float* __restrict__ weight,
                          const float* __restrict__ Mvec,
                          const float* __restrict__ wnorm,
                          const float* __restrict__ uemb,
                          const float* __restrict__ lat,
                          const float* __restrict__ disen,
                          const unsigned* __restrict__ offs,
                          const unsigned* __restrict__ csr,
                          float* __restrict__ out) {
    int gid = blockIdx.x * 256 + threadIdx.x;
    int key = gid >> 3;
    int sub = threadIdx.x & 7;
    if (key >= NKEY) return;
    unsigned beg = offs[key], end = offs[key + 1];
    const float4* e4 = (const float4*)ent;
    const float4* w4 = (const float4*)weight;
    float4* o4 = (float4*)out;
    const float4 z = make_float4(0.f, 0.f, 0.f, 0.f);

    if (key < N_ENT) {
        int h = key;
        if (beg == end) {
            o4[h * 16 + sub * 2] = z;
            o4[h * 16 + sub * 2 + 1] = z;
            return;
        }
        // head row: bf16 shadow in FAST mode (128 B vs 256 B, sequential)
        float4 hv0, hv1;
        if (FAST) {
            uint4 hb = entb[h * 8 + sub];
            hv0 = bf4lo(hb); hv1 = bf4hi(hb);
        } else {
            hv0 = e4[h * 16 + sub * 2]; hv1 = e4[h * 16 + sub * 2 + 1];
        }
        float dr = 0.f;
        if (FAST) {
            for (unsigned i = beg + sub; i < end; i += 8)
                dr += bf2f(E16[h * NREL1 + (csr[i] >> 18)]);
            dr = red8(dr);
        } else {
            for (unsigned i = beg; i < end; ++i) {
                int r = csr[i] >> 18;
                float d = dot4(hv0, ((const float4*)Mvec)[r * 16 + sub * 2]) +
                          dot4(hv1, ((const float4*)Mvec)[r * 16 + sub * 2 + 1]);
                dr += __expf(red8(d) * SCORE_SCALE);
            }
        }
        float inv_dr = 1.0f / dr;
        float4 a0 = z, a1 = z;
        float dt = 0.f;
        unsigned i = beg;
        for (; i + 2 <= end; i += 2) {
            unsigned p0 = csr[i], p1 = csr[i + 1];
            int t0 = p0 & 0x3FFFF, r0 = p0 >> 18;
            int t1 = p1 & 0x3FFFF, r1 = p1 >> 18;
            float4 tv00, tv01, tv10, tv11;
            if (FAST) {
                uint4 tb0 = entb[t0 * 8 + sub];
                uint4 tb1 = entb[t1 * 8 + sub];
                tv00 = bf4lo(tb0); tv01 = bf4hi(tb0);
                tv10 = bf4lo(tb1); tv11 = bf4hi(tb1);
            } else {
                tv00 = e4[t0 * 16 + sub * 2]; tv01 = e4[t0 * 16 + sub * 2 + 1];
                tv10 = e4[t1 * 16 + sub * 2]; tv11 = e4[t1 * 16 + sub * 2 + 1];
            }
            float d0 = red8(dot4(hv0, tv00) + dot4(hv1, tv01));
            float d1 = red8(dot4(hv0, tv10) + dot4(hv1, tv11));
            float er0, er1;
            if (FAST) {
                er0 = bf2f(E16[h * NREL1 + r0]);
                er1 = bf2f(E16[h * NREL1 + r1]);
            } else {
                float q0 = dot4(hv0, ((const float4*)Mvec)[r0 * 16 + sub * 2]) +
                           dot4(hv1, ((const float4*)Mvec)[r0 * 16 + sub * 2 + 1]);
                float q1 = dot4(hv0, ((const float4*)Mvec)[r1 * 16 + sub * 2]) +
                           dot4(hv1, ((const float4*)Mvec)[r1 * 16 + sub * 2 + 1]);
                er0 = __expf(red8(q0) * SCORE_SCALE);
                er1 = __expf(red8(q1) * SCORE_SCALE);
            }
            float ra0 = er0 * inv_dr, ra1 = er1 * inv_dr;
            float et0 = __expf(d0 + ra0 * ra0 * wnorm[r0]);
            float et1 = __expf(d1 + ra1 * ra1 * wnorm[r1]);
            dt += et0 + et1;
            float4 wv;
            wv = w4[r0 * 16 + sub * 2];
            a0.x += et0 * tv00.x * wv.x; a0.y += et0 * tv00.y * wv.y;
            a0.z += et0 * tv00.z * wv.z; a0.w += et0 * tv00.w * wv.w;
            wv = w4[r0 * 16 + sub * 2 + 1];
            a1.x += et0 * tv01.x * wv.x; a1.y += et0 * tv01.y * wv.y;
            a1.z += et0 * tv01.z * wv.z; a1.w += et0 * tv01.w * wv.w;
            wv = w4[r1 * 16 + sub * 2];
            a0.x += et1 * tv10.x * wv.x; a0.y += et1 * tv10.y * wv.y;
            a0.z += et1 * tv10.z * wv.z; a0.w += et1 * tv10.w * wv.w;
            wv = w4[r1 * 16 + sub * 2 + 1];
            a1.x += et1 * tv11.x * wv.x; a1.y += et1 * tv11.y * wv.y;
            a1.z += et1 * tv11.z * wv.z; a1.w += et1 * tv11.w * wv.w;
        }
        if (i < end) {
            unsigned p = csr[i];
            int t = p & 0x3FFFF, r = p >> 18;
            float4 tv0, tv1;
            if (FAST) {
                uint4 tb = entb[t * 8 + sub];
                tv0 = bf4lo(tb); tv1 = bf4hi(tb);
            } else {
                tv0 = e4[t * 16 + sub * 2]; tv1 = e4[t * 16 + sub * 2 + 1];
            }
            float d = red8(dot4(hv0, tv0) + dot4(hv1, tv1));
            float er;
            if (FAST) {
                er = bf2f(E16[h * NREL1 + r]);
            } else {
                float q = dot4(hv0, ((const float4*)Mvec)[r * 16 + sub * 2]) +
                          dot4(hv1, ((const float4*)Mvec)[r * 16 + sub * 2 + 1]);
                er = __expf(red8(q) * SCORE_SCALE);
            }
            float ra = er * inv_dr;
            float et = __expf(d + ra * ra * wnorm[r]);
            dt += et;
            float4 wv;
            wv = w4[r * 16 + sub * 2];
            a0.x += et * tv0.x * wv.x; a0.y += et * tv0.y * wv.y;
            a0.z += et * tv0.z * wv.z; a0.w += et * tv0.w * wv.w;
            wv = w4[r * 16 + sub * 2 + 1];
            a1.x += et * tv1.x * wv.x; a1.y += et * tv1.y * wv.y;
            a1.z += et * tv1.z * wv.z; a1.w += et * tv1.w * wv.w;
        }
        float inv = 1.0f / (dt * (float)(end - beg));
        a0.x *= inv; a0.y *= inv; a0.z *= inv; a0.w *= inv;
        a1.x *= inv; a1.y *= inv; a1.z *= inv; a1.w *= inv;
        o4[h * 16 + sub * 2] = a0;
        o4[h * 16 + sub * 2 + 1] = a1;
    } else {
        int u = key - N_ENT;
        float4 a0 = z, a1 = z;
        unsigned i = beg;
        for (; i + 2 <= end; i += 2) {
            unsigned p0 = csr[i], p1 = csr[i + 1];
            int c0 = p0 & 0x3FFFF, c1 = p1 & 0x3FFFF;
            float v0 = (float)(p0 >> 18) * INV_Q14;
            float v1 = (float)(p1 >> 18) * INV_Q14;
            float4 tv00, tv01, tv10, tv11;
            if (FAST) {
                uint4 tb0 = entb[c0 * 8 + sub];
                uint4 tb1 = entb[c1 * 8 + sub];
                tv00 = bf4lo(tb0); tv01 = bf4hi(tb0);
                tv10 = bf4lo(tb1); tv11 = bf4hi(tb1);
            } else {
                tv00 = e4[c0 * 16 + sub * 2]; tv01 = e4[c0 * 16 + sub * 2 + 1];
                tv10 = e4[c1 * 16 + sub * 2]; tv11 = e4[c1 * 16 + sub * 2 + 1];
            }
            a0.x += v0 * tv00.x + v1 * tv10.x; a0.y += v0 * tv00.y + v1 * tv10.y;
            a0.z += v0 * tv00.z + v1 * tv10.z; a0.w += v0 * tv00.w + v1 * tv10.w;
            a1.x += v0 * tv01.x + v1 * tv11.x; a1.y += v0 * tv01.y + v1 * tv11.y;
            a1.z += v0 * tv01.z + v1 * tv11.z; a1.w += v0 * tv01.w + v1 * tv11.w;
        }
        if (i < end) {
            unsigned p = csr[i];
            int c = p & 0x3FFFF;
            float v = (float)(p >> 18) * INV_Q14;
            float4 tv0, tv1;
            if (FAST) {
                uint4 tb = entb[c * 8 + sub];
                tv0 = bf4lo(tb); tv1 = bf4hi(tb);
            } else {
                tv0 = e4[c * 16 + sub * 2]; tv1 = e4[c * 16 + sub * 2 + 1];
            }
            a0.x += v * tv0.x; a0.y += v * tv0.y; a0.z += v * tv0.z; a0.w += v * tv0.w;
            a1.x += v * tv1.x; a1.y += v * tv1.y; a1.z += v * tv1.z; a1.w += v * tv1.w;
        }
        float4 uv0 = ((const float4*)uemb)[u * 16 + sub * 2];
        float4 uv1 = ((const float4*)uemb)[u * 16 + sub * 2 + 1];
        float d[N_FACTORS];
        for (int f = 0; f < N_FACTORS; ++f) {
            float t = dot4(uv0, ((const float4*)lat)[f * 16 + sub * 2]) +
                      dot4(uv1, ((const float4*)lat)[f * 16 + sub * 2 + 1]);
            d[f] = red8(t);
        }
        float m = fmaxf(fmaxf(d[0], d[1]), fmaxf(d[2], d[3]));
        float s = 0.f, p_[N_FACTORS];
        for (int f = 0; f < N_FACTORS; ++f) { p_[f] = __expf(d[f] - m); s += p_[f]; }
        float invs = 1.0f / s;
        float4 g0 = z, g1 = z;
        for (int f = 0; f < N_FACTORS; ++f) {
            float w = p_[f] * invs;
            float4 dv = ((const float4*)disen)[f * 16 + sub * 2];
            g0.x += w * dv.x; g0.y += w * dv.y; g0.z += w * dv.z; g0.w += w * dv.w;
            dv = ((const float4*)disen)[f * 16 + sub * 2 + 1];
            g1.x += w * dv.x; g1.y += w * dv.y; g1.z += w * dv.z; g1.w += w * dv.w;
        }
        a0.x *= (1.0f + g0.x); a0.y *= (1.0f + g0.y);
        a0.z *= (1.0f + g0.z); a0.w *= (1.0f + g0.w);
        a1.x *= (1.0f + g1.x); a1.y *= (1.0f + g1.y);
        a1.z *= (1.0f + g1.z); a1.w *= (1.0f + g1.w);
        o4[key * 16 + sub * 2] = a0;
        o4[key * 16 + sub * 2 + 1] = a1;
    }
}

extern "C" void kernel_launch(void* const* d_in, const int* in_sizes, int n_in,
                              void* d_out, int out_size, void* d_ws, size_t ws_size,
                              hipStream_t stream) {
    (void)in_sizes; (void)n_in; (void)out_size;
    const float* ent    = (const float*)d_in[0];
    const float* uemb   = (const float*)d_in[1];
    const float* lat    = (const float*)d_in[2];
    const int*   eidx   = (const int*)d_in[3];
    const int*   etype  = (const int*)d_in[4];
    const int*   urows  = (const int*)d_in[5];
    const int*   ucols  = (const int*)d_in[6];
    const float* uvals  = (const float*)d_in[7];
    const float* weight = (const float*)d_in[8];
    const float* datt   = (const float*)d_in[9];
    const float* W      = (const float*)d_in[10];

    const int* head = eidx;
    const int* tail = eidx + N_EDGES;
    float* out = (float*)d_out;

    // ws layout (4B words). offs padded to NKEY+2 so 'big' starts 8B-aligned.
    unsigned* gcur  = (unsigned*)d_ws;            // 256 (147 used; pure counts)
    unsigned* offs  = gcur + 256;                 // NKEY+2 (offs[NKEY] used, +1 pad)
    float*    Mvec  = (float*)(offs + NKEY + 2);  // 1600
    float*    wnorm = Mvec + NREL1 * 64;          // 32
    float*    disen = wnorm + 32;                 // 256
    unsigned* csr   = (unsigned*)(disen + N_FACTORS * 64);   // 2M
    unsigned* big   = csr + NREC;                 // union / sequential region

    size_t base_words = 256 + (NKEY + 2) + 1888 + (size_t)NREC;           // 2.30M
    size_t stg_words  = (size_t)NBUCKET * CAP * 2;                        // 7.23M
    size_t tbl_words  = (size_t)N_ENT * 32 + ((size_t)N_ENT * NREL1 + 1) / 2;  // 8.9M
    size_t big_alias  = stg_words > tbl_words ? stg_words : tbl_words;
    size_t need_fast     = (base_words + big_alias) * 4;              // ~44.8 MB
    size_t need_min      = (base_words + stg_words) * 4;              // ~38.1 MB
    size_t need_disjoint = (base_words + stg_words + tbl_words) * 4;  // ~73.7 MB
    bool fast     = ws_size >= need_fast;
    bool disjoint = ws_size >= need_disjoint;   // disjoint implies fast
    if (ws_size < need_min) return;             // cannot run (never in practice)

    uint2*    stg  = (uint2*)big;
    // serial path: entb/E16 ALIAS stg (legal: convE launches after binplace3).
    // disjoint path: entb/E16 AFTER stg (legal to run concurrently).
    unsigned* entw = disjoint ? (big + stg_words) : big;
    uint4*    entb = (uint4*)entw;
    unsigned short* E16 = (unsigned short*)(entw + (size_t)N_ENT * 32);

    const int BLK = 256;

    hipMemsetAsync(gcur, 0, 256 * sizeof(unsigned), stream);
    precompute_k<<<1, 256, 0, stream>>>(W, weight, datt, Mvec, wnorm, disen);
    binfill_k<<<(NREC + TILE - 1) / TILE, BLK, 0, stream>>>(
        head, tail, etype, urows, ucols, uvals, gcur, stg);

    if (disjoint) {
        placeconv_k<<<NBUCKET + NCONVB, 1024, 0, stream>>>(
            stg, gcur, offs, csr, ent, Mvec, entb, E16);
    } else {
        binplace3_k<<<NBUCKET, 1024, 0, stream>>>(stg, gcur, offs, csr);
        if (fast)
            convE2_k<<<NCONVB, 1024, 0, stream>>>(ent, Mvec, entb, E16);
    }

    int gridG = (NKEY * 8 + BLK - 1) / BLK;
    if (fast) {
        gather8_k<true><<<gridG, BLK, 0, stream>>>(
            ent, entb, E16, weight, Mvec, wnorm,
            uemb, lat, disen, offs, csr, out);
    } else {
        gather8_k<false><<<gridG, BLK, 0, stream>>>(
            ent, entb, E16, weight, Mvec, wnorm,
            uemb, lat, disen, offs, csr, out);
    }
}

// Round 13
// 201.933 us; speedup vs baseline: 2.0720x; 1.0002x over previous
//
#include <hip/hip_runtime.h>
#include <math.h>

#define N_ENT 200000
#define N_USERS 100000
#define NKEY 300000            // N_ENT + N_USERS unified key space
#define N_FACTORS 4
#define NREL1 25               // N_REL - 1
#define CH 64
#define N_EDGES 1000000
#define NNZ 1000000
#define NREC 2000000           // N_EDGES + NNZ unified records
#define BSHIFT 11
#define BKEYS 2048
#define NBUCKET 147            // ceil(NKEY / 2048)
#define TILE 2048
#define NBLK_FILL ((NREC + TILE - 1) / TILE)   // 977
// Per-bucket staging capacity. Entity buckets: mean 2048*5=10240 (sigma~100).
// User buckets: mean 2048*10=20480 (sigma~142). 24576 = user mean + ~29 sigma.
#define CAP 24576
#define NCONVB ((N_ENT * 8 + 1023) / 1024)   // 1563 conv-role blocks

// 1 / (2*sqrt(32))
#define SCORE_SCALE 0.08838834764831845f
#define INV_Q14 6.103888176768602e-05f   // 1/16383

__device__ __forceinline__ float red8(float d) {
    d += __shfl_xor(d, 1);
    d += __shfl_xor(d, 2);
    d += __shfl_xor(d, 4);
    return d;
}
__device__ __forceinline__ float dot4(float4 a, float4 b) {
    return a.x * b.x + a.y * b.y + a.z * b.z + a.w * b.w;
}
__device__ __forceinline__ unsigned short f2bf(float f) {   // RNE
    unsigned u = __float_as_uint(f);
    u += 0x7FFFu + ((u >> 16) & 1u);
    return (unsigned short)(u >> 16);
}
__device__ __forceinline__ float bf2f(unsigned short u) {
    return __uint_as_float(((unsigned)u) << 16);
}
__device__ __forceinline__ float4 bf4lo(uint4 t) {
    return make_float4(__uint_as_float(t.x << 16), __uint_as_float(t.x & 0xFFFF0000u),
                       __uint_as_float(t.y << 16), __uint_as_float(t.y & 0xFFFF0000u));
}
__device__ __forceinline__ float4 bf4hi(uint4 t) {
    return make_float4(__uint_as_float(t.z << 16), __uint_as_float(t.z & 0xFFFF0000u),
                       __uint_as_float(t.w << 16), __uint_as_float(t.w & 0xFFFF0000u));
}

// ---- device body: tiny precompute (256 threads, one block-role) ----
// Mvec[r] = (W W^T) weight[r]; wnorm[r]; disen[f][c]
__device__ __forceinline__
void precompute_dev(int tid, unsigned char* shmraw,
                    const float* __restrict__ W,
                    const float* __restrict__ weight,
                    const float* __restrict__ datt,
                    float* __restrict__ Mvec,
                    float* __restrict__ wnorm,
                    float* __restrict__ disen) {
    float* sW   = (float*)shmraw;          // 4096 f (16384 B)
    float* sw   = sW + 4096;               // 1600 f (6400 B)
    float* sWWt = sw + 1600;               // 4096 f (16384 B) -> 39168 B total
    for (int i = tid; i < 64 * 64; i += 256) sW[i] = W[i];
    for (int i = tid; i < NREL1 * 64; i += 256) sw[i] = weight[i];
    __syncthreads();
    for (int e = tid; e < 64 * 64; e += 256) {
        int i = e >> 6, j = e & 63;
        float s = 0.f;
        for (int k = 0; k < 64; ++k) s += sW[i * 64 + k] * sW[j * 64 + k];
        sWWt[e] = s;
    }
    __syncthreads();
    for (int e = tid; e < NREL1 * 64; e += 256) {
        int r = e >> 6, i = e & 63;
        float s = 0.f;
        for (int j = 0; j < 64; ++j) s += sWWt[i * 64 + j] * sw[r * 64 + j];
        Mvec[e] = s;
    }
    for (int r = tid; r < NREL1; r += 256) {
        float s = 0.f;
        for (int j = 0; j < 64; ++j) { float v = sw[r * 64 + j]; s += v * v; }
        wnorm[r] = s;
    }
    for (int e = tid; e < N_FACTORS * 64; e += 256) {
        int f = e >> 6, c = e & 63;
        float m = -1e30f;
        for (int r = 0; r < NREL1; ++r) m = fmaxf(m, datt[f * NREL1 + r]);
        float ssum = 0.f, acc = 0.f;
        for (int r = 0; r < NREL1; ++r) {
            float p = expf(datt[f * NREL1 + r] - m);
            ssum += p;
            acc += p * sw[r * 64 + c];
        }
        disen[e] = acc / ssum;
    }
}

// ---- fused stage 1 + precompute: blocks [0,NBLK_FILL) bin-fill a 2048-record
// tile (LDS-compacted so staging writes are coalesced; scan is wave-shuffle,
// 5 barriers vs R11's 22); block NBLK_FILL runs precompute (independent data).
__global__ void binpre_k(const int* __restrict__ head, const int* __restrict__ tail,
                         const int* __restrict__ etype,
                         const int* __restrict__ rows, const int* __restrict__ cols,
                         const float* __restrict__ vals,
                         unsigned* __restrict__ gcur,
                         uint2* __restrict__ stg,
                         const float* __restrict__ W,
                         const float* __restrict__ weight,
                         const float* __restrict__ datt,
                         float* __restrict__ Mvec,
                         float* __restrict__ wnorm,
                         float* __restrict__ disen) {
    __shared__ __align__(16) unsigned char shmraw[39936];  // 39 KB union
    int tid = threadIdx.x;
    if (blockIdx.x >= NBLK_FILL) {
        precompute_dev(tid, shmraw, W, weight, datt, Mvec, wnorm, disen);
        return;
    }
    unsigned* hist  = (unsigned*)shmraw;            // 147
    unsigned* base  = hist + NBUCKET;               // 147
    unsigned* gbase = base + NBUCKET;               // 147
    unsigned* wsum  = gbase + NBUCKET;              // 4
    uint2*    lrec  = (uint2*)(shmraw + 2048);      // 2048 uint2 (8B aligned)

    int tile0 = blockIdx.x * TILE;
    int tile_n = min(TILE, NREC - tile0);
    for (int b = tid; b < NBUCKET; b += 256) hist[b] = 0u;
    __syncthreads();                                            // B1
    unsigned key[8], pay[8], rank[8];
    for (int r = 0; r < 8; ++r) {
        int li = r * 256 + tid;
        key[r] = 0xFFFFFFFFu;
        if (li < tile_n) {
            int idx = tile0 + li;
            unsigned k, p;
            if (idx < N_EDGES) {
                k = (unsigned)head[idx];
                p = (unsigned)tail[idx] | ((unsigned)(etype[idx] - 1) << 18);
            } else {
                int j = idx - N_EDGES;
                k = (unsigned)(N_ENT + rows[j]);
                unsigned q = (unsigned)(vals[j] * 16383.f + 0.5f);
                p = (unsigned)cols[j] | (q << 18);
            }
            key[r] = k; pay[r] = p;
            rank[r] = atomicAdd(&hist[k >> BSHIFT], 1u);
        }
    }
    __syncthreads();                                            // B2
    // wave-shuffle exclusive scan of hist[0..146] (147 < 256 threads = 4 waves)
    unsigned h0 = (tid < NBUCKET) ? hist[tid] : 0u;
    unsigned v = h0;
    int lane = tid & 63, wid = tid >> 6;
    for (int o = 1; o < 64; o <<= 1) {
        unsigned t = __shfl_up(v, o);
        if (lane >= o) v += t;
    }
    if (lane == 63) wsum[wid] = v;
    __syncthreads();                                            // B3
    unsigned pre = 0;
    for (int w = 0; w < wid; ++w) pre += wsum[w];
    if (tid < NBUCKET) {
        base[tid] = pre + v - h0;       // exclusive prefix
        gbase[tid] = (unsigned)tid * CAP + (h0 ? atomicAdd(&gcur[tid], h0) : 0u);
    }
    __syncthreads();                                            // B4
    for (int r = 0; r < 8; ++r) {
        if (key[r] != 0xFFFFFFFFu) {
            unsigned b = key[r] >> BSHIFT;
            lrec[base[b] + rank[r]] = make_uint2(key[r], pay[r]);
        }
    }
    __syncthreads();                                            // B5
    // burst copy: consecutive LDS indices -> consecutive staging addresses
    for (int i = tid; i < tile_n; i += 256) {
        uint2 rec = lrec[i];
        unsigned b = rec.x >> BSHIFT;
        unsigned dst = gbase[b] + ((unsigned)i - base[b]);
        if (dst < (b + 1u) * CAP) stg[dst] = rec;   // overflow guard (never fires)
    }
}

// ---- device body: place one bucket (1024 threads); shm needs 3074 words ----
__device__ __forceinline__
void place_bucket_dev(int b, int tid, const uint2* __restrict__ stg,
                      const unsigned* __restrict__ gcur,
                      unsigned* __restrict__ offs, unsigned* __restrict__ csr,
                      unsigned* shm) {
    // inline bucket-base: prefix over clamped counts (147 elems in 256-scan)
    unsigned c = (tid < NBUCKET) ? gcur[tid] : 0u;
    if (c > CAP) c = CAP;
    if (tid < 256) shm[tid] = c;
    __syncthreads();
    for (int o = 1; o < 256; o <<= 1) {
        unsigned t = (tid >= o && tid < 256) ? shm[tid - o] : 0u;
        __syncthreads();
        if (tid < 256) shm[tid] += t;
        __syncthreads();
    }
    if (tid == 0) {
        unsigned cb = gcur[b]; if (cb > CAP) cb = CAP;
        shm[3073] = cb;
        shm[3072] = shm[b] - cb;                      // exclusive base
        if (b == NBUCKET - 1) offs[NKEY] = shm[NBUCKET - 1];  // grand total
    }
    __syncthreads();
    unsigned n = shm[3073], gb = shm[3072];
    const uint2* seg = stg + (size_t)b * CAP;
    unsigned* cnt = shm;            // 2048 (distinct from shm[3072..3073])
    unsigned* sc  = shm + 2048;
    cnt[tid * 2] = 0u; cnt[tid * 2 + 1] = 0u;
    __syncthreads();
    for (unsigned i = tid; i < n; i += 1024) {
        unsigned kk = seg[i].x - ((unsigned)b << BSHIFT);
        atomicAdd(&cnt[kk], 1u);
    }
    __syncthreads();
    unsigned c0 = cnt[tid * 2], c1 = cnt[tid * 2 + 1];
    unsigned tsum = c0 + c1;
    sc[tid] = tsum; __syncthreads();
    for (int o = 1; o < 1024; o <<= 1) {
        unsigned t = (tid >= o) ? sc[tid - o] : 0u;
        __syncthreads();
        sc[tid] += t;
        __syncthreads();
    }
    unsigned e0 = sc[tid] - tsum;
    unsigned e1 = e0 + c0;
    int k0 = (b << BSHIFT) + tid * 2;
    if (k0 < NKEY)     offs[k0]     = gb + e0;
    if (k0 + 1 < NKEY) offs[k0 + 1] = gb + e1;
    cnt[tid * 2] = e0; cnt[tid * 2 + 1] = e1;
    __syncthreads();
    for (unsigned i = tid; i < n; i += 1024) {
        uint2 rec = seg[i];
        unsigned kk = rec.x - ((unsigned)b << BSHIFT);
        unsigned pos = atomicAdd(&cnt[kk], 1u);
        csr[gb + pos] = rec.y;
    }
}

// ---- device body: convE for conv-block cb (1024 threads); shm >= 1600 words ----
__device__ __forceinline__
void convE_dev(int cb, int tid, const float* __restrict__ ent,
               const float* __restrict__ Mvec,
               uint4* __restrict__ entb, unsigned short* __restrict__ E16,
               unsigned* shm) {
    float4* sM = (float4*)shm;          // NREL1*16 = 400 float4 = 1600 words
    for (int i = tid; i < NREL1 * 16; i += 1024) sM[i] = ((const float4*)Mvec)[i];
    __syncthreads();
    int idx = cb * 1024 + tid;
    int h = idx >> 3;
    int sub = tid & 7;
    if (h >= N_ENT) return;
    const float4* e4 = (const float4*)ent;
    float4 a = e4[h * 16 + sub * 2], b4 = e4[h * 16 + sub * 2 + 1];
    uint4 o;
    o.x = (unsigned)f2bf(a.x)  | ((unsigned)f2bf(a.y)  << 16);
    o.y = (unsigned)f2bf(a.z)  | ((unsigned)f2bf(a.w)  << 16);
    o.z = (unsigned)f2bf(b4.x) | ((unsigned)f2bf(b4.y) << 16);
    o.w = (unsigned)f2bf(b4.z) | ((unsigned)f2bf(b4.w) << 16);
    entb[h * 8 + sub] = o;
    for (int r = 0; r < NREL1; ++r) {
        float d = dot4(a, sM[r * 16 + sub * 2]) + dot4(b4, sM[r * 16 + sub * 2 + 1]);
        d = red8(d);
        if (sub == (r & 7)) E16[h * NREL1 + r] = f2bf(__expf(d * SCORE_SCALE));
    }
}

// ---- serial path: place only (convE follows as its own launch; stg aliasing OK) ----
__global__ void binplace3_k(const uint2* __restrict__ stg,
                            const unsigned* __restrict__ gcur,
                            unsigned* __restrict__ offs,
                            unsigned* __restrict__ csr) {
    __shared__ __align__(16) unsigned shm[3074];
    place_bucket_dev(blockIdx.x, threadIdx.x, stg, gcur, offs, csr, shm);
}

__global__ void convE2_k(const float* __restrict__ ent,
                         const float* __restrict__ Mvec,
                         uint4* __restrict__ entb,
                         unsigned short* __restrict__ E16) {
    __shared__ __align__(16) unsigned shm[3074];
    convE_dev(blockIdx.x, threadIdx.x, ent, Mvec, entb, E16, shm);
}

// ---- fused path: ONLY legal when entb/E16 do NOT alias stg (disjoint layout).
__global__ void placeconv_k(const uint2* __restrict__ stg,
                            const unsigned* __restrict__ gcur,
                            unsigned* __restrict__ offs,
                            unsigned* __restrict__ csr,
                            const float* __restrict__ ent,
                            const float* __restrict__ Mvec,
                            uint4* __restrict__ entb,
                            unsigned short* __restrict__ E16) {
    __shared__ __align__(16) unsigned shm[3074];
    int b = blockIdx.x;
    if (b < NBUCKET)
        place_bucket_dev(b, threadIdx.x, stg, gcur, offs, csr, shm);
    else
        convE_dev(b - NBUCKET, threadIdx.x, ent, Mvec, entb, E16, shm);
}

// ---- fused gather: 8 lanes per key; entities then users (unified key space) ----
template<bool FAST>   // FAST: bf16 entb gathers + E-table; else fp32 + on-the-fly Mvec
__global__ void gather8_k(const float* __restrict__ ent,
                          const uint4* __restrict__ entb,
                          const unsigned short* __restrict__ E16,
                          const float* __restrict__ weight,
                          const float* __restrict__ Mvec,
                          const float* __restrict__ wnorm,
                          const float* __restrict__ uemb,
                          const float* __restrict__ lat,
                          const float* __restrict__ disen,
                          const unsigned* __restrict__ offs,
                          const unsigned* __restrict__ csr,
                          float* __restrict__ out) {
    int gid = blockIdx.x * 256 + threadIdx.x;
    int key = gid >> 3;
    int sub = threadIdx.x & 7;
    if (key >= NKEY) return;
    unsigned beg = offs[key], end = offs[key + 1];
    const float4* e4 = (const float4*)ent;
    const float4* w4 = (const float4*)weight;
    float4* o4 = (float4*)out;
    const float4 z = make_float4(0.f, 0.f, 0.f, 0.f);

    if (key < N_ENT) {
        int h = key;
        if (beg == end) {
            o4[h * 16 + sub * 2] = z;
            o4[h * 16 + sub * 2 + 1] = z;
            return;
        }
        float4 hv0, hv1;
        if (FAST) {
            uint4 hb = entb[h * 8 + sub];
            hv0 = bf4lo(hb); hv1 = bf4hi(hb);
        } else {
            hv0 = e4[h * 16 + sub * 2]; hv1 = e4[h * 16 + sub * 2 + 1];
        }
        float dr = 0.f;
        if (FAST) {
            for (unsigned i = beg + sub; i < end; i += 8)
                dr += bf2f(E16[h * NREL1 + (csr[i] >> 18)]);
            dr = red8(dr);
        } else {
            for (unsigned i = beg; i < end; ++i) {
                int r = csr[i] >> 18;
                float d = dot4(hv0, ((const float4*)Mvec)[r * 16 + sub * 2]) +
                          dot4(hv1, ((const float4*)Mvec)[r * 16 + sub * 2 + 1]);
                dr += __expf(red8(d) * SCORE_SCALE);
            }
        }
        float inv_dr = 1.0f / dr;
        float4 a0 = z, a1 = z;
        float dt = 0.f;
        unsigned i = beg;
        for (; i + 2 <= end; i += 2) {
            unsigned p0 = csr[i], p1 = csr[i + 1];
            int t0 = p0 & 0x3FFFF, r0 = p0 >> 18;
            int t1 = p1 & 0x3FFFF, r1 = p1 >> 18;
            float4 tv00, tv01, tv10, tv11;
            if (FAST) {
                uint4 tb0 = entb[t0 * 8 + sub];
                uint4 tb1 = entb[t1 * 8 + sub];
                tv00 = bf4lo(tb0); tv01 = bf4hi(tb0);
                tv10 = bf4lo(tb1); tv11 = bf4hi(tb1);
            } else {
                tv00 = e4[t0 * 16 + sub * 2]; tv01 = e4[t0 * 16 + sub * 2 + 1];
                tv10 = e4[t1 * 16 + sub * 2]; tv11 = e4[t1 * 16 + sub * 2 + 1];
            }
            float d0 = red8(dot4(hv0, tv00) + dot4(hv1, tv01));
            float d1 = red8(dot4(hv0, tv10) + dot4(hv1, tv11));
            float er0, er1;
            if (FAST) {
                er0 = bf2f(E16[h * NREL1 + r0]);
                er1 = bf2f(E16[h * NREL1 + r1]);
            } else {
                float q0 = dot4(hv0, ((const float4*)Mvec)[r0 * 16 + sub * 2]) +
                           dot4(hv1, ((const float4*)Mvec)[r0 * 16 + sub * 2 + 1]);
                float q1 = dot4(hv0, ((const float4*)Mvec)[r1 * 16 + sub * 2]) +
                           dot4(hv1, ((const float4*)Mvec)[r1 * 16 + sub * 2 + 1]);
                er0 = __expf(red8(q0) * SCORE_SCALE);
                er1 = __expf(red8(q1) * SCORE_SCALE);
            }
            float ra0 = er0 * inv_dr, ra1 = er1 * inv_dr;
            float et0 = __expf(d0 + ra0 * ra0 * wnorm[r0]);
            float et1 = __expf(d1 + ra1 * ra1 * wnorm[r1]);
            dt += et0 + et1;
            float4 wv;
            wv = w4[r0 * 16 + sub * 2];
            a0.x += et0 * tv00.x * wv.x; a0.y += et0 * tv00.y * wv.y;
            a0.z += et0 * tv00.z * wv.z; a0.w += et0 * tv00.w * wv.w;
            wv = w4[r0 * 16 + sub * 2 + 1];
            a1.x += et0 * tv01.x * wv.x; a1.y += et0 * tv01.y * wv.y;
            a1.z += et0 * tv01.z * wv.z; a1.w += et0 * tv01.w * wv.w;
            wv = w4[r1 * 16 + sub * 2];
            a0.x += et1 * tv10.x * wv.x; a0.y += et1 * tv10.y * wv.y;
            a0.z += et1 * tv10.z * wv.z; a0.w += et1 * tv10.w * wv.w;
            wv = w4[r1 * 16 + sub * 2 + 1];
            a1.x += et1 * tv11.x * wv.x; a1.y += et1 * tv11.y * wv.y;
            a1.z += et1 * tv11.z * wv.z; a1.w += et1 * tv11.w * wv.w;
        }
        if (i < end) {
            unsigned p = csr[i];
            int t = p & 0x3FFFF, r = p >> 18;
            float4 tv0, tv1;
            if (FAST) {
                uint4 tb = entb[t * 8 + sub];
                tv0 = bf4lo(tb); tv1 = bf4hi(tb);
            } else {
                tv0 = e4[t * 16 + sub * 2]; tv1 = e4[t * 16 + sub * 2 + 1];
            }
            float d = red8(dot4(hv0, tv0) + dot4(hv1, tv1));
            float er;
            if (FAST) {
                er = bf2f(E16[h * NREL1 + r]);
            } else {
                float q = dot4(hv0, ((const float4*)Mvec)[r * 16 + sub * 2]) +
                          dot4(hv1, ((const float4*)Mvec)[r * 16 + sub * 2 + 1]);
                er = __expf(red8(q) * SCORE_SCALE);
            }
            float ra = er * inv_dr;
            float et = __expf(d + ra * ra * wnorm[r]);
            dt += et;
            float4 wv;
            wv = w4[r * 16 + sub * 2];
            a0.x += et * tv0.x * wv.x; a0.y += et * tv0.y * wv.y;
            a0.z += et * tv0.z * wv.z; a0.w += et * tv0.w * wv.w;
            wv = w4[r * 16 + sub * 2 + 1];
            a1.x += et * tv1.x * wv.x; a1.y += et * tv1.y * wv.y;
            a1.z += et * tv1.z * wv.z; a1.w += et * tv1.w * wv.w;
        }
        float inv = 1.0f / (dt * (float)(end - beg));
        a0.x *= inv; a0.y *= inv; a0.z *= inv; a0.w *= inv;
        a1.x *= inv; a1.y *= inv; a1.z *= inv; a1.w *= inv;
        o4[h * 16 + sub * 2] = a0;
        o4[h * 16 + sub * 2 + 1] = a1;
    } else {
        int u = key - N_ENT;
        float4 a0 = z, a1 = z;
        unsigned i = beg;
        for (; i + 2 <= end; i += 2) {
            unsigned p0 = csr[i], p1 = csr[i + 1];
            int c0 = p0 & 0x3FFFF, c1 = p1 & 0x3FFFF;
            float v0 = (float)(p0 >> 18) * INV_Q14;
            float v1 = (float)(p1 >> 18) * INV_Q14;
            float4 tv00, tv01, tv10, tv11;
            if (FAST) {
                uint4 tb0 = entb[c0 * 8 + sub];
                uint4 tb1 = entb[c1 * 8 + sub];
                tv00 = bf4lo(tb0); tv01 = bf4hi(tb0);
                tv10 = bf4lo(tb1); tv11 = bf4hi(tb1);
            } else {
                tv00 = e4[c0 * 16 + sub * 2]; tv01 = e4[c0 * 16 + sub * 2 + 1];
                tv10 = e4[c1 * 16 + sub * 2]; tv11 = e4[c1 * 16 + sub * 2 + 1];
            }
            a0.x += v0 * tv00.x + v1 * tv10.x; a0.y += v0 * tv00.y + v1 * tv10.y;
            a0.z += v0 * tv00.z + v1 * tv10.z; a0.w += v0 * tv00.w + v1 * tv10.w;
            a1.x += v0 * tv01.x + v1 * tv11.x; a1.y += v0 * tv01.y + v1 * tv11.y;
            a1.z += v0 * tv01.z + v1 * tv11.z; a1.w += v0 * tv01.w + v1 * tv11.w;
        }
        if (i < end) {
            unsigned p = csr[i];
            int c = p & 0x3FFFF;
            float v = (float)(p >> 18) * INV_Q14;
            float4 tv0, tv1;
            if (FAST) {
                uint4 tb = entb[c * 8 + sub];
                tv0 = bf4lo(tb); tv1 = bf4hi(tb);
            } else {
                tv0 = e4[c * 16 + sub * 2]; tv1 = e4[c * 16 + sub * 2 + 1];
            }
            a0.x += v * tv0.x; a0.y += v * tv0.y; a0.z += v * tv0.z; a0.w += v * tv0.w;
            a1.x += v * tv1.x; a1.y += v * tv1.y; a1.z += v * tv1.z; a1.w += v * tv1.w;
        }
        float4 uv0 = ((const float4*)uemb)[u * 16 + sub * 2];
        float4 uv1 = ((const float4*)uemb)[u * 16 + sub * 2 + 1];
        float d[N_FACTORS];
        for (int f = 0; f < N_FACTORS; ++f) {
            float t = dot4(uv0, ((const float4*)lat)[f * 16 + sub * 2]) +
                      dot4(uv1, ((const float4*)lat)[f * 16 + sub * 2 + 1]);
            d[f] = red8(t);
        }
        float m = fmaxf(fmaxf(d[0], d[1]), fmaxf(d[2], d[3]));
        float s = 0.f, p_[N_FACTORS];
        for (int f = 0; f < N_FACTORS; ++f) { p_[f] = __expf(d[f] - m); s += p_[f]; }
        float invs = 1.0f / s;
        float4 g0 = z, g1 = z;
        for (int f = 0; f < N_FACTORS; ++f) {
            float w = p_[f] * invs;
            float4 dv = ((const float4*)disen)[f * 16 + sub * 2];
            g0.x += w * dv.x; g0.y += w * dv.y; g0.z += w * dv.z; g0.w += w * dv.w;
            dv = ((const float4*)disen)[f * 16 + sub * 2 + 1];
            g1.x += w * dv.x; g1.y += w * dv.y; g1.z += w * dv.z; g1.w += w * dv.w;
        }
        a0.x *= (1.0f + g0.x); a0.y *= (1.0f + g0.y);
        a0.z *= (1.0f + g0.z); a0.w *= (1.0f + g0.w);
        a1.x *= (1.0f + g1.x); a1.y *= (1.0f + g1.y);
        a1.z *= (1.0f + g1.z); a1.w *= (1.0f + g1.w);
        o4[key * 16 + sub * 2] = a0;
        o4[key * 16 + sub * 2 + 1] = a1;
    }
}

extern "C" void kernel_launch(void* const* d_in, const int* in_sizes, int n_in,
                              void* d_out, int out_size, void* d_ws, size_t ws_size,
                              hipStream_t stream) {
    (void)in_sizes; (void)n_in; (void)out_size;
    const float* ent    = (const float*)d_in[0];
    const float* uemb   = (const float*)d_in[1];
    const float* lat    = (const float*)d_in[2];
    const int*   eidx   = (const int*)d_in[3];
    const int*   etype  = (const int*)d_in[4];
    const int*   urows  = (const int*)d_in[5];
    const int*   ucols  = (const int*)d_in[6];
    const float* uvals  = (const float*)d_in[7];
    const float* weight = (const float*)d_in[8];
    const float* datt   = (const float*)d_in[9];
    const float* W      = (const float*)d_in[10];

    const int* head = eidx;
    const int* tail = eidx + N_EDGES;
    float* out = (float*)d_out;

    // ws layout (4B words). offs padded to NKEY+2 so 'big' starts 8B-aligned.
    unsigned* gcur  = (unsigned*)d_ws;            // 256 (147 used; pure counts)
    unsigned* offs  = gcur + 256;                 // NKEY+2 (offs[NKEY] used, +1 pad)
    float*    Mvec  = (float*)(offs + NKEY + 2);  // 1600
    float*    wnorm = Mvec + NREL1 * 64;          // 32
    float*    disen = wnorm + 32;                 // 256
    unsigned* csr   = (unsigned*)(disen + N_FACTORS * 64);   // 2M
    unsigned* big   = csr + NREC;                 // union / sequential region

    size_t base_words = 256 + (NKEY + 2) + 1888 + (size_t)NREC;           // 2.30M
    size_t stg_words  = (size_t)NBUCKET * CAP * 2;                        // 7.23M
    size_t tbl_words  = (size_t)N_ENT * 32 + ((size_t)N_ENT * NREL1 + 1) / 2;  // 8.9M
    size_t big_alias  = stg_words > tbl_words ? stg_words : tbl_words;
    size_t need_fast     = (base_words + big_alias) * 4;              // ~44.8 MB
    size_t need_min      = (base_words + stg_words) * 4;              // ~38.1 MB
    size_t need_disjoint = (base_words + stg_words + tbl_words) * 4;  // ~73.7 MB
    bool fast     = ws_size >= need_fast;
    bool disjoint = ws_size >= need_disjoint;   // disjoint implies fast
    if (ws_size < need_min) return;             // cannot run (never in practice)

    uint2*    stg  = (uint2*)big;
    // serial path: entb/E16 ALIAS stg (legal: convE launches after binplace3).
    // disjoint path: entb/E16 AFTER stg (legal to run concurrently).
    unsigned* entw = disjoint ? (big + stg_words) : big;
    uint4*    entb = (uint4*)entw;
    unsigned short* E16 = (unsigned short*)(entw + (size_t)N_ENT * 32);

    const int BLK = 256;

    hipMemsetAsync(gcur, 0, 256 * sizeof(unsigned), stream);
    binpre_k<<<NBLK_FILL + 1, BLK, 0, stream>>>(
        head, tail, etype, urows, ucols, uvals, gcur, stg,
        W, weight, datt, Mvec, wnorm, disen);

    if (disjoint) {
        placeconv_k<<<NBUCKET + NCONVB, 1024, 0, stream>>>(
            stg, gcur, offs, csr, ent, Mvec, entb, E16);
    } else {
        binplace3_k<<<NBUCKET, 1024, 0, stream>>>(stg, gcur, offs, csr);
        if (fast)
            convE2_k<<<NCONVB, 1024, 0, stream>>>(ent, Mvec, entb, E16);
    }

    int gridG = (NKEY * 8 + BLK - 1) / BLK;
    if (fast) {
        gather8_k<true><<<gridG, BLK, 0, stream>>>(
            ent, entb, E16, weight, Mvec, wnorm,
            uemb, lat, disen, offs, csr, out);
    } else {
        gather8_k<false><<<gridG, BLK, 0, stream>>>(
            ent, entb, E16, weight, Mvec, wnorm,
            uemb, lat, disen, offs, csr, out);
    }
}

// Round 14
// 198.073 us; speedup vs baseline: 2.1124x; 1.0195x over previous
//
#include <hip/hip_runtime.h>
#include <math.h>

#define N_ENT 200000
#define N_USERS 100000
#define NKEY 300000            // N_ENT + N_USERS unified key space
#define N_FACTORS 4
#define NREL1 25               // N_REL - 1
#define CH 64
#define N_EDGES 1000000
#define NNZ 1000000
#define NREC 2000000           // N_EDGES + NNZ unified records
#define BSHIFT 11
#define BKEYS 2048
#define NBUCKET 147            // ceil(NKEY / 2048)
#define TILE 2048
#define NBLK_FILL ((NREC + TILE - 1) / TILE)   // 977
// Staging lives in d_out now (dead before gather writes) -> roomy capacity.
// User buckets: mean 20480 (sigma~142); 32768 = mean + ~86 sigma.
#define CAP 32768
#define NCONVB ((N_ENT * 8 + 1023) / 1024)   // 1563 conv-role blocks

// 1 / (2*sqrt(32))
#define SCORE_SCALE 0.08838834764831845f
#define INV_Q14 6.103888176768602e-05f   // 1/16383

__device__ __forceinline__ float red8(float d) {
    d += __shfl_xor(d, 1);
    d += __shfl_xor(d, 2);
    d += __shfl_xor(d, 4);
    return d;
}
__device__ __forceinline__ float dot4(float4 a, float4 b) {
    return a.x * b.x + a.y * b.y + a.z * b.z + a.w * b.w;
}
__device__ __forceinline__ unsigned short f2bf(float f) {   // RNE
    unsigned u = __float_as_uint(f);
    u += 0x7FFFu + ((u >> 16) & 1u);
    return (unsigned short)(u >> 16);
}
__device__ __forceinline__ float bf2f(unsigned short u) {
    return __uint_as_float(((unsigned)u) << 16);
}
__device__ __forceinline__ float4 bf4lo(uint4 t) {
    return make_float4(__uint_as_float(t.x << 16), __uint_as_float(t.x & 0xFFFF0000u),
                       __uint_as_float(t.y << 16), __uint_as_float(t.y & 0xFFFF0000u));
}
__device__ __forceinline__ float4 bf4hi(uint4 t) {
    return make_float4(__uint_as_float(t.z << 16), __uint_as_float(t.z & 0xFFFF0000u),
                       __uint_as_float(t.w << 16), __uint_as_float(t.w & 0xFFFF0000u));
}

// ---- device body: tiny precompute (256 threads, one block-role) ----
__device__ __forceinline__
void precompute_dev(int tid, unsigned char* shmraw,
                    const float* __restrict__ W,
                    const float* __restrict__ weight,
                    const float* __restrict__ datt,
                    float* __restrict__ Mvec,
                    float* __restrict__ wnorm,
                    float* __restrict__ disen) {
    float* sW   = (float*)shmraw;          // 4096 f
    float* sw   = sW + 4096;               // 1600 f
    float* sWWt = sw + 1600;               // 4096 f -> 39168 B total
    for (int i = tid; i < 64 * 64; i += 256) sW[i] = W[i];
    for (int i = tid; i < NREL1 * 64; i += 256) sw[i] = weight[i];
    __syncthreads();
    for (int e = tid; e < 64 * 64; e += 256) {
        int i = e >> 6, j = e & 63;
        float s = 0.f;
        for (int k = 0; k < 64; ++k) s += sW[i * 64 + k] * sW[j * 64 + k];
        sWWt[e] = s;
    }
    __syncthreads();
    for (int e = tid; e < NREL1 * 64; e += 256) {
        int r = e >> 6, i = e & 63;
        float s = 0.f;
        for (int j = 0; j < 64; ++j) s += sWWt[i * 64 + j] * sw[r * 64 + j];
        Mvec[e] = s;
    }
    for (int r = tid; r < NREL1; r += 256) {
        float s = 0.f;
        for (int j = 0; j < 64; ++j) { float v = sw[r * 64 + j]; s += v * v; }
        wnorm[r] = s;
    }
    for (int e = tid; e < N_FACTORS * 64; e += 256) {
        int f = e >> 6, c = e & 63;
        float m = -1e30f;
        for (int r = 0; r < NREL1; ++r) m = fmaxf(m, datt[f * NREL1 + r]);
        float ssum = 0.f, acc = 0.f;
        for (int r = 0; r < NREL1; ++r) {
            float p = expf(datt[f * NREL1 + r] - m);
            ssum += p;
            acc += p * sw[r * 64 + c];
        }
        disen[e] = acc / ssum;
    }
}

// ---- fused stage 1 + precompute ----
__global__ void binpre_k(const int* __restrict__ head, const int* __restrict__ tail,
                         const int* __restrict__ etype,
                         const int* __restrict__ rows, const int* __restrict__ cols,
                         const float* __restrict__ vals,
                         unsigned* __restrict__ gcur,
                         uint2* __restrict__ stg,
                         const float* __restrict__ W,
                         const float* __restrict__ weight,
                         const float* __restrict__ datt,
                         float* __restrict__ Mvec,
                         float* __restrict__ wnorm,
                         float* __restrict__ disen) {
    __shared__ __align__(16) unsigned char shmraw[39936];  // 39 KB union
    int tid = threadIdx.x;
    if (blockIdx.x >= NBLK_FILL) {
        precompute_dev(tid, shmraw, W, weight, datt, Mvec, wnorm, disen);
        return;
    }
    unsigned* hist  = (unsigned*)shmraw;            // 147
    unsigned* base  = hist + NBUCKET;               // 147
    unsigned* gbase = base + NBUCKET;               // 147
    unsigned* wsum  = gbase + NBUCKET;              // 4
    uint2*    lrec  = (uint2*)(shmraw + 2048);      // 2048 uint2 (8B aligned)

    int tile0 = blockIdx.x * TILE;
    int tile_n = min(TILE, NREC - tile0);
    for (int b = tid; b < NBUCKET; b += 256) hist[b] = 0u;
    __syncthreads();                                            // B1
    unsigned key[8], pay[8], rank[8];
    for (int r = 0; r < 8; ++r) {
        int li = r * 256 + tid;
        key[r] = 0xFFFFFFFFu;
        if (li < tile_n) {
            int idx = tile0 + li;
            unsigned k, p;
            if (idx < N_EDGES) {
                k = (unsigned)head[idx];
                p = (unsigned)tail[idx] | ((unsigned)(etype[idx] - 1) << 18);
            } else {
                int j = idx - N_EDGES;
                k = (unsigned)(N_ENT + rows[j]);
                unsigned q = (unsigned)(vals[j] * 16383.f + 0.5f);
                p = (unsigned)cols[j] | (q << 18);
            }
            key[r] = k; pay[r] = p;
            rank[r] = atomicAdd(&hist[k >> BSHIFT], 1u);
        }
    }
    __syncthreads();                                            // B2
    // wave-shuffle exclusive scan of hist[0..146]
    unsigned h0 = (tid < NBUCKET) ? hist[tid] : 0u;
    unsigned v = h0;
    int lane = tid & 63, wid = tid >> 6;
    for (int o = 1; o < 64; o <<= 1) {
        unsigned t = __shfl_up(v, o);
        if (lane >= o) v += t;
    }
    if (lane == 63) wsum[wid] = v;
    __syncthreads();                                            // B3
    unsigned pre = 0;
    for (int w = 0; w < wid; ++w) pre += wsum[w];
    if (tid < NBUCKET) {
        base[tid] = pre + v - h0;       // exclusive prefix
        gbase[tid] = (unsigned)tid * CAP + (h0 ? atomicAdd(&gcur[tid], h0) : 0u);
    }
    __syncthreads();                                            // B4
    for (int r = 0; r < 8; ++r) {
        if (key[r] != 0xFFFFFFFFu) {
            unsigned b = key[r] >> BSHIFT;
            lrec[base[b] + rank[r]] = make_uint2(key[r], pay[r]);
        }
    }
    __syncthreads();                                            // B5
    for (int i = tid; i < tile_n; i += 256) {
        uint2 rec = lrec[i];
        unsigned b = rec.x >> BSHIFT;
        unsigned dst = gbase[b] + ((unsigned)i - base[b]);
        if (dst < (b + 1u) * CAP) stg[dst] = rec;   // overflow guard (never fires)
    }
}

// ---- device body: place one bucket (1024 threads); shm needs 3074 words ----
__device__ __forceinline__
void place_bucket_dev(int b, int tid, const uint2* __restrict__ stg,
                      const unsigned* __restrict__ gcur,
                      unsigned* __restrict__ offs, unsigned* __restrict__ csr,
                      unsigned* shm) {
    unsigned c = (tid < NBUCKET) ? gcur[tid] : 0u;
    if (c > CAP) c = CAP;
    if (tid < 256) shm[tid] = c;
    __syncthreads();
    for (int o = 1; o < 256; o <<= 1) {
        unsigned t = (tid >= o && tid < 256) ? shm[tid - o] : 0u;
        __syncthreads();
        if (tid < 256) shm[tid] += t;
        __syncthreads();
    }
    if (tid == 0) {
        unsigned cb = gcur[b]; if (cb > CAP) cb = CAP;
        shm[3073] = cb;
        shm[3072] = shm[b] - cb;                      // exclusive base
        if (b == NBUCKET - 1) offs[NKEY] = shm[NBUCKET - 1];  // grand total
    }
    __syncthreads();
    unsigned n = shm[3073], gb = shm[3072];
    const uint2* seg = stg + (size_t)b * CAP;
    unsigned* cnt = shm;
    unsigned* sc  = shm + 2048;
    cnt[tid * 2] = 0u; cnt[tid * 2 + 1] = 0u;
    __syncthreads();
    for (unsigned i = tid; i < n; i += 1024) {
        unsigned kk = seg[i].x - ((unsigned)b << BSHIFT);
        atomicAdd(&cnt[kk], 1u);
    }
    __syncthreads();
    unsigned c0 = cnt[tid * 2], c1 = cnt[tid * 2 + 1];
    unsigned tsum = c0 + c1;
    sc[tid] = tsum; __syncthreads();
    for (int o = 1; o < 1024; o <<= 1) {
        unsigned t = (tid >= o) ? sc[tid - o] : 0u;
        __syncthreads();
        sc[tid] += t;
        __syncthreads();
    }
    unsigned e0 = sc[tid] - tsum;
    unsigned e1 = e0 + c0;
    int k0 = (b << BSHIFT) + tid * 2;
    if (k0 < NKEY)     offs[k0]     = gb + e0;
    if (k0 + 1 < NKEY) offs[k0 + 1] = gb + e1;
    cnt[tid * 2] = e0; cnt[tid * 2 + 1] = e1;
    __syncthreads();
    for (unsigned i = tid; i < n; i += 1024) {
        uint2 rec = seg[i];
        unsigned kk = rec.x - ((unsigned)b << BSHIFT);
        unsigned pos = atomicAdd(&cnt[kk], 1u);
        csr[gb + pos] = rec.y;
    }
}

// ---- device body: convE for conv-block cb (1024 threads); shm >= 1600 words ----
__device__ __forceinline__
void convE_dev(int cb, int tid, const float* __restrict__ ent,
               const float* __restrict__ Mvec,
               uint4* __restrict__ entb, unsigned short* __restrict__ E16,
               unsigned* shm) {
    float4* sM = (float4*)shm;          // 400 float4 = 1600 words
    for (int i = tid; i < NREL1 * 16; i += 1024) sM[i] = ((const float4*)Mvec)[i];
    __syncthreads();
    int idx = cb * 1024 + tid;
    int h = idx >> 3;
    int sub = tid & 7;
    if (h >= N_ENT) return;
    const float4* e4 = (const float4*)ent;
    float4 a = e4[h * 16 + sub * 2], b4 = e4[h * 16 + sub * 2 + 1];
    uint4 o;
    o.x = (unsigned)f2bf(a.x)  | ((unsigned)f2bf(a.y)  << 16);
    o.y = (unsigned)f2bf(a.z)  | ((unsigned)f2bf(a.w)  << 16);
    o.z = (unsigned)f2bf(b4.x) | ((unsigned)f2bf(b4.y) << 16);
    o.w = (unsigned)f2bf(b4.z) | ((unsigned)f2bf(b4.w) << 16);
    entb[h * 8 + sub] = o;
    for (int r = 0; r < NREL1; ++r) {
        float d = dot4(a, sM[r * 16 + sub * 2]) + dot4(b4, sM[r * 16 + sub * 2 + 1]);
        d = red8(d);
        if (sub == (r & 7)) E16[h * NREL1 + r] = f2bf(__expf(d * SCORE_SCALE));
    }
}

// ---- fused place + convE. SAFE here unconditionally: stg lives in d_out,
// entb/E16 in ws -> disjoint by construction (R10's race is impossible).
__global__ void placeconv_k(const uint2* __restrict__ stg,
                            const unsigned* __restrict__ gcur,
                            unsigned* __restrict__ offs,
                            unsigned* __restrict__ csr,
                            const float* __restrict__ ent,
                            const float* __restrict__ Mvec,
                            uint4* __restrict__ entb,
                            unsigned short* __restrict__ E16) {
    __shared__ __align__(16) unsigned shm[3074];
    int b = blockIdx.x;
    if (b < NBUCKET)
        place_bucket_dev(b, threadIdx.x, stg, gcur, offs, csr, shm);
    else
        convE_dev(b - NBUCKET, threadIdx.x, ent, Mvec, entb, E16, shm);
}

// ---- place only (fallback when tables don't fit ws) ----
__global__ void binplace3_k(const uint2* __restrict__ stg,
                            const unsigned* __restrict__ gcur,
                            unsigned* __restrict__ offs,
                            unsigned* __restrict__ csr) {
    __shared__ __align__(16) unsigned shm[3074];
    place_bucket_dev(blockIdx.x, threadIdx.x, stg, gcur, offs, csr, shm);
}

// ---- fused gather: 8 lanes per key; entities then users (unified key space) ----
template<bool FAST>   // FAST: bf16 entb gathers + E-table; else fp32 + on-the-fly Mvec
__global__ void gather8_k(const float* __restrict__ ent,
                          const uint4* __restrict__ entb,
                          const unsigned short* __restrict__ E16,
                          const float* __restrict__ weight,
                          const float* __restrict__ Mvec,
                          const float* __restrict__ wnorm,
                          const float* __restrict__ uemb,
                          const float* __restrict__ lat,
                          const float* __restrict__ disen,
                          const unsigned* __restrict__ offs,
                          const unsigned* __restrict__ csr,
                          float* __restrict__ out) {
    int gid = blockIdx.x * 256 + threadIdx.x;
    int key = gid >> 3;
    int sub = threadIdx.x & 7;
    if (key >= NKEY) return;
    unsigned beg = offs[key], end = offs[key + 1];
    const float4* e4 = (const float4*)ent;
    const float4* w4 = (const float4*)weight;
    float4* o4 = (float4*)out;
    const float4 z = make_float4(0.f, 0.f, 0.f, 0.f);

    if (key < N_ENT) {
        int h = key;
        if (beg == end) {
            o4[h * 16 + sub * 2] = z;
            o4[h * 16 + sub * 2 + 1] = z;
            return;
        }
        float4 hv0, hv1;
        if (FAST) {
            uint4 hb = entb[h * 8 + sub];
            hv0 = bf4lo(hb); hv1 = bf4hi(hb);
        } else {
            hv0 = e4[h * 16 + sub * 2]; hv1 = e4[h * 16 + sub * 2 + 1];
        }
        float dr = 0.f;
        if (FAST) {
            for (unsigned i = beg + sub; i < end; i += 8)
                dr += bf2f(E16[h * NREL1 + (csr[i] >> 18)]);
            dr = red8(dr);
        } else {
            for (unsigned i = beg; i < end; ++i) {
                int r = csr[i] >> 18;
                float d = dot4(hv0, ((const float4*)Mvec)[r * 16 + sub * 2]) +
                          dot4(hv1, ((const float4*)Mvec)[r * 16 + sub * 2 + 1]);
                dr += __expf(red8(d) * SCORE_SCALE);
            }
        }
        float inv_dr = 1.0f / dr;
        float4 a0 = z, a1 = z;
        float dt = 0.f;
        unsigned i = beg;
        for (; i + 2 <= end; i += 2) {
            unsigned p0 = csr[i], p1 = csr[i + 1];
            int t0 = p0 & 0x3FFFF, r0 = p0 >> 18;
            int t1 = p1 & 0x3FFFF, r1 = p1 >> 18;
            float4 tv00, tv01, tv10, tv11;
            if (FAST) {
                uint4 tb0 = entb[t0 * 8 + sub];
                uint4 tb1 = entb[t1 * 8 + sub];
                tv00 = bf4lo(tb0); tv01 = bf4hi(tb0);
                tv10 = bf4lo(tb1); tv11 = bf4hi(tb1);
            } else {
                tv00 = e4[t0 * 16 + sub * 2]; tv01 = e4[t0 * 16 + sub * 2 + 1];
                tv10 = e4[t1 * 16 + sub * 2]; tv11 = e4[t1 * 16 + sub * 2 + 1];
            }
            float d0 = red8(dot4(hv0, tv00) + dot4(hv1, tv01));
            float d1 = red8(dot4(hv0, tv10) + dot4(hv1, tv11));
            float er0, er1;
            if (FAST) {
                er0 = bf2f(E16[h * NREL1 + r0]);
                er1 = bf2f(E16[h * NREL1 + r1]);
            } else {
                float q0 = dot4(hv0, ((const float4*)Mvec)[r0 * 16 + sub * 2]) +
                           dot4(hv1, ((const float4*)Mvec)[r0 * 16 + sub * 2 + 1]);
                float q1 = dot4(hv0, ((const float4*)Mvec)[r1 * 16 + sub * 2]) +
                           dot4(hv1, ((const float4*)Mvec)[r1 * 16 + sub * 2 + 1]);
                er0 = __expf(red8(q0) * SCORE_SCALE);
                er1 = __expf(red8(q1) * SCORE_SCALE);
            }
            float ra0 = er0 * inv_dr, ra1 = er1 * inv_dr;
            float et0 = __expf(d0 + ra0 * ra0 * wnorm[r0]);
            float et1 = __expf(d1 + ra1 * ra1 * wnorm[r1]);
            dt += et0 + et1;
            float4 wv;
            wv = w4[r0 * 16 + sub * 2];
            a0.x += et0 * tv00.x * wv.x; a0.y += et0 * tv00.y * wv.y;
            a0.z += et0 * tv00.z * wv.z; a0.w += et0 * tv00.w * wv.w;
            wv = w4[r0 * 16 + sub * 2 + 1];
            a1.x += et0 * tv01.x * wv.x; a1.y += et0 * tv01.y * wv.y;
            a1.z += et0 * tv01.z * wv.z; a1.w += et0 * tv01.w * wv.w;
            wv = w4[r1 * 16 + sub * 2];
            a0.x += et1 * tv10.x * wv.x; a0.y += et1 * tv10.y * wv.y;
            a0.z += et1 * tv10.z * wv.z; a0.w += et1 * tv10.w * wv.w;
            wv = w4[r1 * 16 + sub * 2 + 1];
            a1.x += et1 * tv11.x * wv.x; a1.y += et1 * tv11.y * wv.y;
            a1.z += et1 * tv11.z * wv.z; a1.w += et1 * tv11.w * wv.w;
        }
        if (i < end) {
            unsigned p = csr[i];
            int t = p & 0x3FFFF, r = p >> 18;
            float4 tv0, tv1;
            if (FAST) {
                uint4 tb = entb[t * 8 + sub];
                tv0 = bf4lo(tb); tv1 = bf4hi(tb);
            } else {
                tv0 = e4[t * 16 + sub * 2]; tv1 = e4[t * 16 + sub * 2 + 1];
            }
            float d = red8(dot4(hv0, tv0) + dot4(hv1, tv1));
            float er;
            if (FAST) {
                er = bf2f(E16[h * NREL1 + r]);
            } else {
                float q = dot4(hv0, ((const float4*)Mvec)[r * 16 + sub * 2]) +
                          dot4(hv1, ((const float4*)Mvec)[r * 16 + sub * 2 + 1]);
                er = __expf(red8(q) * SCORE_SCALE);
            }
            float ra = er * inv_dr;
            float et = __expf(d + ra * ra * wnorm[r]);
            dt += et;
            float4 wv;
            wv = w4[r * 16 + sub * 2];
            a0.x += et * tv0.x * wv.x; a0.y += et * tv0.y * wv.y;
            a0.z += et * tv0.z * wv.z; a0.w += et * tv0.w * wv.w;
            wv = w4[r * 16 + sub * 2 + 1];
            a1.x += et * tv1.x * wv.x; a1.y += et * tv1.y * wv.y;
            a1.z += et * tv1.z * wv.z; a1.w += et * tv1.w * wv.w;
        }
        float inv = 1.0f / (dt * (float)(end - beg));
        a0.x *= inv; a0.y *= inv; a0.z *= inv; a0.w *= inv;
        a1.x *= inv; a1.y *= inv; a1.z *= inv; a1.w *= inv;
        o4[h * 16 + sub * 2] = a0;
        o4[h * 16 + sub * 2 + 1] = a1;
    } else {
        int u = key - N_ENT;
        float4 a0 = z, a1 = z;
        unsigned i = beg;
        for (; i + 2 <= end; i += 2) {
            unsigned p0 = csr[i], p1 = csr[i + 1];
            int c0 = p0 & 0x3FFFF, c1 = p1 & 0x3FFFF;
            float v0 = (float)(p0 >> 18) * INV_Q14;
            float v1 = (float)(p1 >> 18) * INV_Q14;
            float4 tv00, tv01, tv10, tv11;
            if (FAST) {
                uint4 tb0 = entb[c0 * 8 + sub];
                uint4 tb1 = entb[c1 * 8 + sub];
                tv00 = bf4lo(tb0); tv01 = bf4hi(tb0);
                tv10 = bf4lo(tb1); tv11 = bf4hi(tb1);
            } else {
                tv00 = e4[c0 * 16 + sub * 2]; tv01 = e4[c0 * 16 + sub * 2 + 1];
                tv10 = e4[c1 * 16 + sub * 2]; tv11 = e4[c1 * 16 + sub * 2 + 1];
            }
            a0.x += v0 * tv00.x + v1 * tv10.x; a0.y += v0 * tv00.y + v1 * tv10.y;
            a0.z += v0 * tv00.z + v1 * tv10.z; a0.w += v0 * tv00.w + v1 * tv10.w;
            a1.x += v0 * tv01.x + v1 * tv11.x; a1.y += v0 * tv01.y + v1 * tv11.y;
            a1.z += v0 * tv01.z + v1 * tv11.z; a1.w += v0 * tv01.w + v1 * tv11.w;
        }
        if (i < end) {
            unsigned p = csr[i];
            int c = p & 0x3FFFF;
            float v = (float)(p >> 18) * INV_Q14;
            float4 tv0, tv1;
            if (FAST) {
                uint4 tb = entb[c * 8 + sub];
                tv0 = bf4lo(tb); tv1 = bf4hi(tb);
            } else {
                tv0 = e4[c * 16 + sub * 2]; tv1 = e4[c * 16 + sub * 2 + 1];
            }
            a0.x += v * tv0.x; a0.y += v * tv0.y; a0.z += v * tv0.z; a0.w += v * tv0.w;
            a1.x += v * tv1.x; a1.y += v * tv1.y; a1.z += v * tv1.z; a1.w += v * tv1.w;
        }
        float4 uv0 = ((const float4*)uemb)[u * 16 + sub * 2];
        float4 uv1 = ((const float4*)uemb)[u * 16 + sub * 2 + 1];
        float d[N_FACTORS];
        for (int f = 0; f < N_FACTORS; ++f) {
            float t = dot4(uv0, ((const float4*)lat)[f * 16 + sub * 2]) +
                      dot4(uv1, ((const float4*)lat)[f * 16 + sub * 2 + 1]);
            d[f] = red8(t);
        }
        float m = fmaxf(fmaxf(d[0], d[1]), fmaxf(d[2], d[3]));
        float s = 0.f, p_[N_FACTORS];
        for (int f = 0; f < N_FACTORS; ++f) { p_[f] = __expf(d[f] - m); s += p_[f]; }
        float invs = 1.0f / s;
        float4 g0 = z, g1 = z;
        for (int f = 0; f < N_FACTORS; ++f) {
            float w = p_[f] * invs;
            float4 dv = ((const float4*)disen)[f * 16 + sub * 2];
            g0.x += w * dv.x; g0.y += w * dv.y; g0.z += w * dv.z; g0.w += w * dv.w;
            dv = ((const float4*)disen)[f * 16 + sub * 2 + 1];
            g1.x += w * dv.x; g1.y += w * dv.y; g1.z += w * dv.z; g1.w += w * dv.w;
        }
        a0.x *= (1.0f + g0.x); a0.y *= (1.0f + g0.y);
        a0.z *= (1.0f + g0.z); a0.w *= (1.0f + g0.w);
        a1.x *= (1.0f + g1.x); a1.y *= (1.0f + g1.y);
        a1.z *= (1.0f + g1.z); a1.w *= (1.0f + g1.w);
        o4[key * 16 + sub * 2] = a0;
        o4[key * 16 + sub * 2 + 1] = a1;
    }
}

extern "C" void kernel_launch(void* const* d_in, const int* in_sizes, int n_in,
                              void* d_out, int out_size, void* d_ws, size_t ws_size,
                              hipStream_t stream) {
    (void)in_sizes; (void)n_in; (void)out_size;
    const float* ent    = (const float*)d_in[0];
    const float* uemb   = (const float*)d_in[1];
    const float* lat    = (const float*)d_in[2];
    const int*   eidx   = (const int*)d_in[3];
    const int*   etype  = (const int*)d_in[4];
    const int*   urows  = (const int*)d_in[5];
    const int*   ucols  = (const int*)d_in[6];
    const float* uvals  = (const float*)d_in[7];
    const float* weight = (const float*)d_in[8];
    const float* datt   = (const float*)d_in[9];
    const float* W      = (const float*)d_in[10];

    const int* head = eidx;
    const int* tail = eidx + N_EDGES;
    float* out = (float*)d_out;

    // STAGING IN D_OUT: stg (147*CAP*8B = 38.5 MB <= 76.8 MB) is dead before
    // gather8_k writes any output. Harness validates only after all launches.
    uint2* stg = (uint2*)d_out;

    // ws layout (4B words): everything else, always disjoint from stg.
    unsigned* gcur  = (unsigned*)d_ws;            // 256 (147 used; pure counts)
    unsigned* offs  = gcur + 256;                 // NKEY+2
    float*    Mvec  = (float*)(offs + NKEY + 2);  // 1600
    float*    wnorm = Mvec + NREL1 * 64;          // 32
    float*    disen = wnorm + 32;                 // 256
    unsigned* csr   = (unsigned*)(disen + N_FACTORS * 64);   // 2M
    unsigned* entw  = csr + NREC;                 // tables region
    uint4*    entb  = (uint4*)entw;               // N_ENT*32 words bf16 rows
    unsigned short* E16 = (unsigned short*)(entw + (size_t)N_ENT * 32);  // 2.5M words

    size_t base_words = 256 + (NKEY + 2) + 1888 + (size_t)NREC;           // 2.30M
    size_t tbl_words  = (size_t)N_ENT * 32 + ((size_t)N_ENT * NREL1 + 1) / 2;  // 8.9M
    size_t need_fast  = (base_words + tbl_words) * 4;   // ~44.9 MB
    size_t need_min   = base_words * 4;                 // ~9.2 MB
    size_t need_out   = (size_t)NBUCKET * CAP * 8;      // stg bytes in d_out
    bool fast = (ws_size >= need_fast) &&
                ((size_t)out_size * 4 >= need_out);
    if (ws_size < need_min || (size_t)out_size * 4 < need_out) return;  // never

    const int BLK = 256;

    hipMemsetAsync(gcur, 0, 256 * sizeof(unsigned), stream);
    binpre_k<<<NBLK_FILL + 1, BLK, 0, stream>>>(
        head, tail, etype, urows, ucols, uvals, gcur, stg,
        W, weight, datt, Mvec, wnorm, disen);

    if (fast) {
        placeconv_k<<<NBUCKET + NCONVB, 1024, 0, stream>>>(
            stg, gcur, offs, csr, ent, Mvec, entb, E16);
    } else {
        binplace3_k<<<NBUCKET, 1024, 0, stream>>>(stg, gcur, offs, csr);
    }

    int gridG = (NKEY * 8 + BLK - 1) / BLK;
    if (fast) {
        gather8_k<true><<<gridG, BLK, 0, stream>>>(
            ent, entb, E16, weight, Mvec, wnorm,
            uemb, lat, disen, offs, csr, out);
    } else {
        gather8_k<false><<<gridG, BLK, 0, stream>>>(
            ent, entb, E16, weight, Mvec, wnorm,
            uemb, lat, disen, offs, csr, out);
    }
}

// Round 15
// 196.072 us; speedup vs baseline: 2.1340x; 1.0102x over previous
//
#include <hip/hip_runtime.h>
#include <math.h>

#define N_ENT 200000
#define N_USERS 100000
#define NKEY 300000            // N_ENT + N_USERS unified key space
#define N_FACTORS 4
#define NREL1 25               // N_REL - 1
#define CH 64
#define N_EDGES 1000000
#define NNZ 1000000
#define NREC 2000000           // N_EDGES + NNZ unified records
#define BSHIFT 11
#define BKEYS 2048
#define NBUCKET 147            // ceil(NKEY / 2048)
#define TILE 2048
#define NBLK_FILL ((NREC + TILE - 1) / TILE)   // 977
// Staging lives in d_out (dead before gather writes).
#define CAP 32768
#define NCONVB ((N_ENT * 8 + 1023) / 1024)   // 1563 conv-role blocks

// 1 / (2*sqrt(32))
#define SCORE_SCALE 0.08838834764831845f
#define INV_Q14 6.103888176768602e-05f   // 1/16383

typedef __attribute__((ext_vector_type(2))) float floatx2;

__device__ __forceinline__ float red8(float d) {
    d += __shfl_xor(d, 1);
    d += __shfl_xor(d, 2);
    d += __shfl_xor(d, 4);
    return d;
}
__device__ __forceinline__ float dot4(float4 a, float4 b) {
    return a.x * b.x + a.y * b.y + a.z * b.z + a.w * b.w;
}
__device__ __forceinline__ unsigned short f2bf(float f) {   // RNE
    unsigned u = __float_as_uint(f);
    u += 0x7FFFu + ((u >> 16) & 1u);
    return (unsigned short)(u >> 16);
}
__device__ __forceinline__ float bf2f(unsigned short u) {
    return __uint_as_float(((unsigned)u) << 16);
}
__device__ __forceinline__ float4 bf4lo(uint4 t) {
    return make_float4(__uint_as_float(t.x << 16), __uint_as_float(t.x & 0xFFFF0000u),
                       __uint_as_float(t.y << 16), __uint_as_float(t.y & 0xFFFF0000u));
}
__device__ __forceinline__ float4 bf4hi(uint4 t) {
    return make_float4(__uint_as_float(t.z << 16), __uint_as_float(t.z & 0xFFFF0000u),
                       __uint_as_float(t.w << 16), __uint_as_float(t.w & 0xFFFF0000u));
}
// fp8 e4m3 (gfx950 OCP): HW roundtrip is self-consistent (same cvt unit both ways)
__device__ __forceinline__ void fp8x8_dec(uint2 v, float4& lo, float4& hi) {
    floatx2 a = __builtin_amdgcn_cvt_pk_f32_fp8((int)v.x, false);
    floatx2 b = __builtin_amdgcn_cvt_pk_f32_fp8((int)v.x, true);
    floatx2 c = __builtin_amdgcn_cvt_pk_f32_fp8((int)v.y, false);
    floatx2 d = __builtin_amdgcn_cvt_pk_f32_fp8((int)v.y, true);
    lo = make_float4(a[0], a[1], b[0], b[1]);
    hi = make_float4(c[0], c[1], d[0], d[1]);
}
__device__ __forceinline__ uint2 fp8x8_enc(float4 lo, float4 hi) {
    int l = __builtin_amdgcn_cvt_pk_fp8_f32(lo.x, lo.y, 0, false);
    l = __builtin_amdgcn_cvt_pk_fp8_f32(lo.z, lo.w, l, true);
    int h = __builtin_amdgcn_cvt_pk_fp8_f32(hi.x, hi.y, 0, false);
    h = __builtin_amdgcn_cvt_pk_fp8_f32(hi.z, hi.w, h, true);
    return make_uint2((unsigned)l, (unsigned)h);
}

// ---- device body: tiny precompute (256 threads, one block-role) ----
__device__ __forceinline__
void precompute_dev(int tid, unsigned char* shmraw,
                    const float* __restrict__ W,
                    const float* __restrict__ weight,
                    const float* __restrict__ datt,
                    float* __restrict__ Mvec,
                    float* __restrict__ wnorm,
                    float* __restrict__ disen) {
    float* sW   = (float*)shmraw;          // 4096 f
    float* sw   = sW + 4096;               // 1600 f
    float* sWWt = sw + 1600;               // 4096 f -> 39168 B total
    for (int i = tid; i < 64 * 64; i += 256) sW[i] = W[i];
    for (int i = tid; i < NREL1 * 64; i += 256) sw[i] = weight[i];
    __syncthreads();
    for (int e = tid; e < 64 * 64; e += 256) {
        int i = e >> 6, j = e & 63;
        float s = 0.f;
        for (int k = 0; k < 64; ++k) s += sW[i * 64 + k] * sW[j * 64 + k];
        sWWt[e] = s;
    }
    __syncthreads();
    for (int e = tid; e < NREL1 * 64; e += 256) {
        int r = e >> 6, i = e & 63;
        float s = 0.f;
        for (int j = 0; j < 64; ++j) s += sWWt[i * 64 + j] * sw[r * 64 + j];
        Mvec[e] = s;
    }
    for (int r = tid; r < NREL1; r += 256) {
        float s = 0.f;
        for (int j = 0; j < 64; ++j) { float v = sw[r * 64 + j]; s += v * v; }
        wnorm[r] = s;
    }
    for (int e = tid; e < N_FACTORS * 64; e += 256) {
        int f = e >> 6, c = e & 63;
        float m = -1e30f;
        for (int r = 0; r < NREL1; ++r) m = fmaxf(m, datt[f * NREL1 + r]);
        float ssum = 0.f, acc = 0.f;
        for (int r = 0; r < NREL1; ++r) {
            float p = expf(datt[f * NREL1 + r] - m);
            ssum += p;
            acc += p * sw[r * 64 + c];
        }
        disen[e] = acc / ssum;
    }
}

// ---- fused stage 1 + precompute; wave-privatized histograms (4x147) cut
// same-address LDS-atomic collision width 256 -> 64 lanes ----
__global__ void binpre_k(const int* __restrict__ head, const int* __restrict__ tail,
                         const int* __restrict__ etype,
                         const int* __restrict__ rows, const int* __restrict__ cols,
                         const float* __restrict__ vals,
                         unsigned* __restrict__ gcur,
                         uint2* __restrict__ stg,
                         const float* __restrict__ W,
                         const float* __restrict__ weight,
                         const float* __restrict__ datt,
                         float* __restrict__ Mvec,
                         float* __restrict__ wnorm,
                         float* __restrict__ disen) {
    __shared__ __align__(16) unsigned char shmraw[39936];  // 39 KB union
    int tid = threadIdx.x;
    if (blockIdx.x >= NBLK_FILL) {
        precompute_dev(tid, shmraw, W, weight, datt, Mvec, wnorm, disen);
        return;
    }
    unsigned* hist  = (unsigned*)shmraw;            // 4 waves x 160 (147 used)
    unsigned* base  = hist + 640;                   // 160
    unsigned* gbase = base + 160;                   // 160
    unsigned* wsum  = gbase + 160;                  // 4
    uint2*    lrec  = (uint2*)(shmraw + 4096);      // 2048 uint2 = 16 KB

    int tile0 = blockIdx.x * TILE;
    int tile_n = min(TILE, NREC - tile0);
    for (int i = tid; i < 640; i += 256) hist[i] = 0u;
    __syncthreads();                                            // B1
    int wid = tid >> 6;
    unsigned key[8], pay[8], rank[8];
    for (int r = 0; r < 8; ++r) {
        int li = r * 256 + tid;
        key[r] = 0xFFFFFFFFu;
        if (li < tile_n) {
            int idx = tile0 + li;
            unsigned k, p;
            if (idx < N_EDGES) {
                k = (unsigned)head[idx];
                p = (unsigned)tail[idx] | ((unsigned)(etype[idx] - 1) << 18);
            } else {
                int j = idx - N_EDGES;
                k = (unsigned)(N_ENT + rows[j]);
                unsigned q = (unsigned)(vals[j] * 16383.f + 0.5f);
                p = (unsigned)cols[j] | (q << 18);
            }
            key[r] = k; pay[r] = p;
            rank[r] = atomicAdd(&hist[wid * 160 + (k >> BSHIFT)], 1u);
        }
    }
    __syncthreads();                                            // B2
    // merge per-wave hists: tot per bucket + exclusive wave offsets (in place)
    unsigned tot = 0;
    if (tid < NBUCKET) {
        unsigned h0 = hist[tid], h1 = hist[160 + tid];
        unsigned h2 = hist[320 + tid], h3 = hist[480 + tid];
        tot = h0 + h1 + h2 + h3;
        hist[tid] = 0u;
        hist[160 + tid] = h0;
        hist[320 + tid] = h0 + h1;
        hist[480 + tid] = h0 + h1 + h2;
    }
    // wave-shuffle exclusive scan of tot over buckets
    unsigned v = tot;
    int lane = tid & 63;
    for (int o = 1; o < 64; o <<= 1) {
        unsigned t = __shfl_up(v, o);
        if (lane >= o) v += t;
    }
    if (lane == 63) wsum[wid] = v;
    __syncthreads();                                            // B3
    unsigned pre = 0;
    for (int w = 0; w < wid; ++w) pre += wsum[w];
    if (tid < NBUCKET) {
        base[tid] = pre + v - tot;      // exclusive prefix
        gbase[tid] = (unsigned)tid * CAP + (tot ? atomicAdd(&gcur[tid], tot) : 0u);
    }
    __syncthreads();                                            // B4
    for (int r = 0; r < 8; ++r) {
        if (key[r] != 0xFFFFFFFFu) {
            unsigned b = key[r] >> BSHIFT;
            lrec[base[b] + hist[wid * 160 + b] + rank[r]] = make_uint2(key[r], pay[r]);
        }
    }
    __syncthreads();                                            // B5
    for (int i = tid; i < tile_n; i += 256) {
        uint2 rec = lrec[i];
        unsigned b = rec.x >> BSHIFT;
        unsigned dst = gbase[b] + ((unsigned)i - base[b]);
        if (dst < (b + 1u) * CAP) stg[dst] = rec;   // overflow guard (never fires)
    }
}

// ---- device body: place one bucket (1024 threads); shm needs 3074 words ----
__device__ __forceinline__
void place_bucket_dev(int b, int tid, const uint2* __restrict__ stg,
                      const unsigned* __restrict__ gcur,
                      unsigned* __restrict__ offs, unsigned* __restrict__ csr,
                      unsigned* shm) {
    unsigned c = (tid < NBUCKET) ? gcur[tid] : 0u;
    if (c > CAP) c = CAP;
    if (tid < 256) shm[tid] = c;
    __syncthreads();
    for (int o = 1; o < 256; o <<= 1) {
        unsigned t = (tid >= o && tid < 256) ? shm[tid - o] : 0u;
        __syncthreads();
        if (tid < 256) shm[tid] += t;
        __syncthreads();
    }
    if (tid == 0) {
        unsigned cb = gcur[b]; if (cb > CAP) cb = CAP;
        shm[3073] = cb;
        shm[3072] = shm[b] - cb;                      // exclusive base
        if (b == NBUCKET - 1) offs[NKEY] = shm[NBUCKET - 1];  // grand total
    }
    __syncthreads();
    unsigned n = shm[3073], gb = shm[3072];
    const uint2* seg = stg + (size_t)b * CAP;
    unsigned* cnt = shm;
    unsigned* sc  = shm + 2048;
    cnt[tid * 2] = 0u; cnt[tid * 2 + 1] = 0u;
    __syncthreads();
    for (unsigned i = tid; i < n; i += 1024) {
        unsigned kk = seg[i].x - ((unsigned)b << BSHIFT);
        atomicAdd(&cnt[kk], 1u);
    }
    __syncthreads();
    unsigned c0 = cnt[tid * 2], c1 = cnt[tid * 2 + 1];
    unsigned tsum = c0 + c1;
    sc[tid] = tsum; __syncthreads();
    for (int o = 1; o < 1024; o <<= 1) {
        unsigned t = (tid >= o) ? sc[tid - o] : 0u;
        __syncthreads();
        sc[tid] += t;
        __syncthreads();
    }
    unsigned e0 = sc[tid] - tsum;
    unsigned e1 = e0 + c0;
    int k0 = (b << BSHIFT) + tid * 2;
    if (k0 < NKEY)     offs[k0]     = gb + e0;
    if (k0 + 1 < NKEY) offs[k0 + 1] = gb + e1;
    cnt[tid * 2] = e0; cnt[tid * 2 + 1] = e1;
    __syncthreads();
    for (unsigned i = tid; i < n; i += 1024) {
        uint2 rec = seg[i];
        unsigned kk = rec.x - ((unsigned)b << BSHIFT);
        unsigned pos = atomicAdd(&cnt[kk], 1u);
        csr[gb + pos] = rec.y;
    }
}

// ---- device body: convE for conv-block cb (1024 threads); shm >= 1600 words ----
template<bool W8>
__device__ __forceinline__
void convE_dev(int cb, int tid, const float* __restrict__ ent,
               const float* __restrict__ Mvec,
               uint4* __restrict__ entb, unsigned short* __restrict__ E16,
               uint2* __restrict__ ent8, unsigned* shm) {
    float4* sM = (float4*)shm;          // 400 float4 = 1600 words
    for (int i = tid; i < NREL1 * 16; i += 1024) sM[i] = ((const float4*)Mvec)[i];
    __syncthreads();
    int idx = cb * 1024 + tid;
    int h = idx >> 3;
    int sub = tid & 7;
    if (h >= N_ENT) return;
    const float4* e4 = (const float4*)ent;
    float4 a = e4[h * 16 + sub * 2], b4 = e4[h * 16 + sub * 2 + 1];
    uint4 o;
    o.x = (unsigned)f2bf(a.x)  | ((unsigned)f2bf(a.y)  << 16);
    o.y = (unsigned)f2bf(a.z)  | ((unsigned)f2bf(a.w)  << 16);
    o.z = (unsigned)f2bf(b4.x) | ((unsigned)f2bf(b4.y) << 16);
    o.w = (unsigned)f2bf(b4.z) | ((unsigned)f2bf(b4.w) << 16);
    entb[h * 8 + sub] = o;
    if (W8) ent8[h * 8 + sub] = fp8x8_enc(a, b4);
    for (int r = 0; r < NREL1; ++r) {
        float d = dot4(a, sM[r * 16 + sub * 2]) + dot4(b4, sM[r * 16 + sub * 2 + 1]);
        d = red8(d);
        if (sub == (r & 7)) E16[h * NREL1 + r] = f2bf(__expf(d * SCORE_SCALE));
    }
}

// ---- fused place + convE (stg in d_out, tables in ws -> disjoint, race-free) ----
template<bool W8>
__global__ void placeconv_k(const uint2* __restrict__ stg,
                            const unsigned* __restrict__ gcur,
                            unsigned* __restrict__ offs,
                            unsigned* __restrict__ csr,
                            const float* __restrict__ ent,
                            const float* __restrict__ Mvec,
                            uint4* __restrict__ entb,
                            unsigned short* __restrict__ E16,
                            uint2* __restrict__ ent8) {
    __shared__ __align__(16) unsigned shm[3074];
    int b = blockIdx.x;
    if (b < NBUCKET)
        place_bucket_dev(b, threadIdx.x, stg, gcur, offs, csr, shm);
    else
        convE_dev<W8>(b - NBUCKET, threadIdx.x, ent, Mvec, entb, E16, ent8, shm);
}

// ---- place only (fallback when tables don't fit ws) ----
__global__ void binplace3_k(const uint2* __restrict__ stg,
                            const unsigned* __restrict__ gcur,
                            unsigned* __restrict__ offs,
                            unsigned* __restrict__ csr) {
    __shared__ __align__(16) unsigned shm[3074];
    place_bucket_dev(blockIdx.x, threadIdx.x, stg, gcur, offs, csr, shm);
}

// ---- entity-row loader: MODE 2=fp8, 1=bf16, 0=fp32 ----
template<int MODE>
__device__ __forceinline__
void ent_row(const uint4* entb, const uint2* ent8, const float4* e4,
             int t, int sub, float4& lo, float4& hi) {
    if (MODE == 2) {
        fp8x8_dec(ent8[t * 8 + sub], lo, hi);
    } else if (MODE == 1) {
        uint4 tb = entb[t * 8 + sub];
        lo = bf4lo(tb); hi = bf4hi(tb);
    } else {
        lo = e4[t * 16 + sub * 2]; hi = e4[t * 16 + sub * 2 + 1];
    }
}

// ---- fused gather: 8 lanes per key; entities then users ----
template<int MODE>
__global__ void gather8_k(const float* __restrict__ ent,
                          const uint4* __restrict__ entb,
                          const uint2* __restrict__ ent8,
                          const unsigned short* __restrict__ E16,
                          const float* __restrict__ weight,
                          const float* __restrict__ Mvec,
                          const float* __restrict__ wnorm,
                          const float* __restrict__ uemb,
                          const float* __restrict__ lat,
                          const float* __restrict__ disen,
                          const unsigned* __restrict__ offs,
                          const unsigned* __restrict__ csr,
                          float* __restrict__ out) {
    int gid = blockIdx.x * 256 + threadIdx.x;
    int key = gid >> 3;
    int sub = threadIdx.x & 7;
    if (key >= NKEY) return;
    unsigned beg = offs[key], end = offs[key + 1];
    const float4* e4 = (const float4*)ent;
    const float4* w4 = (const float4*)weight;
    float4* o4 = (float4*)out;
    const float4 z = make_float4(0.f, 0.f, 0.f, 0.f);

    if (key < N_ENT) {
        int h = key;
        if (beg == end) {
            o4[h * 16 + sub * 2] = z;
            o4[h * 16 + sub * 2 + 1] = z;
            return;
        }
        float4 hv0, hv1;
        ent_row<MODE>(entb, ent8, e4, h, sub, hv0, hv1);
        float dr = 0.f;
        if (MODE > 0) {
            for (unsigned i = beg + sub; i < end; i += 8)
                dr += bf2f(E16[h * NREL1 + (csr[i] >> 18)]);
            dr = red8(dr);
        } else {
            for (unsigned i = beg; i < end; ++i) {
                int r = csr[i] >> 18;
                float d = dot4(hv0, ((const float4*)Mvec)[r * 16 + sub * 2]) +
                          dot4(hv1, ((const float4*)Mvec)[r * 16 + sub * 2 + 1]);
                dr += __expf(red8(d) * SCORE_SCALE);
            }
        }
        float inv_dr = 1.0f / dr;
        float4 a0 = z, a1 = z;
        float dt = 0.f;
        unsigned i = beg;
        for (; i + 2 <= end; i += 2) {
            unsigned p0 = csr[i], p1 = csr[i + 1];
            int t0 = p0 & 0x3FFFF, r0 = p0 >> 18;
            int t1 = p1 & 0x3FFFF, r1 = p1 >> 18;
            float4 tv00, tv01, tv10, tv11;
            ent_row<MODE>(entb, ent8, e4, t0, sub, tv00, tv01);
            ent_row<MODE>(entb, ent8, e4, t1, sub, tv10, tv11);
            float d0 = red8(dot4(hv0, tv00) + dot4(hv1, tv01));
            float d1 = red8(dot4(hv0, tv10) + dot4(hv1, tv11));
            float er0, er1;
            if (MODE > 0) {
                er0 = bf2f(E16[h * NREL1 + r0]);
                er1 = bf2f(E16[h * NREL1 + r1]);
            } else {
                float q0 = dot4(hv0, ((const float4*)Mvec)[r0 * 16 + sub * 2]) +
                           dot4(hv1, ((const float4*)Mvec)[r0 * 16 + sub * 2 + 1]);
                float q1 = dot4(hv0, ((const float4*)Mvec)[r1 * 16 + sub * 2]) +
                           dot4(hv1, ((const float4*)Mvec)[r1 * 16 + sub * 2 + 1]);
                er0 = __expf(red8(q0) * SCORE_SCALE);
                er1 = __expf(red8(q1) * SCORE_SCALE);
            }
            float ra0 = er0 * inv_dr, ra1 = er1 * inv_dr;
            float et0 = __expf(d0 + ra0 * ra0 * wnorm[r0]);
            float et1 = __expf(d1 + ra1 * ra1 * wnorm[r1]);
            dt += et0 + et1;
            float4 wv;
            wv = w4[r0 * 16 + sub * 2];
            a0.x += et0 * tv00.x * wv.x; a0.y += et0 * tv00.y * wv.y;
            a0.z += et0 * tv00.z * wv.z; a0.w += et0 * tv00.w * wv.w;
            wv = w4[r0 * 16 + sub * 2 + 1];
            a1.x += et0 * tv01.x * wv.x; a1.y += et0 * tv01.y * wv.y;
            a1.z += et0 * tv01.z * wv.z; a1.w += et0 * tv01.w * wv.w;
            wv = w4[r1 * 16 + sub * 2];
            a0.x += et1 * tv10.x * wv.x; a0.y += et1 * tv10.y * wv.y;
            a0.z += et1 * tv10.z * wv.z; a0.w += et1 * tv10.w * wv.w;
            wv = w4[r1 * 16 + sub * 2 + 1];
            a1.x += et1 * tv11.x * wv.x; a1.y += et1 * tv11.y * wv.y;
            a1.z += et1 * tv11.z * wv.z; a1.w += et1 * tv11.w * wv.w;
        }
        if (i < end) {
            unsigned p = csr[i];
            int t = p & 0x3FFFF, r = p >> 18;
            float4 tv0, tv1;
            ent_row<MODE>(entb, ent8, e4, t, sub, tv0, tv1);
            float d = red8(dot4(hv0, tv0) + dot4(hv1, tv1));
            float er;
            if (MODE > 0) {
                er = bf2f(E16[h * NREL1 + r]);
            } else {
                float q = dot4(hv0, ((const float4*)Mvec)[r * 16 + sub * 2]) +
                          dot4(hv1, ((const float4*)Mvec)[r * 16 + sub * 2 + 1]);
                er = __expf(red8(q) * SCORE_SCALE);
            }
            float ra = er * inv_dr;
            float et = __expf(d + ra * ra * wnorm[r]);
            dt += et;
            float4 wv;
            wv = w4[r * 16 + sub * 2];
            a0.x += et * tv0.x * wv.x; a0.y += et * tv0.y * wv.y;
            a0.z += et * tv0.z * wv.z; a0.w += et * tv0.w * wv.w;
            wv = w4[r * 16 + sub * 2 + 1];
            a1.x += et * tv1.x * wv.x; a1.y += et * tv1.y * wv.y;
            a1.z += et * tv1.z * wv.z; a1.w += et * tv1.w * wv.w;
        }
        float inv = 1.0f / (dt * (float)(end - beg));
        a0.x *= inv; a0.y *= inv; a0.z *= inv; a0.w *= inv;
        a1.x *= inv; a1.y *= inv; a1.z *= inv; a1.w *= inv;
        o4[h * 16 + sub * 2] = a0;
        o4[h * 16 + sub * 2 + 1] = a1;
    } else {
        int u = key - N_ENT;
        float4 a0 = z, a1 = z;
        unsigned i = beg;
        for (; i + 2 <= end; i += 2) {
            unsigned p0 = csr[i], p1 = csr[i + 1];
            int c0 = p0 & 0x3FFFF, c1 = p1 & 0x3FFFF;
            float v0 = (float)(p0 >> 18) * INV_Q14;
            float v1 = (float)(p1 >> 18) * INV_Q14;
            float4 tv00, tv01, tv10, tv11;
            ent_row<(MODE > 0 ? 1 : 0)>(entb, ent8, e4, c0, sub, tv00, tv01);
            ent_row<(MODE > 0 ? 1 : 0)>(entb, ent8, e4, c1, sub, tv10, tv11);
            a0.x += v0 * tv00.x + v1 * tv10.x; a0.y += v0 * tv00.y + v1 * tv10.y;
            a0.z += v0 * tv00.z + v1 * tv10.z; a0.w += v0 * tv00.w + v1 * tv10.w;
            a1.x += v0 * tv01.x + v1 * tv11.x; a1.y += v0 * tv01.y + v1 * tv11.y;
            a1.z += v0 * tv01.z + v1 * tv11.z; a1.w += v0 * tv01.w + v1 * tv11.w;
        }
        if (i < end) {
            unsigned p = csr[i];
            int c = p & 0x3FFFF;
            float v = (float)(p >> 18) * INV_Q14;
            float4 tv0, tv1;
            ent_row<(MODE > 0 ? 1 : 0)>(entb, ent8, e4, c, sub, tv0, tv1);
            a0.x += v * tv0.x; a0.y += v * tv0.y; a0.z += v * tv0.z; a0.w += v * tv0.w;
            a1.x += v * tv1.x; a1.y += v * tv1.y; a1.z += v * tv1.z; a1.w += v * tv1.w;
        }
        float4 uv0 = ((const float4*)uemb)[u * 16 + sub * 2];
        float4 uv1 = ((const float4*)uemb)[u * 16 + sub * 2 + 1];
        float d[N_FACTORS];
        for (int f = 0; f < N_FACTORS; ++f) {
            float t = dot4(uv0, ((const float4*)lat)[f * 16 + sub * 2]) +
                      dot4(uv1, ((const float4*)lat)[f * 16 + sub * 2 + 1]);
            d[f] = red8(t);
        }
        float m = fmaxf(fmaxf(d[0], d[1]), fmaxf(d[2], d[3]));
        float s = 0.f, p_[N_FACTORS];
        for (int f = 0; f < N_FACTORS; ++f) { p_[f] = __expf(d[f] - m); s += p_[f]; }
        float invs = 1.0f / s;
        float4 g0 = z, g1 = z;
        for (int f = 0; f < N_FACTORS; ++f) {
            float w = p_[f] * invs;
            float4 dv = ((const float4*)disen)[f * 16 + sub * 2];
            g0.x += w * dv.x; g0.y += w * dv.y; g0.z += w * dv.z; g0.w += w * dv.w;
            dv = ((const float4*)disen)[f * 16 + sub * 2 + 1];
            g1.x += w * dv.x; g1.y += w * dv.y; g1.z += w * dv.z; g1.w += w * dv.w;
        }
        a0.x *= (1.0f + g0.x); a0.y *= (1.0f + g0.y);
        a0.z *= (1.0f + g0.z); a0.w *= (1.0f + g0.w);
        a1.x *= (1.0f + g1.x); a1.y *= (1.0f + g1.y);
        a1.z *= (1.0f + g1.z); a1.w *= (1.0f + g1.w);
        o4[key * 16 + sub * 2] = a0;
        o4[key * 16 + sub * 2 + 1] = a1;
    }
}

extern "C" void kernel_launch(void* const* d_in, const int* in_sizes, int n_in,
                              void* d_out, int out_size, void* d_ws, size_t ws_size,
                              hipStream_t stream) {
    (void)in_sizes; (void)n_in; (void)out_size;
    const float* ent    = (const float*)d_in[0];
    const float* uemb   = (const float*)d_in[1];
    const float* lat    = (const float*)d_in[2];
    const int*   eidx   = (const int*)d_in[3];
    const int*   etype  = (const int*)d_in[4];
    const int*   urows  = (const int*)d_in[5];
    const int*   ucols  = (const int*)d_in[6];
    const float* uvals  = (const float*)d_in[7];
    const float* weight = (const float*)d_in[8];
    const float* datt   = (const float*)d_in[9];
    const float* W      = (const float*)d_in[10];

    const int* head = eidx;
    const int* tail = eidx + N_EDGES;
    float* out = (float*)d_out;

    // Staging in d_out (38.5 MB <= 76.8 MB), dead before gather writes.
    uint2* stg = (uint2*)d_out;

    // ws layout (4B words)
    unsigned* gcur  = (unsigned*)d_ws;            // 256 (147 used; pure counts)
    unsigned* offs  = gcur + 256;                 // NKEY+2
    float*    Mvec  = (float*)(offs + NKEY + 2);  // 1600
    float*    wnorm = Mvec + NREL1 * 64;          // 32
    float*    disen = wnorm + 32;                 // 256
    unsigned* csr   = (unsigned*)(disen + N_FACTORS * 64);   // 2M
    unsigned* entw  = csr + NREC;                 // tables region
    uint4*    entb  = (uint4*)entw;                               // 6.4M words
    unsigned short* E16 = (unsigned short*)(entw + (size_t)N_ENT * 32);  // 2.5M w
    uint2*    ent8  = (uint2*)(entw + (size_t)N_ENT * 32 +
                               ((size_t)N_ENT * NREL1 + 1) / 2);  // 3.2M words

    size_t base_words = 256 + (NKEY + 2) + 1888 + (size_t)NREC;   // 2.302M
    size_t need1 = (base_words + 8900000ull) * 4;     // entb+E16       ~44.8 MB
    size_t need2 = (base_words + 12100000ull) * 4;    // + ent8 fp8     ~57.6 MB
    size_t need_out = (size_t)NBUCKET * CAP * 8;      // stg bytes in d_out
    int mode = (ws_size >= need2) ? 2 : (ws_size >= need1) ? 1 : 0;
    if (ws_size < base_words * 4 || (size_t)out_size * 4 < need_out) return;

    const int BLK = 256;

    hipMemsetAsync(gcur, 0, 256 * sizeof(unsigned), stream);
    binpre_k<<<NBLK_FILL + 1, BLK, 0, stream>>>(
        head, tail, etype, urows, ucols, uvals, gcur, stg,
        W, weight, datt, Mvec, wnorm, disen);

    if (mode == 2) {
        placeconv_k<true><<<NBUCKET + NCONVB, 1024, 0, stream>>>(
            stg, gcur, offs, csr, ent, Mvec, entb, E16, ent8);
    } else if (mode == 1) {
        placeconv_k<false><<<NBUCKET + NCONVB, 1024, 0, stream>>>(
            stg, gcur, offs, csr, ent, Mvec, entb, E16, ent8);
    } else {
        binplace3_k<<<NBUCKET, 1024, 0, stream>>>(stg, gcur, offs, csr);
    }

    int gridG = (NKEY * 8 + BLK - 1) / BLK;
    if (mode == 2) {
        gather8_k<2><<<gridG, BLK, 0, stream>>>(
            ent, entb, ent8, E16, weight, Mvec, wnorm,
            uemb, lat, disen, offs, csr, out);
    } else if (mode == 1) {
        gather8_k<1><<<gridG, BLK, 0, stream>>>(
            ent, entb, ent8, E16, weight, Mvec, wnorm,
            uemb, lat, disen, offs, csr, out);
    } else {
        gather8_k<0><<<gridG, BLK, 0, stream>>>(
            ent, entb, ent8, E16, weight, Mvec, wnorm,
            uemb, lat, disen, offs, csr, out);
    }
}

// Round 16
// 191.395 us; speedup vs baseline: 2.1861x; 1.0244x over previous
//
#include <hip/hip_runtime.h>
#include <math.h>

#define N_ENT 200000
#define N_USERS 100000
#define NKEY 300000            // N_ENT + N_USERS unified key space
#define N_FACTORS 4
#define NREL1 25               // N_REL - 1
#define CH 64
#define N_EDGES 1000000
#define NNZ 1000000
#define NREC 2000000           // N_EDGES + NNZ unified records
#define BSHIFT 11
#define BKEYS 2048
#define NBUCKET 147            // ceil(NKEY / 2048)
#define TILE 2048
#define NBLK_FILL ((NREC + TILE - 1) / TILE)   // 977
// Staging lives in d_out (dead before gather writes).
#define CAP 32768
#define NCONVB ((N_ENT * 8 + 255) / 256)     // 6250 conv blocks (256 thr, binpre)
#define NE16B  ((N_ENT * 8 + 1023) / 1024)   // 1563 E16 blocks (1024 thr, placeconv)

// 1 / (2*sqrt(32))
#define SCORE_SCALE 0.08838834764831845f
#define INV_Q14 6.103888176768602e-05f   // 1/16383

typedef __attribute__((ext_vector_type(2))) float floatx2;

__device__ __forceinline__ float red8(float d) {
    d += __shfl_xor(d, 1);
    d += __shfl_xor(d, 2);
    d += __shfl_xor(d, 4);
    return d;
}
__device__ __forceinline__ float dot4(float4 a, float4 b) {
    return a.x * b.x + a.y * b.y + a.z * b.z + a.w * b.w;
}
__device__ __forceinline__ unsigned short f2bf(float f) {   // RNE
    unsigned u = __float_as_uint(f);
    u += 0x7FFFu + ((u >> 16) & 1u);
    return (unsigned short)(u >> 16);
}
__device__ __forceinline__ float bf2f(unsigned short u) {
    return __uint_as_float(((unsigned)u) << 16);
}
__device__ __forceinline__ float4 bf4lo(uint4 t) {
    return make_float4(__uint_as_float(t.x << 16), __uint_as_float(t.x & 0xFFFF0000u),
                       __uint_as_float(t.y << 16), __uint_as_float(t.y & 0xFFFF0000u));
}
__device__ __forceinline__ float4 bf4hi(uint4 t) {
    return make_float4(__uint_as_float(t.z << 16), __uint_as_float(t.z & 0xFFFF0000u),
                       __uint_as_float(t.w << 16), __uint_as_float(t.w & 0xFFFF0000u));
}
// fp8 e4m3 (gfx950 OCP)
__device__ __forceinline__ void fp8x8_dec(uint2 v, float4& lo, float4& hi) {
    floatx2 a = __builtin_amdgcn_cvt_pk_f32_fp8((int)v.x, false);
    floatx2 b = __builtin_amdgcn_cvt_pk_f32_fp8((int)v.x, true);
    floatx2 c = __builtin_amdgcn_cvt_pk_f32_fp8((int)v.y, false);
    floatx2 d = __builtin_amdgcn_cvt_pk_f32_fp8((int)v.y, true);
    lo = make_float4(a[0], a[1], b[0], b[1]);
    hi = make_float4(c[0], c[1], d[0], d[1]);
}
__device__ __forceinline__ uint2 fp8x8_enc(float4 lo, float4 hi) {
    int l = __builtin_amdgcn_cvt_pk_fp8_f32(lo.x, lo.y, 0, false);
    l = __builtin_amdgcn_cvt_pk_fp8_f32(lo.z, lo.w, l, true);
    int h = __builtin_amdgcn_cvt_pk_fp8_f32(hi.x, hi.y, 0, false);
    h = __builtin_amdgcn_cvt_pk_fp8_f32(hi.z, hi.w, h, true);
    return make_uint2((unsigned)l, (unsigned)h);
}

// ---- device body: tiny precompute (256 threads, one block-role) ----
__device__ __forceinline__
void precompute_dev(int tid, unsigned char* shmraw,
                    const float* __restrict__ W,
                    const float* __restrict__ weight,
                    const float* __restrict__ datt,
                    float* __restrict__ Mvec,
                    float* __restrict__ wnorm,
                    float* __restrict__ disen) {
    float* sW   = (float*)shmraw;          // 4096 f
    float* sw   = sW + 4096;               // 1600 f
    float* sWWt = sw + 1600;               // 4096 f -> 39168 B total
    for (int i = tid; i < 64 * 64; i += 256) sW[i] = W[i];
    for (int i = tid; i < NREL1 * 64; i += 256) sw[i] = weight[i];
    __syncthreads();
    for (int e = tid; e < 64 * 64; e += 256) {
        int i = e >> 6, j = e & 63;
        float s = 0.f;
        for (int k = 0; k < 64; ++k) s += sW[i * 64 + k] * sW[j * 64 + k];
        sWWt[e] = s;
    }
    __syncthreads();
    for (int e = tid; e < NREL1 * 64; e += 256) {
        int r = e >> 6, i = e & 63;
        float s = 0.f;
        for (int j = 0; j < 64; ++j) s += sWWt[i * 64 + j] * sw[r * 64 + j];
        Mvec[e] = s;
    }
    for (int r = tid; r < NREL1; r += 256) {
        float s = 0.f;
        for (int j = 0; j < 64; ++j) { float v = sw[r * 64 + j]; s += v * v; }
        wnorm[r] = s;
    }
    for (int e = tid; e < N_FACTORS * 64; e += 256) {
        int f = e >> 6, c = e & 63;
        float m = -1e30f;
        for (int r = 0; r < NREL1; ++r) m = fmaxf(m, datt[f * NREL1 + r]);
        float ssum = 0.f, acc = 0.f;
        for (int r = 0; r < NREL1; ++r) {
            float p = expf(datt[f * NREL1 + r] - m);
            ssum += p;
            acc += p * sw[r * 64 + c];
        }
        disen[e] = acc / ssum;
    }
}

// ---- device body: entb/ent8 conversion (256 threads; no LDS, no Mvec dep) ----
template<bool W8>
__device__ __forceinline__
void convtbl_dev(int cb, int tid, const float* __restrict__ ent,
                 uint4* __restrict__ entb, uint2* __restrict__ ent8) {
    int idx = cb * 256 + tid;
    int h = idx >> 3;
    int sub = idx & 7;
    if (h >= N_ENT) return;
    const float4* e4 = (const float4*)ent;
    float4 a = e4[h * 16 + sub * 2], b4 = e4[h * 16 + sub * 2 + 1];
    uint4 o;
    o.x = (unsigned)f2bf(a.x)  | ((unsigned)f2bf(a.y)  << 16);
    o.y = (unsigned)f2bf(a.z)  | ((unsigned)f2bf(a.w)  << 16);
    o.z = (unsigned)f2bf(b4.x) | ((unsigned)f2bf(b4.y) << 16);
    o.w = (unsigned)f2bf(b4.z) | ((unsigned)f2bf(b4.w) << 16);
    entb[h * 8 + sub] = o;
    if (W8) ent8[h * 8 + sub] = fp8x8_enc(a, b4);
}

// ---- fused stage 1 + precompute + entb/ent8 conversion ----
// blocks [0,NBLK_FILL): bin-fill; NBLK_FILL: precompute; rest: conv (overlaps).
template<bool W8>
__global__ void binpre_k(const int* __restrict__ head, const int* __restrict__ tail,
                         const int* __restrict__ etype,
                         const int* __restrict__ rows, const int* __restrict__ cols,
                         const float* __restrict__ vals,
                         unsigned* __restrict__ gcur,
                         uint2* __restrict__ stg,
                         const float* __restrict__ W,
                         const float* __restrict__ weight,
                         const float* __restrict__ datt,
                         float* __restrict__ Mvec,
                         float* __restrict__ wnorm,
                         float* __restrict__ disen,
                         const float* __restrict__ ent,
                         uint4* __restrict__ entb,
                         uint2* __restrict__ ent8) {
    __shared__ __align__(16) unsigned char shmraw[39936];  // 39 KB union
    int tid = threadIdx.x;
    if (blockIdx.x == NBLK_FILL) {
        precompute_dev(tid, shmraw, W, weight, datt, Mvec, wnorm, disen);
        return;
    }
    if (blockIdx.x > NBLK_FILL) {
        convtbl_dev<W8>(blockIdx.x - NBLK_FILL - 1, tid, ent, entb, ent8);
        return;
    }
    unsigned* hist  = (unsigned*)shmraw;            // 4 waves x 160 (147 used)
    unsigned* base  = hist + 640;                   // 160
    unsigned* gbase = base + 160;                   // 160
    unsigned* wsum  = gbase + 160;                  // 4
    uint2*    lrec  = (uint2*)(shmraw + 4096);      // 2048 uint2 = 16 KB

    int tile0 = blockIdx.x * TILE;
    int tile_n = min(TILE, NREC - tile0);
    for (int i = tid; i < 640; i += 256) hist[i] = 0u;
    __syncthreads();                                            // B1
    int wid = tid >> 6;
    unsigned key[8], pay[8], rank[8];
    for (int r = 0; r < 8; ++r) {
        int li = r * 256 + tid;
        key[r] = 0xFFFFFFFFu;
        if (li < tile_n) {
            int idx = tile0 + li;
            unsigned k, p;
            if (idx < N_EDGES) {
                k = (unsigned)head[idx];
                p = (unsigned)tail[idx] | ((unsigned)(etype[idx] - 1) << 18);
            } else {
                int j = idx - N_EDGES;
                k = (unsigned)(N_ENT + rows[j]);
                unsigned q = (unsigned)(vals[j] * 16383.f + 0.5f);
                p = (unsigned)cols[j] | (q << 18);
            }
            key[r] = k; pay[r] = p;
            rank[r] = atomicAdd(&hist[wid * 160 + (k >> BSHIFT)], 1u);
        }
    }
    __syncthreads();                                            // B2
    unsigned tot = 0;
    if (tid < NBUCKET) {
        unsigned h0 = hist[tid], h1 = hist[160 + tid];
        unsigned h2 = hist[320 + tid], h3 = hist[480 + tid];
        tot = h0 + h1 + h2 + h3;
        hist[tid] = 0u;
        hist[160 + tid] = h0;
        hist[320 + tid] = h0 + h1;
        hist[480 + tid] = h0 + h1 + h2;
    }
    unsigned v = tot;
    int lane = tid & 63;
    for (int o = 1; o < 64; o <<= 1) {
        unsigned t = __shfl_up(v, o);
        if (lane >= o) v += t;
    }
    if (lane == 63) wsum[wid] = v;
    __syncthreads();                                            // B3
    unsigned pre = 0;
    for (int w = 0; w < wid; ++w) pre += wsum[w];
    if (tid < NBUCKET) {
        base[tid] = pre + v - tot;      // exclusive prefix
        gbase[tid] = (unsigned)tid * CAP + (tot ? atomicAdd(&gcur[tid], tot) : 0u);
    }
    __syncthreads();                                            // B4
    for (int r = 0; r < 8; ++r) {
        if (key[r] != 0xFFFFFFFFu) {
            unsigned b = key[r] >> BSHIFT;
            lrec[base[b] + hist[wid * 160 + b] + rank[r]] = make_uint2(key[r], pay[r]);
        }
    }
    __syncthreads();                                            // B5
    for (int i = tid; i < tile_n; i += 256) {
        uint2 rec = lrec[i];
        unsigned b = rec.x >> BSHIFT;
        unsigned dst = gbase[b] + ((unsigned)i - base[b]);
        if (dst < (b + 1u) * CAP) stg[dst] = rec;   // overflow guard (never fires)
    }
}

// ---- device body: place one bucket (1024 threads); shm needs 3074 words ----
__device__ __forceinline__
void place_bucket_dev(int b, int tid, const uint2* __restrict__ stg,
                      const unsigned* __restrict__ gcur,
                      unsigned* __restrict__ offs, unsigned* __restrict__ csr,
                      unsigned* shm) {
    unsigned c = (tid < NBUCKET) ? gcur[tid] : 0u;
    if (c > CAP) c = CAP;
    if (tid < 256) shm[tid] = c;
    __syncthreads();
    for (int o = 1; o < 256; o <<= 1) {
        unsigned t = (tid >= o && tid < 256) ? shm[tid - o] : 0u;
        __syncthreads();
        if (tid < 256) shm[tid] += t;
        __syncthreads();
    }
    if (tid == 0) {
        unsigned cb = gcur[b]; if (cb > CAP) cb = CAP;
        shm[3073] = cb;
        shm[3072] = shm[b] - cb;                      // exclusive base
        if (b == NBUCKET - 1) offs[NKEY] = shm[NBUCKET - 1];  // grand total
    }
    __syncthreads();
    unsigned n = shm[3073], gb = shm[3072];
    const uint2* seg = stg + (size_t)b * CAP;
    unsigned* cnt = shm;
    unsigned* sc  = shm + 2048;
    cnt[tid * 2] = 0u; cnt[tid * 2 + 1] = 0u;
    __syncthreads();
    for (unsigned i = tid; i < n; i += 1024) {
        unsigned kk = seg[i].x - ((unsigned)b << BSHIFT);
        atomicAdd(&cnt[kk], 1u);
    }
    __syncthreads();
    unsigned c0 = cnt[tid * 2], c1 = cnt[tid * 2 + 1];
    unsigned tsum = c0 + c1;
    sc[tid] = tsum; __syncthreads();
    for (int o = 1; o < 1024; o <<= 1) {
        unsigned t = (tid >= o) ? sc[tid - o] : 0u;
        __syncthreads();
        sc[tid] += t;
        __syncthreads();
    }
    unsigned e0 = sc[tid] - tsum;
    unsigned e1 = e0 + c0;
    int k0 = (b << BSHIFT) + tid * 2;
    if (k0 < NKEY)     offs[k0]     = gb + e0;
    if (k0 + 1 < NKEY) offs[k0 + 1] = gb + e1;
    cnt[tid * 2] = e0; cnt[tid * 2 + 1] = e1;
    __syncthreads();
    for (unsigned i = tid; i < n; i += 1024) {
        uint2 rec = seg[i];
        unsigned kk = rec.x - ((unsigned)b << BSHIFT);
        unsigned pos = atomicAdd(&cnt[kk], 1u);
        csr[gb + pos] = rec.y;
    }
}

// ---- device body: E16 from bf16 entb (1024 threads; shm >= 1600 words) ----
__device__ __forceinline__
void e16_dev(int cb, int tid, const uint4* __restrict__ entb,
             const float* __restrict__ Mvec,
             unsigned short* __restrict__ E16, unsigned* shm) {
    float4* sM = (float4*)shm;          // 400 float4 = 1600 words
    for (int i = tid; i < NREL1 * 16; i += 1024) sM[i] = ((const float4*)Mvec)[i];
    __syncthreads();
    int idx = cb * 1024 + tid;
    int h = idx >> 3;
    int sub = tid & 7;
    if (h >= N_ENT) return;
    uint4 tb = entb[h * 8 + sub];
    float4 a = bf4lo(tb), b4 = bf4hi(tb);
    for (int r = 0; r < NREL1; ++r) {
        float d = dot4(a, sM[r * 16 + sub * 2]) + dot4(b4, sM[r * 16 + sub * 2 + 1]);
        d = red8(d);
        if (sub == (r & 7)) E16[h * NREL1 + r] = f2bf(__expf(d * SCORE_SCALE));
    }
}

// ---- fused place + E16 (stg in d_out, tables in ws -> disjoint, race-free) ----
__global__ void placee16_k(const uint2* __restrict__ stg,
                           const unsigned* __restrict__ gcur,
                           unsigned* __restrict__ offs,
                           unsigned* __restrict__ csr,
                           const uint4* __restrict__ entb,
                           const float* __restrict__ Mvec,
                           unsigned short* __restrict__ E16) {
    __shared__ __align__(16) unsigned shm[3074];
    int b = blockIdx.x;
    if (b < NBUCKET)
        place_bucket_dev(b, threadIdx.x, stg, gcur, offs, csr, shm);
    else
        e16_dev(b - NBUCKET, threadIdx.x, entb, Mvec, E16, shm);
}

// ---- place only (fallback when tables don't fit ws) ----
__global__ void binplace3_k(const uint2* __restrict__ stg,
                            const unsigned* __restrict__ gcur,
                            unsigned* __restrict__ offs,
                            unsigned* __restrict__ csr) {
    __shared__ __align__(16) unsigned shm[3074];
    place_bucket_dev(blockIdx.x, threadIdx.x, stg, gcur, offs, csr, shm);
}

// ---- entity-row loader: MODE 2=fp8, 1=bf16, 0=fp32 ----
template<int MODE>
__device__ __forceinline__
void ent_row(const uint4* entb, const uint2* ent8, const float4* e4,
             int t, int sub, float4& lo, float4& hi) {
    if (MODE == 2) {
        fp8x8_dec(ent8[t * 8 + sub], lo, hi);
    } else if (MODE == 1) {
        uint4 tb = entb[t * 8 + sub];
        lo = bf4lo(tb); hi = bf4hi(tb);
    } else {
        lo = e4[t * 16 + sub * 2]; hi = e4[t * 16 + sub * 2 + 1];
    }
}

// ---- fused gather: 8 lanes per key; entities then users ----
template<int MODE>
__global__ void gather8_k(const float* __restrict__ ent,
                          const uint4* __restrict__ entb,
                          const uint2* __restrict__ ent8,
                          const unsigned short* __restrict__ E16,
                          const float* __restrict__ weight,
                          const float* __restrict__ Mvec,
                          const float* __restrict__ wnorm,
                          const float* __restrict__ uemb,
                          const float* __restrict__ lat,
                          const float* __restrict__ disen,
                          const unsigned* __restrict__ offs,
                          const unsigned* __restrict__ csr,
                          float* __restrict__ out) {
    int gid = blockIdx.x * 256 + threadIdx.x;
    int key = gid >> 3;
    int sub = threadIdx.x & 7;
    if (key >= NKEY) return;
    unsigned beg = offs[key], end = offs[key + 1];
    const float4* e4 = (const float4*)ent;
    const float4* w4 = (const float4*)weight;
    float4* o4 = (float4*)out;
    const float4 z = make_float4(0.f, 0.f, 0.f, 0.f);

    if (key < N_ENT) {
        int h = key;
        if (beg == end) {
            o4[h * 16 + sub * 2] = z;
            o4[h * 16 + sub * 2 + 1] = z;
            return;
        }
        float4 hv0, hv1;
        ent_row<MODE>(entb, ent8, e4, h, sub, hv0, hv1);
        float dr = 0.f;
        if (MODE > 0) {
            for (unsigned i = beg + sub; i < end; i += 8)
                dr += bf2f(E16[h * NREL1 + (csr[i] >> 18)]);
            dr = red8(dr);
        } else {
            for (unsigned i = beg; i < end; ++i) {
                int r = csr[i] >> 18;
                float d = dot4(hv0, ((const float4*)Mvec)[r * 16 + sub * 2]) +
                          dot4(hv1, ((const float4*)Mvec)[r * 16 + sub * 2 + 1]);
                dr += __expf(red8(d) * SCORE_SCALE);
            }
        }
        float inv_dr = 1.0f / dr;
        float4 a0 = z, a1 = z;
        float dt = 0.f;
        unsigned i = beg;
        for (; i + 2 <= end; i += 2) {
            unsigned p0 = csr[i], p1 = csr[i + 1];
            int t0 = p0 & 0x3FFFF, r0 = p0 >> 18;
            int t1 = p1 & 0x3FFFF, r1 = p1 >> 18;
            float4 tv00, tv01, tv10, tv11;
            ent_row<MODE>(entb, ent8, e4, t0, sub, tv00, tv01);
            ent_row<MODE>(entb, ent8, e4, t1, sub, tv10, tv11);
            float d0 = red8(dot4(hv0, tv00) + dot4(hv1, tv01));
            float d1 = red8(dot4(hv0, tv10) + dot4(hv1, tv11));
            float er0, er1;
            if (MODE > 0) {
                er0 = bf2f(E16[h * NREL1 + r0]);
                er1 = bf2f(E16[h * NREL1 + r1]);
            } else {
                float q0 = dot4(hv0, ((const float4*)Mvec)[r0 * 16 + sub * 2]) +
                           dot4(hv1, ((const float4*)Mvec)[r0 * 16 + sub * 2 + 1]);
                float q1 = dot4(hv0, ((const float4*)Mvec)[r1 * 16 + sub * 2]) +
                           dot4(hv1, ((const float4*)Mvec)[r1 * 16 + sub * 2 + 1]);
                er0 = __expf(red8(q0) * SCORE_SCALE);
                er1 = __expf(red8(q1) * SCORE_SCALE);
            }
            float ra0 = er0 * inv_dr, ra1 = er1 * inv_dr;
            float et0 = __expf(d0 + ra0 * ra0 * wnorm[r0]);
            float et1 = __expf(d1 + ra1 * ra1 * wnorm[r1]);
            dt += et0 + et1;
            float4 wv;
            wv = w4[r0 * 16 + sub * 2];
            a0.x += et0 * tv00.x * wv.x; a0.y += et0 * tv00.y * wv.y;
            a0.z += et0 * tv00.z * wv.z; a0.w += et0 * tv00.w * wv.w;
            wv = w4[r0 * 16 + sub * 2 + 1];
            a1.x += et0 * tv01.x * wv.x; a1.y += et0 * tv01.y * wv.y;
            a1.z += et0 * tv01.z * wv.z; a1.w += et0 * tv01.w * wv.w;
            wv = w4[r1 * 16 + sub * 2];
            a0.x += et1 * tv10.x * wv.x; a0.y += et1 * tv10.y * wv.y;
            a0.z += et1 * tv10.z * wv.z; a0.w += et1 * tv10.w * wv.w;
            wv = w4[r1 * 16 + sub * 2 + 1];
            a1.x += et1 * tv11.x * wv.x; a1.y += et1 * tv11.y * wv.y;
            a1.z += et1 * tv11.z * wv.z; a1.w += et1 * tv11.w * wv.w;
        }
        if (i < end) {
            unsigned p = csr[i];
            int t = p & 0x3FFFF, r = p >> 18;
            float4 tv0, tv1;
            ent_row<MODE>(entb, ent8, e4, t, sub, tv0, tv1);
            float d = red8(dot4(hv0, tv0) + dot4(hv1, tv1));
            float er;
            if (MODE > 0) {
                er = bf2f(E16[h * NREL1 + r]);
            } else {
                float q = dot4(hv0, ((const float4*)Mvec)[r * 16 + sub * 2]) +
                          dot4(hv1, ((const float4*)Mvec)[r * 16 + sub * 2 + 1]);
                er = __expf(red8(q) * SCORE_SCALE);
            }
            float ra = er * inv_dr;
            float et = __expf(d + ra * ra * wnorm[r]);
            dt += et;
            float4 wv;
            wv = w4[r * 16 + sub * 2];
            a0.x += et * tv0.x * wv.x; a0.y += et * tv0.y * wv.y;
            a0.z += et * tv0.z * wv.z; a0.w += et * tv0.w * wv.w;
            wv = w4[r * 16 + sub * 2 + 1];
            a1.x += et * tv1.x * wv.x; a1.y += et * tv1.y * wv.y;
            a1.z += et * tv1.z * wv.z; a1.w += et * tv1.w * wv.w;
        }
        float inv = 1.0f / (dt * (float)(end - beg));
        a0.x *= inv; a0.y *= inv; a0.z *= inv; a0.w *= inv;
        a1.x *= inv; a1.y *= inv; a1.z *= inv; a1.w *= inv;
        o4[h * 16 + sub * 2] = a0;
        o4[h * 16 + sub * 2 + 1] = a1;
    } else {
        int u = key - N_ENT;
        float4 a0 = z, a1 = z;
        unsigned i = beg;
        for (; i + 2 <= end; i += 2) {
            unsigned p0 = csr[i], p1 = csr[i + 1];
            int c0 = p0 & 0x3FFFF, c1 = p1 & 0x3FFFF;
            float v0 = (float)(p0 >> 18) * INV_Q14;
            float v1 = (float)(p1 >> 18) * INV_Q14;
            float4 tv00, tv01, tv10, tv11;
            ent_row<(MODE > 0 ? 1 : 0)>(entb, ent8, e4, c0, sub, tv00, tv01);
            ent_row<(MODE > 0 ? 1 : 0)>(entb, ent8, e4, c1, sub, tv10, tv11);
            a0.x += v0 * tv00.x + v1 * tv10.x; a0.y += v0 * tv00.y + v1 * tv10.y;
            a0.z += v0 * tv00.z + v1 * tv10.z; a0.w += v0 * tv00.w + v1 * tv10.w;
            a1.x += v0 * tv01.x + v1 * tv11.x; a1.y += v0 * tv01.y + v1 * tv11.y;
            a1.z += v0 * tv01.z + v1 * tv11.z; a1.w += v0 * tv01.w + v1 * tv11.w;
        }
        if (i < end) {
            unsigned p = csr[i];
            int c = p & 0x3FFFF;
            float v = (float)(p >> 18) * INV_Q14;
            float4 tv0, tv1;
            ent_row<(MODE > 0 ? 1 : 0)>(entb, ent8, e4, c, sub, tv0, tv1);
            a0.x += v * tv0.x; a0.y += v * tv0.y; a0.z += v * tv0.z; a0.w += v * tv0.w;
            a1.x += v * tv1.x; a1.y += v * tv1.y; a1.z += v * tv1.z; a1.w += v * tv1.w;
        }
        float4 uv0 = ((const float4*)uemb)[u * 16 + sub * 2];
        float4 uv1 = ((const float4*)uemb)[u * 16 + sub * 2 + 1];
        float d[N_FACTORS];
        for (int f = 0; f < N_FACTORS; ++f) {
            float t = dot4(uv0, ((const float4*)lat)[f * 16 + sub * 2]) +
                      dot4(uv1, ((const float4*)lat)[f * 16 + sub * 2 + 1]);
            d[f] = red8(t);
        }
        float m = fmaxf(fmaxf(d[0], d[1]), fmaxf(d[2], d[3]));
        float s = 0.f, p_[N_FACTORS];
        for (int f = 0; f < N_FACTORS; ++f) { p_[f] = __expf(d[f] - m); s += p_[f]; }
        float invs = 1.0f / s;
        float4 g0 = z, g1 = z;
        for (int f = 0; f < N_FACTORS; ++f) {
            float w = p_[f] * invs;
            float4 dv = ((const float4*)disen)[f * 16 + sub * 2];
            g0.x += w * dv.x; g0.y += w * dv.y; g0.z += w * dv.z; g0.w += w * dv.w;
            dv = ((const float4*)disen)[f * 16 + sub * 2 + 1];
            g1.x += w * dv.x; g1.y += w * dv.y; g1.z += w * dv.z; g1.w += w * dv.w;
        }
        a0.x *= (1.0f + g0.x); a0.y *= (1.0f + g0.y);
        a0.z *= (1.0f + g0.z); a0.w *= (1.0f + g0.w);
        a1.x *= (1.0f + g1.x); a1.y *= (1.0f + g1.y);
        a1.z *= (1.0f + g1.z); a1.w *= (1.0f + g1.w);
        o4[key * 16 + sub * 2] = a0;
        o4[key * 16 + sub * 2 + 1] = a1;
    }
}

extern "C" void kernel_launch(void* const* d_in, const int* in_sizes, int n_in,
                              void* d_out, int out_size, void* d_ws, size_t ws_size,
                              hipStream_t stream) {
    (void)in_sizes; (void)n_in; (void)out_size;
    const float* ent    = (const float*)d_in[0];
    const float* uemb   = (const float*)d_in[1];
    const float* lat    = (const float*)d_in[2];
    const int*   eidx   = (const int*)d_in[3];
    const int*   etype  = (const int*)d_in[4];
    const int*   urows  = (const int*)d_in[5];
    const int*   ucols  = (const int*)d_in[6];
    const float* uvals  = (const float*)d_in[7];
    const float* weight = (const float*)d_in[8];
    const float* datt   = (const float*)d_in[9];
    const float* W      = (const float*)d_in[10];

    const int* head = eidx;
    const int* tail = eidx + N_EDGES;
    float* out = (float*)d_out;

    // Staging in d_out (38.5 MB <= 76.8 MB), dead before gather writes.
    uint2* stg = (uint2*)d_out;

    // ws layout (4B words)
    unsigned* gcur  = (unsigned*)d_ws;            // 256 (147 used; pure counts)
    unsigned* offs  = gcur + 256;                 // NKEY+2
    float*    Mvec  = (float*)(offs + NKEY + 2);  // 1600
    float*    wnorm = Mvec + NREL1 * 64;          // 32
    float*    disen = wnorm + 32;                 // 256
    unsigned* csr   = (unsigned*)(disen + N_FACTORS * 64);   // 2M
    unsigned* entw  = csr + NREC;                 // tables region
    uint4*    entb  = (uint4*)entw;                               // 6.4M words
    unsigned short* E16 = (unsigned short*)(entw + (size_t)N_ENT * 32);  // 2.5M w
    uint2*    ent8  = (uint2*)(entw + (size_t)N_ENT * 32 +
                               ((size_t)N_ENT * NREL1 + 1) / 2);  // 3.2M words

    size_t base_words = 256 + (NKEY + 2) + 1888 + (size_t)NREC;   // 2.302M
    size_t need1 = (base_words + 8900000ull) * 4;     // entb+E16       ~44.8 MB
    size_t need2 = (base_words + 12100000ull) * 4;    // + ent8 fp8     ~57.6 MB
    size_t need_out = (size_t)NBUCKET * CAP * 8;      // stg bytes in d_out
    int mode = (ws_size >= need2) ? 2 : (ws_size >= need1) ? 1 : 0;
    if (ws_size < base_words * 4 || (size_t)out_size * 4 < need_out) return;

    const int BLK = 256;
    int gridPre = NBLK_FILL + 1 + (mode >= 1 ? NCONVB : 0);

    hipMemsetAsync(gcur, 0, 256 * sizeof(unsigned), stream);
    if (mode == 2) {
        binpre_k<true><<<gridPre, BLK, 0, stream>>>(
            head, tail, etype, urows, ucols, uvals, gcur, stg,
            W, weight, datt, Mvec, wnorm, disen, ent, entb, ent8);
    } else {
        binpre_k<false><<<gridPre, BLK, 0, stream>>>(
            head, tail, etype, urows, ucols, uvals, gcur, stg,
            W, weight, datt, Mvec, wnorm, disen, ent, entb, ent8);
    }

    if (mode >= 1) {
        placee16_k<<<NBUCKET + NE16B, 1024, 0, stream>>>(
            stg, gcur, offs, csr, entb, Mvec, E16);
    } else {
        binplace3_k<<<NBUCKET, 1024, 0, stream>>>(stg, gcur, offs, csr);
    }

    int gridG = (NKEY * 8 + BLK - 1) / BLK;
    if (mode == 2) {
        gather8_k<2><<<gridG, BLK, 0, stream>>>(
            ent, entb, ent8, E16, weight, Mvec, wnorm,
            uemb, lat, disen, offs, csr, out);
    } else if (mode == 1) {
        gather8_k<1><<<gridG, BLK, 0, stream>>>(
            ent, entb, ent8, E16, weight, Mvec, wnorm,
            uemb, lat, disen, offs, csr, out);
    } else {
        gather8_k<0><<<gridG, BLK, 0, stream>>>(
            ent, entb, ent8, E16, weight, Mvec, wnorm,
            uemb, lat, disen, offs, csr, out);
    }
}